// Round 5
// baseline (235.988 us; speedup 1.0000x reference)
//
#include <hip/hip_runtime.h>
#include <hip/hip_bf16.h>

#define NN 4096

typedef __attribute__((ext_vector_type(8))) short short8;
typedef __attribute__((ext_vector_type(4))) float f32x4;

__device__ __forceinline__ unsigned short f2bf(float f) {
  union { float f; unsigned u; } v; v.f = f;
  unsigned u = v.u;
  u += 0x7fffu + ((u >> 16) & 1u);
  return (unsigned short)(u >> 16);
}

__device__ __forceinline__ unsigned packpair(float a, float b) {
  __hip_bfloat162 h = __float22bfloat162_rn(make_float2(a, b));  // v_cvt_pk_bf16_f32
  union { __hip_bfloat162 h; unsigned u; } cv; cv.h = h;
  return cv.u;
}

// ---------------- transpose q/k/v: f32 [256][NN] -> bf16 [NN][256]; + coords fill ----------------
// grid (64, 4, 3), block 256
__global__ __launch_bounds__(256) void transpose3_kernel(
    const float* __restrict__ q, const float* __restrict__ k, const float* __restrict__ v,
    unsigned short* __restrict__ Xt, const float* __restrict__ coords1,
    unsigned short* __restrict__ Vb) {
  __shared__ float Tl[64][65];
  const float* X = (blockIdx.z == 0) ? q : (blockIdx.z == 1) ? k : v;
  unsigned short* dst = Xt + (size_t)blockIdx.z * NN * 256;
  const int n0 = blockIdx.x << 6, k0 = blockIdx.y << 6;
  const int t = threadIdx.x;
  const int r = t >> 4, c4 = (t & 15) << 2;
#pragma unroll
  for (int i = 0; i < 4; ++i) {
    const float4 vv = *(const float4*)(X + (size_t)(k0 + r + 16 * i) * NN + n0 + c4);
    Tl[r + 16 * i][c4] = vv.x; Tl[r + 16 * i][c4 + 1] = vv.y;
    Tl[r + 16 * i][c4 + 2] = vv.z; Tl[r + 16 * i][c4 + 3] = vv.w;
  }
  __syncthreads();
  const int kc = (t & 7) << 3;
#pragma unroll
  for (int j = 0; j < 2; ++j) {
    const int n = (t >> 3) + (j << 5);
    unsigned pk[4];
#pragma unroll
    for (int u = 0; u < 4; ++u)
      pk[u] = packpair(Tl[kc + 2 * u][n], Tl[kc + 2 * u + 1][n]);
    *(uint4*)(dst + (size_t)(n0 + n) * 256 + k0 + kc) = *(uint4*)pk;
  }
  // folded coords fill: V rows 64..66 = coords1, 67..79 = 0 (once per n-chunk)
  if (blockIdx.z == 2 && blockIdx.y == 0) {
    const int rr = t >> 2, seg = t & 3;
    const int h = rr >> 4, d = 64 + (rr & 15);
    unsigned short* vd = Vb + (size_t)(h * 80 + d) * NN + n0 + seg * 16;
    if (d < 67) {
      const float* src = coords1 + (size_t)(d - 64) * NN + n0 + seg * 16;
      unsigned u[8];
#pragma unroll
      for (int i = 0; i < 4; ++i) {
        const float4 cv = *(const float4*)(src + 4 * i);
        u[2 * i] = packpair(cv.x, cv.y);
        u[2 * i + 1] = packpair(cv.z, cv.w);
      }
      *(uint4*)vd = *(uint4*)&u[0];
      *(uint4*)(vd + 8) = *(uint4*)&u[4];
    } else {
      const uint4 zz = make_uint4(0u, 0u, 0u, 0u);
      *(uint4*)vd = zz;
      *(uint4*)(vd + 8) = zz;
    }
  }
}

// ---------------- MFMA projection GEMM: C = W(256x256) . X(256xNN) ----------------
// grid (NN/64, 4, 3), block 256 = 4 waves (2x2). BM=64, BN=64, BK=64.
__global__ __launch_bounds__(256) void proj_gemm_kernel(
    const float* __restrict__ Wq, const float* __restrict__ bq,
    const float* __restrict__ Wk, const float* __restrict__ bk,
    const float* __restrict__ Wv, const float* __restrict__ bv,
    const unsigned short* __restrict__ Xt,
    unsigned short* __restrict__ Qb, unsigned short* __restrict__ Kb,
    unsigned short* __restrict__ Vb) {
  __shared__ __align__(16) unsigned char smem[16384];  // Al 64x128B | Bl 64x128B
  __shared__ float Bls[64];
  const int z = blockIdx.z;
  const float* W  = (z == 0) ? Wq : (z == 1) ? Wk : Wv;
  const float* bb = (z == 0) ? bq : (z == 1) ? bk : bv;
  const unsigned short* Xz = Xt + (size_t)z * NN * 256;
  const int co0 = blockIdx.y << 6;
  const int n0 = blockIdx.x << 6;
  const int tid = threadIdx.x;
  const int w = tid >> 6, l = tid & 63;
  const int wm = w >> 1, wn = w & 1;
  const int c = l & 15, g = l >> 4;
  char* const Al = (char*)smem;
  char* const Bl = (char*)smem + 8192;

  if (tid < 64) Bls[tid] = bb[co0 + tid];

  const int ar = tid >> 2, ac = (tid & 3) << 4;  // A: 4 thr/row, 16 f32 each
  const int br = tid >> 3, bch = tid & 7;        // B: rows br, br+32
  const int aswz = (ar & 7) << 4;
  const int bswz = (br & 7) << 4;                // (br+32)&7 == br&7

  float4 wa[4];
  uint4 wb[2];
  f32x4 acc[2][2];
#pragma unroll
  for (int mf = 0; mf < 2; ++mf)
#pragma unroll
    for (int nf = 0; nf < 2; ++nf) acc[mf][nf] = (f32x4){0.f, 0.f, 0.f, 0.f};

#define PJ_LOAD(k0_) do { \
  _Pragma("unroll") for (int i = 0; i < 4; ++i) \
    wa[i] = *(const float4*)(W + (size_t)(co0 + ar) * 256 + (k0_) + ac + 4 * i); \
  wb[0] = *(const uint4*)(Xz + (size_t)(n0 + br) * 256 + (k0_) + bch * 8); \
  wb[1] = *(const uint4*)(Xz + (size_t)(n0 + br + 32) * 256 + (k0_) + bch * 8); \
} while (0)

#define PJ_STORE() do { \
  unsigned pk[8]; \
  _Pragma("unroll") for (int i = 0; i < 4; ++i) { \
    pk[2 * i] = packpair(wa[i].x, wa[i].y); \
    pk[2 * i + 1] = packpair(wa[i].z, wa[i].w); \
  } \
  *(uint4*)(Al + ar * 128 + (((ac << 1)) ^ aswz)) = *(uint4*)&pk[0]; \
  *(uint4*)(Al + ar * 128 + (((ac << 1) + 16) ^ aswz)) = *(uint4*)&pk[4]; \
  *(uint4*)(Bl + br * 128 + ((bch << 4) ^ bswz)) = wb[0]; \
  *(uint4*)(Bl + (br + 32) * 128 + ((bch << 4) ^ bswz)) = wb[1]; \
} while (0)

  PJ_LOAD(0);
  PJ_STORE();
  __syncthreads();

  for (int s = 0; s < 4; ++s) {
    const bool hav = (s + 1 < 4);
    if (hav) PJ_LOAD((s + 1) << 6);
    __builtin_amdgcn_s_setprio(1);
#pragma unroll
    for (int ks = 0; ks < 2; ++ks) {
      short8 af[2], bf[2];
#pragma unroll
      for (int mf = 0; mf < 2; ++mf) {
        const int row = wm * 32 + mf * 16 + c;
        af[mf] = *(const short8*)(Al + row * 128 + (((ks << 6) + (g << 4)) ^ ((row & 7) << 4)));
      }
#pragma unroll
      for (int nf = 0; nf < 2; ++nf) {
        const int row = wn * 32 + nf * 16 + c;
        bf[nf] = *(const short8*)(Bl + row * 128 + (((ks << 6) + (g << 4)) ^ ((row & 7) << 4)));
      }
#pragma unroll
      for (int mf = 0; mf < 2; ++mf)
#pragma unroll
        for (int nf = 0; nf < 2; ++nf)
          acc[mf][nf] = __builtin_amdgcn_mfma_f32_16x16x32_bf16(af[mf], bf[nf], acc[mf][nf], 0, 0, 0);
    }
    __builtin_amdgcn_s_setprio(0);
    __syncthreads();
    if (hav) {
      PJ_STORE();
      __syncthreads();
    }
  }

  // epilogue: acc -> LDS bounce (bf16, stride 72) -> layout-specific global writes
  unsigned short* Clu = (unsigned short*)smem;  // [64][72]
  const float scale = (z == 0) ? 0.125f : 1.0f;
#pragma unroll
  for (int mf = 0; mf < 2; ++mf)
#pragma unroll
    for (int nf = 0; nf < 2; ++nf)
#pragma unroll
      for (int rr = 0; rr < 4; ++rr) {
        const int row = wm * 32 + mf * 16 + (g << 2) + rr;
        const int col = wn * 32 + nf * 16 + c;
        Clu[row * 72 + col] = f2bf((acc[mf][nf][rr] + Bls[row]) * scale);
      }
  __syncthreads();
  if (z <= 1) {
    unsigned short* Ob = (z == 0) ? Qb : Kb;
    const int d0 = co0 >> 2;
    const int h = tid >> 6, n = tid & 63;
    unsigned u[8];
#pragma unroll
    for (int p = 0; p < 8; ++p)
      u[p] = (unsigned)Clu[((p << 3) + h) * 72 + n] |
             ((unsigned)Clu[((p << 3) + 4 + h) * 72 + n] << 16);
    uint4* dd = (uint4*)(Ob + ((size_t)h * NN + n0 + n) * 64 + d0);
    dd[0] = *(uint4*)&u[0];
    dd[1] = *(uint4*)&u[4];
  } else {
    const int rl = tid >> 2, seg = (tid & 3) << 4;
    const int h = rl & 3, d = (co0 >> 2) + (rl >> 2);
    unsigned short* vd = Vb + (size_t)(h * 80 + d) * NN + n0 + seg;
    *(uint4*)vd = *(const uint4*)((char*)Clu + rl * 144 + (seg << 1));
    *(uint4*)(vd + 8) = *(const uint4*)((char*)Clu + rl * 144 + (seg << 1) + 16);
  }
}

// ---------------- fused flash attention (split-K, swapped-S^T, async stage, defer-max) ----------------
// grid (32, 4, nsplit): x = q-tile of 128, y = head, z = key-split.
__global__ __launch_bounds__(256) void attn_kernel(
    const unsigned short* __restrict__ Qb, const unsigned short* __restrict__ Kb,
    const unsigned short* __restrict__ Vb, float* __restrict__ Opart, int chunkKeys) {
  __shared__ __align__(16) unsigned char smem[34816];  // K 8192 | Vt 10240 | P 4x4096
  const int h = blockIdx.y;
  const int sp = blockIdx.z;
  const int qbase = blockIdx.x * 128;
  const int tid = threadIdx.x;
  const int w = tid >> 6;
  const int l = tid & 63;
  const int c = l & 15;
  const int g = l >> 4;
  const int swc = (c & 7) << 4;

  char* const Kls = (char*)smem;
  char* const Vls = (char*)smem + 8192;
  char* const Pls = (char*)smem + 18432 + w * 4096;

  short8 qf[2][2];
#pragma unroll
  for (int qs = 0; qs < 2; ++qs) {
    const unsigned short* qsrc = Qb + (((h * NN) + qbase + w * 32 + qs * 16 + c) << 6) + (g << 3);
    qf[qs][0] = *(const short8*)qsrc;
    qf[qs][1] = *(const short8*)(qsrc + 32);
  }

  f32x4 Of[2][5];
#pragma unroll
  for (int qs = 0; qs < 2; ++qs)
#pragma unroll
    for (int dt = 0; dt < 5; ++dt) Of[qs][dt] = (f32x4){0.f, 0.f, 0.f, 0.f};
  float mrun[2] = {-1e30f, -1e30f};
  float lrun[2] = {0.f, 0.f};

  const int r0 = tid >> 3, ch = tid & 7;
  const int so = (ch << 4) ^ ((r0 & 7) << 4);
  const int mStart = sp * chunkKeys;
  const int niter = chunkKeys >> 6;

  {
    const unsigned short* kbase = Kb + ((h * NN + mStart) << 6);
    const unsigned short* vbase = Vb + (size_t)(h * 80) * NN + mStart;
    const uint4 ka  = *(const uint4*)(kbase + (r0 << 6) + (ch << 3));
    const uint4 kb2 = *(const uint4*)(kbase + ((r0 + 32) << 6) + (ch << 3));
    const uint4 va  = *(const uint4*)(vbase + (size_t)r0 * NN + (ch << 3));
    const uint4 vb2 = *(const uint4*)(vbase + (size_t)(r0 + 32) * NN + (ch << 3));
    *(uint4*)(Kls + r0 * 128 + so) = ka;
    *(uint4*)(Kls + (r0 + 32) * 128 + so) = kb2;
    *(uint4*)(Vls + r0 * 128 + so) = va;
    *(uint4*)(Vls + (r0 + 32) * 128 + so) = vb2;
    if (tid < 128) {
      const uint4 vc = *(const uint4*)(vbase + (size_t)(r0 + 64) * NN + (ch << 3));
      *(uint4*)(Vls + (r0 + 64) * 128 + so) = vc;
    }
  }
  __syncthreads();

  for (int it = 0; it < niter; ++it) {
    uint4 ka, kb2, va, vb2, vc;
    const bool hav = (it + 1 < niter);
    if (hav) {
      const int m0 = mStart + ((it + 1) << 6);
      const unsigned short* kbase = Kb + ((h * NN + m0) << 6);
      const unsigned short* vbase = Vb + (size_t)(h * 80) * NN + m0;
      ka  = *(const uint4*)(kbase + (r0 << 6) + (ch << 3));
      kb2 = *(const uint4*)(kbase + ((r0 + 32) << 6) + (ch << 3));
      va  = *(const uint4*)(vbase + (size_t)r0 * NN + (ch << 3));
      vb2 = *(const uint4*)(vbase + (size_t)(r0 + 32) * NN + (ch << 3));
      if (tid < 128) vc = *(const uint4*)(vbase + (size_t)(r0 + 64) * NN + (ch << 3));
    }

    f32x4 sD[2][4];
    __builtin_amdgcn_s_setprio(1);
#pragma unroll
    for (int t = 0; t < 4; ++t) {
      const char* rp = Kls + (t * 16 + c) * 128;
      const short8 ka0 = *(const short8*)(rp + ((g << 4) ^ swc));
      const short8 ka1 = *(const short8*)(rp + ((64 + (g << 4)) ^ swc));
#pragma unroll
      for (int qs = 0; qs < 2; ++qs) {
        f32x4 a = (f32x4){0.f, 0.f, 0.f, 0.f};
        a = __builtin_amdgcn_mfma_f32_16x16x32_bf16(ka0, qf[qs][0], a, 0, 0, 0);
        a = __builtin_amdgcn_mfma_f32_16x16x32_bf16(ka1, qf[qs][1], a, 0, 0, 0);
        sD[qs][t] = a;
      }
    }
    __builtin_amdgcn_s_setprio(0);

#pragma unroll
    for (int qs = 0; qs < 2; ++qs) {
      float m01 = fmaxf(fmaxf(sD[qs][0][0], sD[qs][0][1]), fmaxf(sD[qs][0][2], sD[qs][0][3]));
      float m11 = fmaxf(fmaxf(sD[qs][1][0], sD[qs][1][1]), fmaxf(sD[qs][1][2], sD[qs][1][3]));
      float m21 = fmaxf(fmaxf(sD[qs][2][0], sD[qs][2][1]), fmaxf(sD[qs][2][2], sD[qs][2][3]));
      float m31 = fmaxf(fmaxf(sD[qs][3][0], sD[qs][3][1]), fmaxf(sD[qs][3][2], sD[qs][3][3]));
      float mx = fmaxf(fmaxf(m01, m11), fmaxf(m21, m31));
      mx = fmaxf(mx, __shfl_xor(mx, 16));
      mx = fmaxf(mx, __shfl_xor(mx, 32));
      // T13 defer-max: skip rescale when tile max within THR=8 of running max
      if (!__all(mx - mrun[qs] <= 8.f)) {
        const float mnew = fmaxf(mrun[qs], mx);
        const float a = __expf(mrun[qs] - mnew);
        mrun[qs] = mnew;
        lrun[qs] *= a;
#pragma unroll
        for (int dt = 0; dt < 5; ++dt)
#pragma unroll
          for (int r = 0; r < 4; ++r) Of[qs][dt][r] *= a;
      }
      const float mm = mrun[qs];
      float rs = 0.f;
      unsigned pk[8];
#pragma unroll
      for (int t = 0; t < 4; ++t) {
        const float e0 = __expf(sD[qs][t][0] - mm);
        const float e1 = __expf(sD[qs][t][1] - mm);
        const float e2 = __expf(sD[qs][t][2] - mm);
        const float e3 = __expf(sD[qs][t][3] - mm);
        rs += (e0 + e1) + (e2 + e3);
        pk[t * 2]     = packpair(e0, e1);
        pk[t * 2 + 1] = packpair(e2, e3);
      }
      rs += __shfl_xor(rs, 16);
      rs += __shfl_xor(rs, 32);
      lrun[qs] += rs;
      char* prow = Pls + (qs * 16 + c) * 128;
#pragma unroll
      for (int t = 0; t < 4; ++t)
        *(uint2*)(prow + ((t * 32 + (g << 3)) ^ swc)) = make_uint2(pk[t * 2], pk[t * 2 + 1]);
    }

    short8 pb[2][2];
#pragma unroll
    for (int qs = 0; qs < 2; ++qs) {
      const char* prow = Pls + (qs * 16 + c) * 128;
      pb[qs][0] = *(const short8*)(prow + ((g << 4) ^ swc));
      pb[qs][1] = *(const short8*)(prow + ((64 + (g << 4)) ^ swc));
    }
    __builtin_amdgcn_s_setprio(1);
#pragma unroll
    for (int dt = 0; dt < 5; ++dt) {
      const char* vp = Vls + (dt * 16 + c) * 128;
      const short8 va0 = *(const short8*)(vp + ((g << 4) ^ swc));
      const short8 va1 = *(const short8*)(vp + ((64 + (g << 4)) ^ swc));
#pragma unroll
      for (int qs = 0; qs < 2; ++qs) {
        Of[qs][dt] = __builtin_amdgcn_mfma_f32_16x16x32_bf16(va0, pb[qs][0], Of[qs][dt], 0, 0, 0);
        Of[qs][dt] = __builtin_amdgcn_mfma_f32_16x16x32_bf16(va1, pb[qs][1], Of[qs][dt], 0, 0, 0);
      }
    }
    __builtin_amdgcn_s_setprio(0);

    __syncthreads();
    if (hav) {
      *(uint4*)(Kls + r0 * 128 + so) = ka;
      *(uint4*)(Kls + (r0 + 32) * 128 + so) = kb2;
      *(uint4*)(Vls + r0 * 128 + so) = va;
      *(uint4*)(Vls + (r0 + 32) * 128 + so) = vb2;
      if (tid < 128) *(uint4*)(Vls + (r0 + 64) * 128 + so) = vc;
    }
    __syncthreads();
  }

  const int rowbase = (sp * 4 + h) * 69;
#pragma unroll
  for (int qs = 0; qs < 2; ++qs) {
    const int qg = qbase + w * 32 + qs * 16 + c;
#pragma unroll
    for (int dt = 0; dt < 5; ++dt)
#pragma unroll
      for (int r = 0; r < 4; ++r) {
        const int dv = dt * 16 + (g << 2) + r;
        if (dv < 67) Opart[(size_t)(rowbase + dv) * NN + qg] = Of[qs][dt][r];
      }
    if (g == 0) {
      Opart[(size_t)(rowbase + 67) * NN + qg] = mrun[qs];
      Opart[(size_t)(rowbase + 68) * NN + qg] = lrun[qs];
    }
  }
}

// ---------------- combine splits + augment, write Yt bf16 [NN][288] directly ----------------
// grid (64), block 256 = 4 h x 64 q
__global__ __launch_bounds__(256) void combine_t_kernel(
    const float* __restrict__ Opart, const float* __restrict__ coords0,
    unsigned short* __restrict__ Yt, int nsplit) {
  __shared__ __align__(16) unsigned char Yl[64 * 640];  // [64 q][320 ushort], XOR-swizzled
  const int t = threadIdx.x;
  const int q0 = blockIdx.x << 6;
  const int h = t >> 6, q = t & 63;
  const int qg = q0 + q;
  const int rowb = q * 640;
  const int sw = (q & 7) << 4;

  float m[8], wgt[8];
  float M = -1e30f;
  for (int s = 0; s < nsplit; ++s) {
    m[s] = Opart[((size_t)(s * 4 + h) * 69 + 67) * NN + qg];
    M = fmaxf(M, m[s]);
  }
  float L = 0.f;
  for (int s = 0; s < nsplit; ++s) {
    wgt[s] = __expf(m[s] - M);
    L += Opart[((size_t)(s * 4 + h) * 69 + 68) * NN + qg] * wgt[s];
  }
  const float invL = 1.f / L;

  if (h == 0) *(uint2*)(Yl + rowb + (568 ^ sw)) = make_uint2(0u, 0u);  // pad cols 284..287

  for (int dv = 0; dv < 64; ++dv) {
    float a = 0.f;
    for (int s = 0; s < nsplit; ++s)
      a += Opart[((size_t)(s * 4 + h) * 69 + dv) * NN + qg] * wgt[s];
    a *= invL;
    *(unsigned short*)(Yl + rowb + ((((dv << 2) + h) << 1) ^ sw)) = f2bf(a);
  }
  float ss = 0.f;
#pragma unroll
  for (int i = 0; i < 3; ++i) {
    const int dv = 64 + i;
    float a = 0.f;
    for (int s = 0; s < nsplit; ++s)
      a += Opart[((size_t)(s * 4 + h) * 69 + dv) * NN + qg] * wgt[s];
    a *= invL;
    *(unsigned short*)(Yl + rowb + ((((dv << 2) + h) << 1) ^ sw)) = f2bf(a);
    const float au = a - coords0[(size_t)i * NN + qg];
    *(unsigned short*)(Yl + rowb + (((((67 + i) << 2) + h) << 1) ^ sw)) = f2bf(au);
    ss += au * au;
  }
  *(unsigned short*)(Yl + rowb + ((((280 + h) << 1)) ^ sw)) = f2bf(sqrtf(ss));
  __syncthreads();

  for (int i = t; i < 64 * 36; i += 256) {
    const int row = i / 36, seg = i - row * 36;
    *(uint4*)(Yt + (size_t)(q0 + row) * 288 + (seg << 3)) =
        *(const uint4*)(Yl + row * 640 + ((seg << 4) ^ ((row & 7) << 4)));
  }
}

// ---------------- MFMA out projection: out = Wm(284x284) . y + bm ----------------
// grid (NN/128, 5), block 256 = 4 waves (2x2). BM=64, BN=128, BK=96, K=288.
#define OP_LOAD(k0_) do { \
  const int arow = co0 + ar; \
  _Pragma("unroll") for (int i = 0; i < 6; ++i) { \
    const int col = (k0_) + ac + 4 * i; \
    wa[i] = (arow < 284 && col < 284) ? *(const float4*)(Wm + (size_t)arow * 284 + col) \
                                      : make_float4(0.f, 0.f, 0.f, 0.f); \
  } \
  _Pragma("unroll") for (int i = 0; i < 6; ++i) \
    wb[i] = *(const uint4*)(Yt + (size_t)(n0 + bn) * 288 + (k0_) + bc + 8 * i); \
} while (0)

#define OP_WRITE_LDS() do { \
  unsigned pk[12]; \
  _Pragma("unroll") for (int i = 0; i < 6; ++i) { \
    pk[2 * i] = packpair(wa[i].x, wa[i].y); \
    pk[2 * i + 1] = packpair(wa[i].z, wa[i].w); \
  } \
  _Pragma("unroll") for (int i = 0; i < 3; ++i) \
    *(uint4*)(Al + ar * 256 + (((ac << 1) + (i << 4)) ^ aswz)) = *(uint4*)&pk[4 * i]; \
  _Pragma("unroll") for (int i = 0; i < 6; ++i) \
    *(uint4*)(Bl + bn * 256 + (((bc << 1) + (i << 4)) ^ bswz)) = wb[i]; \
} while (0)

__global__ __launch_bounds__(256) void outproj_gemm_kernel(
    const unsigned short* __restrict__ Yt, const float* __restrict__ Wm,
    const float* __restrict__ bm, float* __restrict__ out) {
  __shared__ __align__(16) unsigned char smem[49152];  // Al 64x256B | Bl 128x256B
  __shared__ float Bls[64];
  const int co0 = blockIdx.y << 6;
  const int n0 = blockIdx.x << 7;
  const int tid = threadIdx.x;
  const int w = tid >> 6, l = tid & 63;
  const int wm = w >> 1, wn = w & 1;
  const int c = l & 15, g = l >> 4;
  char* const Al = (char*)smem;
  char* const Bl = (char*)smem + 16384;

  if (tid < 64) { const int co = co0 + tid; Bls[tid] = (co < 284) ? bm[co] : 0.f; }

  const int ar = tid >> 2, ac = (tid & 3) * 24;
  const int bn = tid >> 1, bc = (tid & 1) * 48;
  const int aswz = (ar & 7) << 4;
  const int bswz = (bn & 7) << 4;

  float4 wa[6];
  uint4 wb[6];
  f32x4 acc[2][4];
#pragma unroll
  for (int mf = 0; mf < 2; ++mf)
#pragma unroll
    for (int nf = 0; nf < 4; ++nf) acc[mf][nf] = (f32x4){0.f, 0.f, 0.f, 0.f};

  OP_LOAD(0);
  OP_WRITE_LDS();
  __syncthreads();

  for (int s = 0; s < 3; ++s) {
    const bool hav = (s + 1 < 3);
    if (hav) OP_LOAD((s + 1) * 96);
    __builtin_amdgcn_s_setprio(1);
#pragma unroll
    for (int ks = 0; ks < 3; ++ks) {
      short8 af[2], bf[4];
#pragma unroll
      for (int mf = 0; mf < 2; ++mf) {
        const int row = wm * 32 + mf * 16 + c;
        af[mf] = *(const short8*)(Al + row * 256 + (((ks << 6) + (g << 4)) ^ ((row & 7) << 4)));
      }
#pragma unroll
      for (int nf = 0; nf < 4; ++nf) {
        const int row = wn * 64 + nf * 16 + c;
        bf[nf] = *(const short8*)(Bl + row * 256 + (((ks << 6) + (g << 4)) ^ ((row & 7) << 4)));
      }
#pragma unroll
      for (int mf = 0; mf < 2; ++mf)
#pragma unroll
        for (int nf = 0; nf < 4; ++nf)
          acc[mf][nf] = __builtin_amdgcn_mfma_f32_16x16x32_bf16(af[mf], bf[nf], acc[mf][nf], 0, 0, 0);
    }
    __builtin_amdgcn_s_setprio(0);
    __syncthreads();
    if (hav) {
      OP_WRITE_LDS();
      __syncthreads();
    }
  }

#pragma unroll
  for (int mf = 0; mf < 2; ++mf)
#pragma unroll
    for (int nf = 0; nf < 4; ++nf)
#pragma unroll
      for (int rr = 0; rr < 4; ++rr) {
        const int row = wm * 32 + mf * 16 + (g << 2) + rr;
        const int co = co0 + row;
        if (co < 284)
          out[(size_t)co * NN + n0 + wn * 64 + nf * 16 + c] = acc[mf][nf][rr] + Bls[row];
      }
}

extern "C" void kernel_launch(void* const* d_in, const int* in_sizes, int n_in,
                              void* d_out, int out_size, void* d_ws, size_t ws_size,
                              hipStream_t stream) {
  const float* query   = (const float*)d_in[0];
  const float* key_    = (const float*)d_in[1];
  const float* value   = (const float*)d_in[2];
  const float* coords0 = (const float*)d_in[3];
  const float* coords1 = (const float*)d_in[4];
  const float* Wq = (const float*)d_in[5];
  const float* bq = (const float*)d_in[6];
  const float* Wk = (const float*)d_in[7];
  const float* bk = (const float*)d_in[8];
  const float* Wv = (const float*)d_in[9];
  const float* bv = (const float*)d_in[10];
  const float* Wm = (const float*)d_in[11];
  const float* bm = (const float*)d_in[12];
  float* out = (float*)d_out;

  // ws: Qb 2MB | Kb 2MB | Vb 2.62MB | Xt 6MB | Yt 2.25MB | Opart nsplit*4.52MB
  unsigned short* Qb = (unsigned short*)d_ws;
  unsigned short* Kb = Qb + (size_t)4 * NN * 64;
  unsigned short* Vb = Kb + (size_t)4 * NN * 64;
  unsigned short* Xt = Vb + (size_t)4 * 80 * NN;
  unsigned short* Yt = Xt + (size_t)3 * NN * 256;
  float* Opart = (float*)(Yt + (size_t)NN * 288);

  const size_t fixedB = (size_t)((char*)Opart - (char*)d_ws);
  const size_t per = (size_t)4 * 69 * NN * 4;
  int nsplit = 8;
  while (nsplit > 1 && ws_size < fixedB + (size_t)nsplit * per) nsplit >>= 1;

  hipLaunchKernelGGL(transpose3_kernel, dim3(64, 4, 3), dim3(256), 0, stream,
                     query, key_, value, Xt, coords1, Vb);
  hipLaunchKernelGGL(proj_gemm_kernel, dim3(64, 4, 3), dim3(256), 0, stream,
                     Wq, bq, Wk, bk, Wv, bv, Xt, Qb, Kb, Vb);
  hipLaunchKernelGGL(attn_kernel, dim3(32, 4, nsplit), dim3(256), 0, stream,
                     Qb, Kb, Vb, Opart, NN / nsplit);
  hipLaunchKernelGGL(combine_t_kernel, dim3(64), dim3(256), 0, stream,
                     Opart, coords0, Yt, nsplit);
  hipLaunchKernelGGL(outproj_gemm_kernel, dim3(32, 5), dim3(256), 0, stream, Yt, Wm, bm, out);
}

// Round 6
// 130.760 us; speedup vs baseline: 1.8047x; 1.8047x over previous
//
#include <hip/hip_runtime.h>
#include <hip/hip_bf16.h>

#define NN 4096

typedef __attribute__((ext_vector_type(8))) short short8;
typedef __attribute__((ext_vector_type(4))) float f32x4;

__device__ __forceinline__ unsigned short f2bf(float f) {
  union { float f; unsigned u; } v; v.f = f;
  unsigned u = v.u;
  u += 0x7fffu + ((u >> 16) & 1u);
  return (unsigned short)(u >> 16);
}

__device__ __forceinline__ unsigned packpair(float a, float b) {
  __hip_bfloat162 h = __float22bfloat162_rn(make_float2(a, b));  // v_cvt_pk_bf16_f32
  union { __hip_bfloat162 h; unsigned u; } cv; cv.h = h;
  return cv.u;
}

// ---------------- transpose q/k/v: f32 [256][NN] -> bf16 [NN][256]; + coords fill ----------------
// grid (64, 4, 3), block 256
__global__ __launch_bounds__(256) void transpose3_kernel(
    const float* __restrict__ q, const float* __restrict__ k, const float* __restrict__ v,
    unsigned short* __restrict__ Xt, const float* __restrict__ coords1,
    unsigned short* __restrict__ Vb) {
  __shared__ float Tl[64][65];
  const float* X = (blockIdx.z == 0) ? q : (blockIdx.z == 1) ? k : v;
  unsigned short* dst = Xt + (size_t)blockIdx.z * NN * 256;
  const int n0 = blockIdx.x << 6, k0 = blockIdx.y << 6;
  const int t = threadIdx.x;
  const int r = t >> 4, c4 = (t & 15) << 2;
#pragma unroll
  for (int i = 0; i < 4; ++i) {
    const float4 vv = *(const float4*)(X + (size_t)(k0 + r + 16 * i) * NN + n0 + c4);
    Tl[r + 16 * i][c4] = vv.x; Tl[r + 16 * i][c4 + 1] = vv.y;
    Tl[r + 16 * i][c4 + 2] = vv.z; Tl[r + 16 * i][c4 + 3] = vv.w;
  }
  __syncthreads();
  const int kc = (t & 7) << 3;
#pragma unroll
  for (int j = 0; j < 2; ++j) {
    const int n = (t >> 3) + (j << 5);
    unsigned pk[4];
#pragma unroll
    for (int u = 0; u < 4; ++u)
      pk[u] = packpair(Tl[kc + 2 * u][n], Tl[kc + 2 * u + 1][n]);
    *(uint4*)(dst + (size_t)(n0 + n) * 256 + k0 + kc) = *(uint4*)pk;
  }
  // folded coords fill: V rows 64..66 = coords1, 67..79 = 0 (once per n-chunk)
  if (blockIdx.z == 2 && blockIdx.y == 0) {
    const int rr = t >> 2, seg = t & 3;
    const int h = rr >> 4, d = 64 + (rr & 15);
    unsigned short* vd = Vb + (size_t)(h * 80 + d) * NN + n0 + seg * 16;
    if (d < 67) {
      const float* src = coords1 + (size_t)(d - 64) * NN + n0 + seg * 16;
      unsigned u[8];
#pragma unroll
      for (int i = 0; i < 4; ++i) {
        const float4 cv = *(const float4*)(src + 4 * i);
        u[2 * i] = packpair(cv.x, cv.y);
        u[2 * i + 1] = packpair(cv.z, cv.w);
      }
      *(uint4*)vd = *(uint4*)&u[0];
      *(uint4*)(vd + 8) = *(uint4*)&u[4];
    } else {
      const uint4 zz = make_uint4(0u, 0u, 0u, 0u);
      *(uint4*)vd = zz;
      *(uint4*)(vd + 8) = zz;
    }
  }
}

// ---------------- MFMA projection GEMM: C = W(256x256) . X(256xNN) ----------------
// grid (NN/64, 4, 3), block 256 = 4 waves (2x2). BM=64, BN=64, BK=64.
__global__ __launch_bounds__(256) void proj_gemm_kernel(
    const float* __restrict__ Wq, const float* __restrict__ bq,
    const float* __restrict__ Wk, const float* __restrict__ bk,
    const float* __restrict__ Wv, const float* __restrict__ bv,
    const unsigned short* __restrict__ Xt,
    unsigned short* __restrict__ Qb, unsigned short* __restrict__ Kb,
    unsigned short* __restrict__ Vb) {
  __shared__ __align__(16) unsigned char smem[16384];  // Al 64x128B | Bl 64x128B
  __shared__ float Bls[64];
  const int z = blockIdx.z;
  const float* W  = (z == 0) ? Wq : (z == 1) ? Wk : Wv;
  const float* bb = (z == 0) ? bq : (z == 1) ? bk : bv;
  const unsigned short* Xz = Xt + (size_t)z * NN * 256;
  const int co0 = blockIdx.y << 6;
  const int n0 = blockIdx.x << 6;
  const int tid = threadIdx.x;
  const int w = tid >> 6, l = tid & 63;
  const int wm = w >> 1, wn = w & 1;
  const int c = l & 15, g = l >> 4;
  char* const Al = (char*)smem;
  char* const Bl = (char*)smem + 8192;

  if (tid < 64) Bls[tid] = bb[co0 + tid];

  const int ar = tid >> 2, ac = (tid & 3) << 4;  // A: 4 thr/row, 16 f32 each
  const int br = tid >> 3, bch = tid & 7;        // B: rows br, br+32
  const int aswz = (ar & 7) << 4;
  const int bswz = (br & 7) << 4;                // (br+32)&7 == br&7

  float4 wa[4];
  uint4 wb[2];
  f32x4 acc[2][2];
#pragma unroll
  for (int mf = 0; mf < 2; ++mf)
#pragma unroll
    for (int nf = 0; nf < 2; ++nf) acc[mf][nf] = (f32x4){0.f, 0.f, 0.f, 0.f};

#define PJ_LOAD(k0_) do { \
  _Pragma("unroll") for (int i = 0; i < 4; ++i) \
    wa[i] = *(const float4*)(W + (size_t)(co0 + ar) * 256 + (k0_) + ac + 4 * i); \
  wb[0] = *(const uint4*)(Xz + (size_t)(n0 + br) * 256 + (k0_) + bch * 8); \
  wb[1] = *(const uint4*)(Xz + (size_t)(n0 + br + 32) * 256 + (k0_) + bch * 8); \
} while (0)

#define PJ_STORE() do { \
  unsigned pk[8]; \
  _Pragma("unroll") for (int i = 0; i < 4; ++i) { \
    pk[2 * i] = packpair(wa[i].x, wa[i].y); \
    pk[2 * i + 1] = packpair(wa[i].z, wa[i].w); \
  } \
  *(uint4*)(Al + ar * 128 + (((ac << 1)) ^ aswz)) = *(uint4*)&pk[0]; \
  *(uint4*)(Al + ar * 128 + (((ac << 1) + 16) ^ aswz)) = *(uint4*)&pk[4]; \
  *(uint4*)(Bl + br * 128 + ((bch << 4) ^ bswz)) = wb[0]; \
  *(uint4*)(Bl + (br + 32) * 128 + ((bch << 4) ^ bswz)) = wb[1]; \
} while (0)

  PJ_LOAD(0);
  PJ_STORE();
  __syncthreads();

  for (int s = 0; s < 4; ++s) {
    const bool hav = (s + 1 < 4);
    if (hav) PJ_LOAD((s + 1) << 6);
    __builtin_amdgcn_s_setprio(1);
#pragma unroll
    for (int ks = 0; ks < 2; ++ks) {
      short8 af[2], bf[2];
#pragma unroll
      for (int mf = 0; mf < 2; ++mf) {
        const int row = wm * 32 + mf * 16 + c;
        af[mf] = *(const short8*)(Al + row * 128 + (((ks << 6) + (g << 4)) ^ ((row & 7) << 4)));
      }
#pragma unroll
      for (int nf = 0; nf < 2; ++nf) {
        const int row = wn * 32 + nf * 16 + c;
        bf[nf] = *(const short8*)(Bl + row * 128 + (((ks << 6) + (g << 4)) ^ ((row & 7) << 4)));
      }
#pragma unroll
      for (int mf = 0; mf < 2; ++mf)
#pragma unroll
        for (int nf = 0; nf < 2; ++nf)
          acc[mf][nf] = __builtin_amdgcn_mfma_f32_16x16x32_bf16(af[mf], bf[nf], acc[mf][nf], 0, 0, 0);
    }
    __builtin_amdgcn_s_setprio(0);
    __syncthreads();
    if (hav) {
      PJ_STORE();
      __syncthreads();
    }
  }

  // epilogue: acc -> LDS bounce (bf16, stride 72) -> layout-specific global writes
  unsigned short* Clu = (unsigned short*)smem;  // [64][72]
  const float scale = (z == 0) ? 0.125f : 1.0f;
#pragma unroll
  for (int mf = 0; mf < 2; ++mf)
#pragma unroll
    for (int nf = 0; nf < 2; ++nf)
#pragma unroll
      for (int rr = 0; rr < 4; ++rr) {
        const int row = wm * 32 + mf * 16 + (g << 2) + rr;
        const int col = wn * 32 + nf * 16 + c;
        Clu[row * 72 + col] = f2bf((acc[mf][nf][rr] + Bls[row]) * scale);
      }
  __syncthreads();
  if (z <= 1) {
    unsigned short* Ob = (z == 0) ? Qb : Kb;
    const int d0 = co0 >> 2;
    const int h = tid >> 6, n = tid & 63;
    unsigned u[8];
#pragma unroll
    for (int p = 0; p < 8; ++p)
      u[p] = (unsigned)Clu[((p << 3) + h) * 72 + n] |
             ((unsigned)Clu[((p << 3) + 4 + h) * 72 + n] << 16);
    uint4* dd = (uint4*)(Ob + ((size_t)h * NN + n0 + n) * 64 + d0);
    dd[0] = *(uint4*)&u[0];
    dd[1] = *(uint4*)&u[4];
  } else {
    const int rl = tid >> 2, seg = (tid & 3) << 4;
    const int h = rl & 3, d = (co0 >> 2) + (rl >> 2);
    unsigned short* vd = Vb + (size_t)(h * 80 + d) * NN + n0 + seg;
    *(uint4*)vd = *(const uint4*)((char*)Clu + rl * 144 + (seg << 1));
    *(uint4*)(vd + 8) = *(const uint4*)((char*)Clu + rl * 144 + (seg << 1) + 16);
  }
}

// ---------------- fused flash attention (split-K, swapped-S^T, async stage, defer-max) ----------------
// grid (32, 4, nsplit): x = q-tile of 128, y = head, z = key-split.
__global__ __launch_bounds__(256) void attn_kernel(
    const unsigned short* __restrict__ Qb, const unsigned short* __restrict__ Kb,
    const unsigned short* __restrict__ Vb, float* __restrict__ Opart, int chunkKeys) {
  __shared__ __align__(16) unsigned char smem[34816];  // K 8192 | Vt 10240 | P 4x4096
  const int h = blockIdx.y;
  const int sp = blockIdx.z;
  const int qbase = blockIdx.x * 128;
  const int tid = threadIdx.x;
  const int w = tid >> 6;
  const int l = tid & 63;
  const int c = l & 15;
  const int g = l >> 4;
  const int swc = (c & 7) << 4;

  char* const Kls = (char*)smem;
  char* const Vls = (char*)smem + 8192;
  char* const Pls = (char*)smem + 18432 + w * 4096;

  short8 qf[2][2];
#pragma unroll
  for (int qs = 0; qs < 2; ++qs) {
    const unsigned short* qsrc = Qb + (((h * NN) + qbase + w * 32 + qs * 16 + c) << 6) + (g << 3);
    qf[qs][0] = *(const short8*)qsrc;
    qf[qs][1] = *(const short8*)(qsrc + 32);
  }

  f32x4 Of[2][5];
#pragma unroll
  for (int qs = 0; qs < 2; ++qs)
#pragma unroll
    for (int dt = 0; dt < 5; ++dt) Of[qs][dt] = (f32x4){0.f, 0.f, 0.f, 0.f};
  float mrun[2] = {-1e30f, -1e30f};
  float lrun[2] = {0.f, 0.f};

  const int r0 = tid >> 3, ch = tid & 7;
  const int so = (ch << 4) ^ ((r0 & 7) << 4);
  const int mStart = sp * chunkKeys;
  const int niter = chunkKeys >> 6;

  {
    const unsigned short* kbase = Kb + ((h * NN + mStart) << 6);
    const unsigned short* vbase = Vb + (size_t)(h * 80) * NN + mStart;
    const uint4 ka  = *(const uint4*)(kbase + (r0 << 6) + (ch << 3));
    const uint4 kb2 = *(const uint4*)(kbase + ((r0 + 32) << 6) + (ch << 3));
    const uint4 va  = *(const uint4*)(vbase + (size_t)r0 * NN + (ch << 3));
    const uint4 vb2 = *(const uint4*)(vbase + (size_t)(r0 + 32) * NN + (ch << 3));
    *(uint4*)(Kls + r0 * 128 + so) = ka;
    *(uint4*)(Kls + (r0 + 32) * 128 + so) = kb2;
    *(uint4*)(Vls + r0 * 128 + so) = va;
    *(uint4*)(Vls + (r0 + 32) * 128 + so) = vb2;
    if (tid < 128) {
      const uint4 vc = *(const uint4*)(vbase + (size_t)(r0 + 64) * NN + (ch << 3));
      *(uint4*)(Vls + (r0 + 64) * 128 + so) = vc;
    }
  }
  __syncthreads();

  for (int it = 0; it < niter; ++it) {
    uint4 ka, kb2, va, vb2, vc;
    const bool hav = (it + 1 < niter);
    if (hav) {
      const int m0 = mStart + ((it + 1) << 6);
      const unsigned short* kbase = Kb + ((h * NN + m0) << 6);
      const unsigned short* vbase = Vb + (size_t)(h * 80) * NN + m0;
      ka  = *(const uint4*)(kbase + (r0 << 6) + (ch << 3));
      kb2 = *(const uint4*)(kbase + ((r0 + 32) << 6) + (ch << 3));
      va  = *(const uint4*)(vbase + (size_t)r0 * NN + (ch << 3));
      vb2 = *(const uint4*)(vbase + (size_t)(r0 + 32) * NN + (ch << 3));
      if (tid < 128) vc = *(const uint4*)(vbase + (size_t)(r0 + 64) * NN + (ch << 3));
    }

    f32x4 sD[2][4];
    __builtin_amdgcn_s_setprio(1);
#pragma unroll
    for (int t = 0; t < 4; ++t) {
      const char* rp = Kls + (t * 16 + c) * 128;
      const short8 ka0 = *(const short8*)(rp + ((g << 4) ^ swc));
      const short8 ka1 = *(const short8*)(rp + ((64 + (g << 4)) ^ swc));
#pragma unroll
      for (int qs = 0; qs < 2; ++qs) {
        f32x4 a = (f32x4){0.f, 0.f, 0.f, 0.f};
        a = __builtin_amdgcn_mfma_f32_16x16x32_bf16(ka0, qf[qs][0], a, 0, 0, 0);
        a = __builtin_amdgcn_mfma_f32_16x16x32_bf16(ka1, qf[qs][1], a, 0, 0, 0);
        sD[qs][t] = a;
      }
    }
    __builtin_amdgcn_s_setprio(0);

#pragma unroll
    for (int qs = 0; qs < 2; ++qs) {
      float m01 = fmaxf(fmaxf(sD[qs][0][0], sD[qs][0][1]), fmaxf(sD[qs][0][2], sD[qs][0][3]));
      float m11 = fmaxf(fmaxf(sD[qs][1][0], sD[qs][1][1]), fmaxf(sD[qs][1][2], sD[qs][1][3]));
      float m21 = fmaxf(fmaxf(sD[qs][2][0], sD[qs][2][1]), fmaxf(sD[qs][2][2], sD[qs][2][3]));
      float m31 = fmaxf(fmaxf(sD[qs][3][0], sD[qs][3][1]), fmaxf(sD[qs][3][2], sD[qs][3][3]));
      float mx = fmaxf(fmaxf(m01, m11), fmaxf(m21, m31));
      mx = fmaxf(mx, __shfl_xor(mx, 16));
      mx = fmaxf(mx, __shfl_xor(mx, 32));
      // T13 defer-max: skip rescale when tile max within THR=8 of running max
      if (!__all(mx - mrun[qs] <= 8.f)) {
        const float mnew = fmaxf(mrun[qs], mx);
        const float a = __expf(mrun[qs] - mnew);
        mrun[qs] = mnew;
        lrun[qs] *= a;
#pragma unroll
        for (int dt = 0; dt < 5; ++dt)
#pragma unroll
          for (int r = 0; r < 4; ++r) Of[qs][dt][r] *= a;
      }
      const float mm = mrun[qs];
      float rs = 0.f;
      unsigned pk[8];
#pragma unroll
      for (int t = 0; t < 4; ++t) {
        const float e0 = __expf(sD[qs][t][0] - mm);
        const float e1 = __expf(sD[qs][t][1] - mm);
        const float e2 = __expf(sD[qs][t][2] - mm);
        const float e3 = __expf(sD[qs][t][3] - mm);
        rs += (e0 + e1) + (e2 + e3);
        pk[t * 2]     = packpair(e0, e1);
        pk[t * 2 + 1] = packpair(e2, e3);
      }
      rs += __shfl_xor(rs, 16);
      rs += __shfl_xor(rs, 32);
      lrun[qs] += rs;
      char* prow = Pls + (qs * 16 + c) * 128;
#pragma unroll
      for (int t = 0; t < 4; ++t)
        *(uint2*)(prow + ((t * 32 + (g << 3)) ^ swc)) = make_uint2(pk[t * 2], pk[t * 2 + 1]);
    }

    short8 pb[2][2];
#pragma unroll
    for (int qs = 0; qs < 2; ++qs) {
      const char* prow = Pls + (qs * 16 + c) * 128;
      pb[qs][0] = *(const short8*)(prow + ((g << 4) ^ swc));
      pb[qs][1] = *(const short8*)(prow + ((64 + (g << 4)) ^ swc));
    }
    __builtin_amdgcn_s_setprio(1);
#pragma unroll
    for (int dt = 0; dt < 5; ++dt) {
      const char* vp = Vls + (dt * 16 + c) * 128;
      const short8 va0 = *(const short8*)(vp + ((g << 4) ^ swc));
      const short8 va1 = *(const short8*)(vp + ((64 + (g << 4)) ^ swc));
#pragma unroll
      for (int qs = 0; qs < 2; ++qs) {
        Of[qs][dt] = __builtin_amdgcn_mfma_f32_16x16x32_bf16(va0, pb[qs][0], Of[qs][dt], 0, 0, 0);
        Of[qs][dt] = __builtin_amdgcn_mfma_f32_16x16x32_bf16(va1, pb[qs][1], Of[qs][dt], 0, 0, 0);
      }
    }
    __builtin_amdgcn_s_setprio(0);

    __syncthreads();
    if (hav) {
      *(uint4*)(Kls + r0 * 128 + so) = ka;
      *(uint4*)(Kls + (r0 + 32) * 128 + so) = kb2;
      *(uint4*)(Vls + r0 * 128 + so) = va;
      *(uint4*)(Vls + (r0 + 32) * 128 + so) = vb2;
      if (tid < 128) *(uint4*)(Vls + (r0 + 64) * 128 + so) = vc;
    }
    __syncthreads();
  }

  const int rowbase = (sp * 4 + h) * 69;
#pragma unroll
  for (int qs = 0; qs < 2; ++qs) {
    const int qg = qbase + w * 32 + qs * 16 + c;
#pragma unroll
    for (int dt = 0; dt < 5; ++dt)
#pragma unroll
      for (int r = 0; r < 4; ++r) {
        const int dv = dt * 16 + (g << 2) + r;
        if (dv < 67) Opart[(size_t)(rowbase + dv) * NN + qg] = Of[qs][dt][r];
      }
    if (g == 0) {
      Opart[(size_t)(rowbase + 67) * NN + qg] = mrun[qs];
      Opart[(size_t)(rowbase + 68) * NN + qg] = lrun[qs];
    }
  }
}

// ---------------- combine splits + augment, write Yt bf16 [NN][288] directly ----------------
// grid (256), block 256: q-chunk of 16; workers = 4 h x 4 dv-groups.
// Wave w = dv-group w over all 4 heads; lanes 0-15 = consecutive q (64B-coalesced per h).
__global__ __launch_bounds__(256) void combine_t_kernel(
    const float* __restrict__ Opart, const float* __restrict__ coords0,
    unsigned short* __restrict__ Yt, int nsplit) {
  __shared__ __align__(16) unsigned char Yl[16 * 640];  // [16 q][320 ushort], XOR-swizzled
  const int t = threadIdx.x;
  const int q = t & 15;
  const int worker = t >> 4;       // 0..15
  const int h = worker & 3;
  const int dgrp = worker >> 2;    // 0..3
  const int q0 = blockIdx.x << 4;
  const int qg = q0 + q;
  const int rowb = q * 640;
  const int sw = (q & 7) << 4;

  float m[8], wgt[8];
  float M = -1e30f;
  for (int s = 0; s < nsplit; ++s) {
    m[s] = Opart[((size_t)(s * 4 + h) * 69 + 67) * NN + qg];
    M = fmaxf(M, m[s]);
  }
  float L = 0.f;
  for (int s = 0; s < nsplit; ++s) {
    wgt[s] = __expf(m[s] - M);
    L += Opart[((size_t)(s * 4 + h) * 69 + 68) * NN + qg] * wgt[s];
  }
  const float invL = 1.f / L;

  if (worker == 0) *(uint2*)(Yl + rowb + (568 ^ sw)) = make_uint2(0u, 0u);  // pad cols 284..287

  const int dv0 = dgrp * 17;
  const int dv1 = (dgrp == 3) ? 67 : dv0 + 17;
  float ss = 0.f;
  for (int dv = dv0; dv < dv1; ++dv) {
    float a = 0.f;
    for (int s = 0; s < nsplit; ++s)
      a += Opart[((size_t)(s * 4 + h) * 69 + dv) * NN + qg] * wgt[s];
    a *= invL;
    *(unsigned short*)(Yl + rowb + ((((dv << 2) + h) << 1) ^ sw)) = f2bf(a);
    if (dv >= 64) {
      const float au = a - coords0[(size_t)(dv - 64) * NN + qg];
      *(unsigned short*)(Yl + rowb + (((((dv + 3) << 2) + h) << 1) ^ sw)) = f2bf(au);
      ss += au * au;
    }
  }
  if (dgrp == 3) *(unsigned short*)(Yl + rowb + (((280 + h) << 1) ^ sw)) = f2bf(sqrtf(ss));
  __syncthreads();

  // cooperative swizzle-undo copy: 16 rows x 36 uint4 segs = 576 over 256 threads
  for (int i = t; i < 16 * 36; i += 256) {
    const int row = i / 36, seg = i - row * 36;
    *(uint4*)(Yt + (size_t)(q0 + row) * 288 + (seg << 3)) =
        *(const uint4*)(Yl + row * 640 + ((seg << 4) ^ ((row & 7) << 4)));
  }
}

// ---------------- MFMA out projection: out = Wm(284x284) . y + bm ----------------
// grid (NN/128, 5), block 256 = 4 waves (2x2). BM=64, BN=128, BK=96, K=288.
#define OP_LOAD(k0_) do { \
  const int arow = co0 + ar; \
  _Pragma("unroll") for (int i = 0; i < 6; ++i) { \
    const int col = (k0_) + ac + 4 * i; \
    wa[i] = (arow < 284 && col < 284) ? *(const float4*)(Wm + (size_t)arow * 284 + col) \
                                      : make_float4(0.f, 0.f, 0.f, 0.f); \
  } \
  _Pragma("unroll") for (int i = 0; i < 6; ++i) \
    wb[i] = *(const uint4*)(Yt + (size_t)(n0 + bn) * 288 + (k0_) + bc + 8 * i); \
} while (0)

#define OP_WRITE_LDS() do { \
  unsigned pk[12]; \
  _Pragma("unroll") for (int i = 0; i < 6; ++i) { \
    pk[2 * i] = packpair(wa[i].x, wa[i].y); \
    pk[2 * i + 1] = packpair(wa[i].z, wa[i].w); \
  } \
  _Pragma("unroll") for (int i = 0; i < 3; ++i) \
    *(uint4*)(Al + ar * 256 + (((ac << 1) + (i << 4)) ^ aswz)) = *(uint4*)&pk[4 * i]; \
  _Pragma("unroll") for (int i = 0; i < 6; ++i) \
    *(uint4*)(Bl + bn * 256 + (((bc << 1) + (i << 4)) ^ bswz)) = wb[i]; \
} while (0)

__global__ __launch_bounds__(256) void outproj_gemm_kernel(
    const unsigned short* __restrict__ Yt, const float* __restrict__ Wm,
    const float* __restrict__ bm, float* __restrict__ out) {
  __shared__ __align__(16) unsigned char smem[49152];  // Al 64x256B | Bl 128x256B
  __shared__ float Bls[64];
  const int co0 = blockIdx.y << 6;
  const int n0 = blockIdx.x << 7;
  const int tid = threadIdx.x;
  const int w = tid >> 6, l = tid & 63;
  const int wm = w >> 1, wn = w & 1;
  const int c = l & 15, g = l >> 4;
  char* const Al = (char*)smem;
  char* const Bl = (char*)smem + 16384;

  if (tid < 64) { const int co = co0 + tid; Bls[tid] = (co < 284) ? bm[co] : 0.f; }

  const int ar = tid >> 2, ac = (tid & 3) * 24;
  const int bn = tid >> 1, bc = (tid & 1) * 48;
  const int aswz = (ar & 7) << 4;
  const int bswz = (bn & 7) << 4;

  float4 wa[6];
  uint4 wb[6];
  f32x4 acc[2][4];
#pragma unroll
  for (int mf = 0; mf < 2; ++mf)
#pragma unroll
    for (int nf = 0; nf < 4; ++nf) acc[mf][nf] = (f32x4){0.f, 0.f, 0.f, 0.f};

  OP_LOAD(0);
  OP_WRITE_LDS();
  __syncthreads();

  for (int s = 0; s < 3; ++s) {
    const bool hav = (s + 1 < 3);
    if (hav) OP_LOAD((s + 1) * 96);
    __builtin_amdgcn_s_setprio(1);
#pragma unroll
    for (int ks = 0; ks < 3; ++ks) {
      short8 af[2], bf[4];
#pragma unroll
      for (int mf = 0; mf < 2; ++mf) {
        const int row = wm * 32 + mf * 16 + c;
        af[mf] = *(const short8*)(Al + row * 256 + (((ks << 6) + (g << 4)) ^ ((row & 7) << 4)));
      }
#pragma unroll
      for (int nf = 0; nf < 4; ++nf) {
        const int row = wn * 64 + nf * 16 + c;
        bf[nf] = *(const short8*)(Bl + row * 256 + (((ks << 6) + (g << 4)) ^ ((row & 7) << 4)));
      }
#pragma unroll
      for (int mf = 0; mf < 2; ++mf)
#pragma unroll
        for (int nf = 0; nf < 4; ++nf)
          acc[mf][nf] = __builtin_amdgcn_mfma_f32_16x16x32_bf16(af[mf], bf[nf], acc[mf][nf], 0, 0, 0);
    }
    __builtin_amdgcn_s_setprio(0);
    __syncthreads();
    if (hav) {
      OP_WRITE_LDS();
      __syncthreads();
    }
  }

#pragma unroll
  for (int mf = 0; mf < 2; ++mf)
#pragma unroll
    for (int nf = 0; nf < 4; ++nf)
#pragma unroll
      for (int rr = 0; rr < 4; ++rr) {
        const int row = wm * 32 + mf * 16 + (g << 2) + rr;
        const int co = co0 + row;
        if (co < 284)
          out[(size_t)co * NN + n0 + wn * 64 + nf * 16 + c] = acc[mf][nf][rr] + Bls[row];
      }
}

extern "C" void kernel_launch(void* const* d_in, const int* in_sizes, int n_in,
                              void* d_out, int out_size, void* d_ws, size_t ws_size,
                              hipStream_t stream) {
  const float* query   = (const float*)d_in[0];
  const float* key_    = (const float*)d_in[1];
  const float* value   = (const float*)d_in[2];
  const float* coords0 = (const float*)d_in[3];
  const float* coords1 = (const float*)d_in[4];
  const float* Wq = (const float*)d_in[5];
  const float* bq = (const float*)d_in[6];
  const float* Wk = (const float*)d_in[7];
  const float* bk = (const float*)d_in[8];
  const float* Wv = (const float*)d_in[9];
  const float* bv = (const float*)d_in[10];
  const float* Wm = (const float*)d_in[11];
  const float* bm = (const float*)d_in[12];
  float* out = (float*)d_out;

  // ws: Qb 2MB | Kb 2MB | Vb 2.62MB | Xt 6MB | Yt 2.25MB | Opart nsplit*4.52MB
  unsigned short* Qb = (unsigned short*)d_ws;
  unsigned short* Kb = Qb + (size_t)4 * NN * 64;
  unsigned short* Vb = Kb + (size_t)4 * NN * 64;
  unsigned short* Xt = Vb + (size_t)4 * 80 * NN;
  unsigned short* Yt = Xt + (size_t)3 * NN * 256;
  float* Opart = (float*)(Yt + (size_t)NN * 288);

  const size_t fixedB = (size_t)((char*)Opart - (char*)d_ws);
  const size_t per = (size_t)4 * 69 * NN * 4;
  int nsplit = 8;
  while (nsplit > 1 && ws_size < fixedB + (size_t)nsplit * per) nsplit >>= 1;

  hipLaunchKernelGGL(transpose3_kernel, dim3(64, 4, 3), dim3(256), 0, stream,
                     query, key_, value, Xt, coords1, Vb);
  hipLaunchKernelGGL(proj_gemm_kernel, dim3(64, 4, 3), dim3(256), 0, stream,
                     Wq, bq, Wk, bk, Wv, bv, Xt, Qb, Kb, Vb);
  hipLaunchKernelGGL(attn_kernel, dim3(32, 4, nsplit), dim3(256), 0, stream,
                     Qb, Kb, Vb, Opart, NN / nsplit);
  hipLaunchKernelGGL(combine_t_kernel, dim3(256), dim3(256), 0, stream,
                     Opart, coords0, Yt, nsplit);
  hipLaunchKernelGGL(outproj_gemm_kernel, dim3(32, 5), dim3(256), 0, stream, Yt, Wm, bm, out);
}

// Round 8
// 93.471 us; speedup vs baseline: 2.5247x; 1.3989x over previous
//
#include <hip/hip_runtime.h>
#include <hip/hip_bf16.h>

#define NN 4096

typedef __attribute__((ext_vector_type(8))) short short8;
typedef __attribute__((ext_vector_type(4))) float f32x4;

__device__ __forceinline__ unsigned short f2bf(float f) {
  union { float f; unsigned u; } v; v.f = f;
  unsigned u = v.u;
  u += 0x7fffu + ((u >> 16) & 1u);
  return (unsigned short)(u >> 16);
}

__device__ __forceinline__ unsigned packpair(float a, float b) {
  __hip_bfloat162 h = __float22bfloat162_rn(make_float2(a, b));  // v_cvt_pk_bf16_f32
  union { __hip_bfloat162 h; unsigned u; } cv; cv.h = h;
  return cv.u;
}

// ---------------- transpose q/k/v: f32 [256][NN] -> bf16 [NN][256]; + coords fill ----------------
// grid (64, 4, 3), block 256
__global__ __launch_bounds__(256) void transpose3_kernel(
    const float* __restrict__ q, const float* __restrict__ k, const float* __restrict__ v,
    unsigned short* __restrict__ Xt, const float* __restrict__ coords1,
    unsigned short* __restrict__ Vb) {
  __shared__ float Tl[64][65];
  const float* X = (blockIdx.z == 0) ? q : (blockIdx.z == 1) ? k : v;
  unsigned short* dst = Xt + (size_t)blockIdx.z * NN * 256;
  const int n0 = blockIdx.x << 6, k0 = blockIdx.y << 6;
  const int t = threadIdx.x;
  const int r = t >> 4, c4 = (t & 15) << 2;
#pragma unroll
  for (int i = 0; i < 4; ++i) {
    const float4 vv = *(const float4*)(X + (size_t)(k0 + r + 16 * i) * NN + n0 + c4);
    Tl[r + 16 * i][c4] = vv.x; Tl[r + 16 * i][c4 + 1] = vv.y;
    Tl[r + 16 * i][c4 + 2] = vv.z; Tl[r + 16 * i][c4 + 3] = vv.w;
  }
  __syncthreads();
  const int kc = (t & 7) << 3;
#pragma unroll
  for (int j = 0; j < 2; ++j) {
    const int n = (t >> 3) + (j << 5);
    unsigned pk[4];
#pragma unroll
    for (int u = 0; u < 4; ++u)
      pk[u] = packpair(Tl[kc + 2 * u][n], Tl[kc + 2 * u + 1][n]);
    *(uint4*)(dst + (size_t)(n0 + n) * 256 + k0 + kc) = *(uint4*)pk;
  }
  // folded coords fill: V rows 64..66 = coords1, 67..79 = 0 (once per n-chunk)
  if (blockIdx.z == 2 && blockIdx.y == 0) {
    const int rr = t >> 2, seg = t & 3;
    const int h = rr >> 4, d = 64 + (rr & 15);
    unsigned short* vd = Vb + (size_t)(h * 80 + d) * NN + n0 + seg * 16;
    if (d < 67) {
      const float* src = coords1 + (size_t)(d - 64) * NN + n0 + seg * 16;
      unsigned u[8];
#pragma unroll
      for (int i = 0; i < 4; ++i) {
        const float4 cv = *(const float4*)(src + 4 * i);
        u[2 * i] = packpair(cv.x, cv.y);
        u[2 * i + 1] = packpair(cv.z, cv.w);
      }
      *(uint4*)vd = *(uint4*)&u[0];
      *(uint4*)(vd + 8) = *(uint4*)&u[4];
    } else {
      const uint4 zz = make_uint4(0u, 0u, 0u, 0u);
      *(uint4*)vd = zz;
      *(uint4*)(vd + 8) = zz;
    }
  }
}

// ---------------- MFMA projection GEMM: C = W(256x256) . X(256xNN) ----------------
// grid (NN/64, 4, 3), block 256 = 4 waves (2x2). BM=64, BN=64, BK=64.
__global__ __launch_bounds__(256) void proj_gemm_kernel(
    const float* __restrict__ Wq, const float* __restrict__ bq,
    const float* __restrict__ Wk, const float* __restrict__ bk,
    const float* __restrict__ Wv, const float* __restrict__ bv,
    const unsigned short* __restrict__ Xt,
    unsigned short* __restrict__ Qb, unsigned short* __restrict__ Kb,
    unsigned short* __restrict__ Vb) {
  __shared__ __align__(16) unsigned char smem[16384];  // Al 64x128B | Bl 64x128B
  __shared__ float Bls[64];
  const int z = blockIdx.z;
  const float* W  = (z == 0) ? Wq : (z == 1) ? Wk : Wv;
  const float* bb = (z == 0) ? bq : (z == 1) ? bk : bv;
  const unsigned short* Xz = Xt + (size_t)z * NN * 256;
  const int co0 = blockIdx.y << 6;
  const int n0 = blockIdx.x << 6;
  const int tid = threadIdx.x;
  const int w = tid >> 6, l = tid & 63;
  const int wm = w >> 1, wn = w & 1;
  const int c = l & 15, g = l >> 4;
  char* const Al = (char*)smem;
  char* const Bl = (char*)smem + 8192;

  if (tid < 64) Bls[tid] = bb[co0 + tid];

  const int ar = tid >> 2, ac = (tid & 3) << 4;  // A: 4 thr/row, 16 f32 each
  const int br = tid >> 3, bch = tid & 7;        // B: rows br, br+32
  const int aswz = (ar & 7) << 4;
  const int bswz = (br & 7) << 4;                // (br+32)&7 == br&7

  float4 wa[4];
  uint4 wb[2];
  f32x4 acc[2][2];
#pragma unroll
  for (int mf = 0; mf < 2; ++mf)
#pragma unroll
    for (int nf = 0; nf < 2; ++nf) acc[mf][nf] = (f32x4){0.f, 0.f, 0.f, 0.f};

#define PJ_LOAD(k0_) do { \
  _Pragma("unroll") for (int i = 0; i < 4; ++i) \
    wa[i] = *(const float4*)(W + (size_t)(co0 + ar) * 256 + (k0_) + ac + 4 * i); \
  wb[0] = *(const uint4*)(Xz + (size_t)(n0 + br) * 256 + (k0_) + bch * 8); \
  wb[1] = *(const uint4*)(Xz + (size_t)(n0 + br + 32) * 256 + (k0_) + bch * 8); \
} while (0)

#define PJ_STORE() do { \
  unsigned pk[8]; \
  _Pragma("unroll") for (int i = 0; i < 4; ++i) { \
    pk[2 * i] = packpair(wa[i].x, wa[i].y); \
    pk[2 * i + 1] = packpair(wa[i].z, wa[i].w); \
  } \
  *(uint4*)(Al + ar * 128 + (((ac << 1)) ^ aswz)) = *(uint4*)&pk[0]; \
  *(uint4*)(Al + ar * 128 + (((ac << 1) + 16) ^ aswz)) = *(uint4*)&pk[4]; \
  *(uint4*)(Bl + br * 128 + ((bch << 4) ^ bswz)) = wb[0]; \
  *(uint4*)(Bl + (br + 32) * 128 + ((bch << 4) ^ bswz)) = wb[1]; \
} while (0)

  PJ_LOAD(0);
  PJ_STORE();
  __syncthreads();

  for (int s = 0; s < 4; ++s) {
    const bool hav = (s + 1 < 4);
    if (hav) PJ_LOAD((s + 1) << 6);
    __builtin_amdgcn_s_setprio(1);
#pragma unroll
    for (int ks = 0; ks < 2; ++ks) {
      short8 af[2], bf[2];
#pragma unroll
      for (int mf = 0; mf < 2; ++mf) {
        const int row = wm * 32 + mf * 16 + c;
        af[mf] = *(const short8*)(Al + row * 128 + (((ks << 6) + (g << 4)) ^ ((row & 7) << 4)));
      }
#pragma unroll
      for (int nf = 0; nf < 2; ++nf) {
        const int row = wn * 32 + nf * 16 + c;
        bf[nf] = *(const short8*)(Bl + row * 128 + (((ks << 6) + (g << 4)) ^ ((row & 7) << 4)));
      }
#pragma unroll
      for (int mf = 0; mf < 2; ++mf)
#pragma unroll
        for (int nf = 0; nf < 2; ++nf)
          acc[mf][nf] = __builtin_amdgcn_mfma_f32_16x16x32_bf16(af[mf], bf[nf], acc[mf][nf], 0, 0, 0);
    }
    __builtin_amdgcn_s_setprio(0);
    __syncthreads();
    if (hav) {
      PJ_STORE();
      __syncthreads();
    }
  }

  // epilogue: acc -> LDS bounce (bf16, stride 72) -> layout-specific global writes
  unsigned short* Clu = (unsigned short*)smem;  // [64][72]
  const float scale = (z == 0) ? 0.125f : 1.0f;
#pragma unroll
  for (int mf = 0; mf < 2; ++mf)
#pragma unroll
    for (int nf = 0; nf < 2; ++nf)
#pragma unroll
      for (int rr = 0; rr < 4; ++rr) {
        const int row = wm * 32 + mf * 16 + (g << 2) + rr;
        const int col = wn * 32 + nf * 16 + c;
        Clu[row * 72 + col] = f2bf((acc[mf][nf][rr] + Bls[row]) * scale);
      }
  __syncthreads();
  if (z <= 1) {
    unsigned short* Ob = (z == 0) ? Qb : Kb;
    const int d0 = co0 >> 2;
    const int h = tid >> 6, n = tid & 63;
    unsigned u[8];
#pragma unroll
    for (int p = 0; p < 8; ++p)
      u[p] = (unsigned)Clu[((p << 3) + h) * 72 + n] |
             ((unsigned)Clu[((p << 3) + 4 + h) * 72 + n] << 16);
    uint4* dd = (uint4*)(Ob + ((size_t)h * NN + n0 + n) * 64 + d0);
    dd[0] = *(uint4*)&u[0];
    dd[1] = *(uint4*)&u[4];
  } else {
    const int rl = tid >> 2, seg = (tid & 3) << 4;
    const int h = rl & 3, d = (co0 >> 2) + (rl >> 2);
    unsigned short* vd = Vb + (size_t)(h * 80 + d) * NN + n0 + seg;
    *(uint4*)vd = *(const uint4*)((char*)Clu + rl * 144 + (seg << 1));
    *(uint4*)(vd + 8) = *(const uint4*)((char*)Clu + rl * 144 + (seg << 1) + 16);
  }
}

// ---------------- fused flash attention (split-K, swapped-S^T, async stage, defer-max) ----------------
// grid (32, 4, nsplit): x = q-tile of 128, y = head, z = key-split.
__global__ __launch_bounds__(256) void attn_kernel(
    const unsigned short* __restrict__ Qb, const unsigned short* __restrict__ Kb,
    const unsigned short* __restrict__ Vb, float* __restrict__ Opart, int chunkKeys) {
  __shared__ __align__(16) unsigned char smem[34816];  // K 8192 | Vt 10240 | P 4x4096
  const int h = blockIdx.y;
  const int sp = blockIdx.z;
  const int qbase = blockIdx.x * 128;
  const int tid = threadIdx.x;
  const int w = tid >> 6;
  const int l = tid & 63;
  const int c = l & 15;
  const int g = l >> 4;
  const int swc = (c & 7) << 4;

  char* const Kls = (char*)smem;
  char* const Vls = (char*)smem + 8192;
  char* const Pls = (char*)smem + 18432 + w * 4096;

  short8 qf[2][2];
#pragma unroll
  for (int qs = 0; qs < 2; ++qs) {
    const unsigned short* qsrc = Qb + (((h * NN) + qbase + w * 32 + qs * 16 + c) << 6) + (g << 3);
    qf[qs][0] = *(const short8*)qsrc;
    qf[qs][1] = *(const short8*)(qsrc + 32);
  }

  f32x4 Of[2][5];
#pragma unroll
  for (int qs = 0; qs < 2; ++qs)
#pragma unroll
    for (int dt = 0; dt < 5; ++dt) Of[qs][dt] = (f32x4){0.f, 0.f, 0.f, 0.f};
  float mrun[2] = {-1e30f, -1e30f};
  float lrun[2] = {0.f, 0.f};

  const int r0 = tid >> 3, ch = tid & 7;
  const int so = (ch << 4) ^ ((r0 & 7) << 4);
  const int mStart = sp * chunkKeys;
  const int niter = chunkKeys >> 6;

  {
    const unsigned short* kbase = Kb + ((h * NN + mStart) << 6);
    const unsigned short* vbase = Vb + (size_t)(h * 80) * NN + mStart;
    const uint4 ka  = *(const uint4*)(kbase + (r0 << 6) + (ch << 3));
    const uint4 kb2 = *(const uint4*)(kbase + ((r0 + 32) << 6) + (ch << 3));
    const uint4 va  = *(const uint4*)(vbase + (size_t)r0 * NN + (ch << 3));
    const uint4 vb2 = *(const uint4*)(vbase + (size_t)(r0 + 32) * NN + (ch << 3));
    *(uint4*)(Kls + r0 * 128 + so) = ka;
    *(uint4*)(Kls + (r0 + 32) * 128 + so) = kb2;
    *(uint4*)(Vls + r0 * 128 + so) = va;
    *(uint4*)(Vls + (r0 + 32) * 128 + so) = vb2;
    if (tid < 128) {
      const uint4 vc = *(const uint4*)(vbase + (size_t)(r0 + 64) * NN + (ch << 3));
      *(uint4*)(Vls + (r0 + 64) * 128 + so) = vc;
    }
  }
  __syncthreads();

  for (int it = 0; it < niter; ++it) {
    uint4 ka, kb2, va, vb2, vc;
    const bool hav = (it + 1 < niter);
    if (hav) {
      const int m0 = mStart + ((it + 1) << 6);
      const unsigned short* kbase = Kb + ((h * NN + m0) << 6);
      const unsigned short* vbase = Vb + (size_t)(h * 80) * NN + m0;
      ka  = *(const uint4*)(kbase + (r0 << 6) + (ch << 3));
      kb2 = *(const uint4*)(kbase + ((r0 + 32) << 6) + (ch << 3));
      va  = *(const uint4*)(vbase + (size_t)r0 * NN + (ch << 3));
      vb2 = *(const uint4*)(vbase + (size_t)(r0 + 32) * NN + (ch << 3));
      if (tid < 128) vc = *(const uint4*)(vbase + (size_t)(r0 + 64) * NN + (ch << 3));
    }

    f32x4 sD[2][4];
    __builtin_amdgcn_s_setprio(1);
#pragma unroll
    for (int t = 0; t < 4; ++t) {
      const char* rp = Kls + (t * 16 + c) * 128;
      const short8 ka0 = *(const short8*)(rp + ((g << 4) ^ swc));
      const short8 ka1 = *(const short8*)(rp + ((64 + (g << 4)) ^ swc));
#pragma unroll
      for (int qs = 0; qs < 2; ++qs) {
        f32x4 a = (f32x4){0.f, 0.f, 0.f, 0.f};
        a = __builtin_amdgcn_mfma_f32_16x16x32_bf16(ka0, qf[qs][0], a, 0, 0, 0);
        a = __builtin_amdgcn_mfma_f32_16x16x32_bf16(ka1, qf[qs][1], a, 0, 0, 0);
        sD[qs][t] = a;
      }
    }
    __builtin_amdgcn_s_setprio(0);

#pragma unroll
    for (int qs = 0; qs < 2; ++qs) {
      float m01 = fmaxf(fmaxf(sD[qs][0][0], sD[qs][0][1]), fmaxf(sD[qs][0][2], sD[qs][0][3]));
      float m11 = fmaxf(fmaxf(sD[qs][1][0], sD[qs][1][1]), fmaxf(sD[qs][1][2], sD[qs][1][3]));
      float m21 = fmaxf(fmaxf(sD[qs][2][0], sD[qs][2][1]), fmaxf(sD[qs][2][2], sD[qs][2][3]));
      float m31 = fmaxf(fmaxf(sD[qs][3][0], sD[qs][3][1]), fmaxf(sD[qs][3][2], sD[qs][3][3]));
      float mx = fmaxf(fmaxf(m01, m11), fmaxf(m21, m31));
      mx = fmaxf(mx, __shfl_xor(mx, 16));
      mx = fmaxf(mx, __shfl_xor(mx, 32));
      // T13 defer-max: skip rescale when tile max within THR=8 of running max
      if (!__all(mx - mrun[qs] <= 8.f)) {
        const float mnew = fmaxf(mrun[qs], mx);
        const float a = __expf(mrun[qs] - mnew);
        mrun[qs] = mnew;
        lrun[qs] *= a;
#pragma unroll
        for (int dt = 0; dt < 5; ++dt)
#pragma unroll
          for (int r = 0; r < 4; ++r) Of[qs][dt][r] *= a;
      }
      const float mm = mrun[qs];
      float rs = 0.f;
      unsigned pk[8];
#pragma unroll
      for (int t = 0; t < 4; ++t) {
        const float e0 = __expf(sD[qs][t][0] - mm);
        const float e1 = __expf(sD[qs][t][1] - mm);
        const float e2 = __expf(sD[qs][t][2] - mm);
        const float e3 = __expf(sD[qs][t][3] - mm);
        rs += (e0 + e1) + (e2 + e3);
        pk[t * 2]     = packpair(e0, e1);
        pk[t * 2 + 1] = packpair(e2, e3);
      }
      rs += __shfl_xor(rs, 16);
      rs += __shfl_xor(rs, 32);
      lrun[qs] += rs;
      char* prow = Pls + (qs * 16 + c) * 128;
#pragma unroll
      for (int t = 0; t < 4; ++t)
        *(uint2*)(prow + ((t * 32 + (g << 3)) ^ swc)) = make_uint2(pk[t * 2], pk[t * 2 + 1]);
    }

    short8 pb[2][2];
#pragma unroll
    for (int qs = 0; qs < 2; ++qs) {
      const char* prow = Pls + (qs * 16 + c) * 128;
      pb[qs][0] = *(const short8*)(prow + ((g << 4) ^ swc));
      pb[qs][1] = *(const short8*)(prow + ((64 + (g << 4)) ^ swc));
    }
    __builtin_amdgcn_s_setprio(1);
#pragma unroll
    for (int dt = 0; dt < 5; ++dt) {
      const char* vp = Vls + (dt * 16 + c) * 128;
      const short8 va0 = *(const short8*)(vp + ((g << 4) ^ swc));
      const short8 va1 = *(const short8*)(vp + ((64 + (g << 4)) ^ swc));
#pragma unroll
      for (int qs = 0; qs < 2; ++qs) {
        Of[qs][dt] = __builtin_amdgcn_mfma_f32_16x16x32_bf16(va0, pb[qs][0], Of[qs][dt], 0, 0, 0);
        Of[qs][dt] = __builtin_amdgcn_mfma_f32_16x16x32_bf16(va1, pb[qs][1], Of[qs][dt], 0, 0, 0);
      }
    }
    __builtin_amdgcn_s_setprio(0);

    __syncthreads();
    if (hav) {
      *(uint4*)(Kls + r0 * 128 + so) = ka;
      *(uint4*)(Kls + (r0 + 32) * 128 + so) = kb2;
      *(uint4*)(Vls + r0 * 128 + so) = va;
      *(uint4*)(Vls + (r0 + 32) * 128 + so) = vb2;
      if (tid < 128) *(uint4*)(Vls + (r0 + 64) * 128 + so) = vc;
    }
    __syncthreads();
  }

  const int rowbase = (sp * 4 + h) * 69;
#pragma unroll
  for (int qs = 0; qs < 2; ++qs) {
    const int qg = qbase + w * 32 + qs * 16 + c;
#pragma unroll
    for (int dt = 0; dt < 5; ++dt)
#pragma unroll
      for (int r = 0; r < 4; ++r) {
        const int dv = dt * 16 + (g << 2) + r;
        if (dv < 67) Opart[(size_t)(rowbase + dv) * NN + qg] = Of[qs][dt][r];
      }
    if (g == 0) {
      Opart[(size_t)(rowbase + 67) * NN + qg] = mrun[qs];
      Opart[(size_t)(rowbase + 68) * NN + qg] = lrun[qs];
    }
  }
}

// ---------------- combine splits + augment, write Yt bf16 [NN][288] directly ----------------
// grid (256), block 256: q-chunk of 16; workers = 4 h x 4 dv-groups.
// NS = compile-time nsplit so the s-loop fully unrolls (8 independent loads in flight).
template <int NS>
__global__ __launch_bounds__(256) void combine_t_kernel(
    const float* __restrict__ Opart, const float* __restrict__ coords0,
    unsigned short* __restrict__ Yt) {
  __shared__ __align__(16) unsigned char Yl[16 * 640];  // [16 q][320 ushort], XOR-swizzled
  const int t = threadIdx.x;
  const int q = t & 15;
  const int worker = t >> 4;       // 0..15
  const int h = worker & 3;
  const int dgrp = worker >> 2;    // 0..3
  const int q0 = blockIdx.x << 4;
  const int qg = q0 + q;
  const int rowb = q * 640;
  const int sw = (q & 7) << 4;

  float m[NS], wgt[NS], lv[NS];
  float M = -1e30f;
#pragma unroll
  for (int s = 0; s < NS; ++s)
    m[s] = Opart[((size_t)(s * 4 + h) * 69 + 67) * NN + qg];
#pragma unroll
  for (int s = 0; s < NS; ++s)
    lv[s] = Opart[((size_t)(s * 4 + h) * 69 + 68) * NN + qg];
#pragma unroll
  for (int s = 0; s < NS; ++s) M = fmaxf(M, m[s]);
  float L = 0.f;
#pragma unroll
  for (int s = 0; s < NS; ++s) {
    wgt[s] = __expf(m[s] - M);
    L += lv[s] * wgt[s];
  }
  const float invL = 1.f / L;
#pragma unroll
  for (int s = 0; s < NS; ++s) wgt[s] *= invL;  // fold normalization into weights

  if (worker == 0) *(uint2*)(Yl + rowb + (568 ^ sw)) = make_uint2(0u, 0u);  // pad cols 284..287

  const int dv0 = dgrp * 17;
  const int dv1 = (dgrp == 3) ? 67 : dv0 + 17;
  float ss = 0.f;
#pragma unroll 2
  for (int dv = dv0; dv < dv1; ++dv) {
    float vals[NS];
#pragma unroll
    for (int s = 0; s < NS; ++s)
      vals[s] = Opart[((size_t)(s * 4 + h) * 69 + dv) * NN + qg];
    float a = 0.f;
#pragma unroll
    for (int s = 0; s < NS; ++s) a += vals[s] * wgt[s];
    *(unsigned short*)(Yl + rowb + ((((dv << 2) + h) << 1) ^ sw)) = f2bf(a);
    if (dv >= 64) {
      const float au = a - coords0[(size_t)(dv - 64) * NN + qg];
      *(unsigned short*)(Yl + rowb + (((((dv + 3) << 2) + h) << 1) ^ sw)) = f2bf(au);
      ss += au * au;
    }
  }
  if (dgrp == 3) *(unsigned short*)(Yl + rowb + (((280 + h) << 1) ^ sw)) = f2bf(sqrtf(ss));
  __syncthreads();

  // cooperative swizzle-undo copy: 16 rows x 36 uint4 segs = 576 over 256 threads
  for (int i = t; i < 16 * 36; i += 256) {
    const int row = i / 36, seg = i - row * 36;
    *(uint4*)(Yt + (size_t)(q0 + row) * 288 + (seg << 3)) =
        *(const uint4*)(Yl + row * 640 + ((seg << 4) ^ ((row & 7) << 4)));
  }
}

// ---------------- MFMA out projection: out = Wm(284x284) . y + bm ----------------
// grid (NN/128, 5), block 256 = 4 waves (2x2). BM=64, BN=128, BK=96, K=288.
#define OP_LOAD(k0_) do { \
  const int arow = co0 + ar; \
  _Pragma("unroll") for (int i = 0; i < 6; ++i) { \
    const int col = (k0_) + ac + 4 * i; \
    wa[i] = (arow < 284 && col < 284) ? *(const float4*)(Wm + (size_t)arow * 284 + col) \
                                      : make_float4(0.f, 0.f, 0.f, 0.f); \
  } \
  _Pragma("unroll") for (int i = 0; i < 6; ++i) \
    wb[i] = *(const uint4*)(Yt + (size_t)(n0 + bn) * 288 + (k0_) + bc + 8 * i); \
} while (0)

#define OP_WRITE_LDS() do { \
  unsigned pk[12]; \
  _Pragma("unroll") for (int i = 0; i < 6; ++i) { \
    pk[2 * i] = packpair(wa[i].x, wa[i].y); \
    pk[2 * i + 1] = packpair(wa[i].z, wa[i].w); \
  } \
  _Pragma("unroll") for (int i = 0; i < 3; ++i) \
    *(uint4*)(Al + ar * 256 + (((ac << 1) + (i << 4)) ^ aswz)) = *(uint4*)&pk[4 * i]; \
  _Pragma("unroll") for (int i = 0; i < 6; ++i) \
    *(uint4*)(Bl + bn * 256 + (((bc << 1) + (i << 4)) ^ bswz)) = wb[i]; \
} while (0)

__global__ __launch_bounds__(256) void outproj_gemm_kernel(
    const unsigned short* __restrict__ Yt, const float* __restrict__ Wm,
    const float* __restrict__ bm, float* __restrict__ out) {
  __shared__ __align__(16) unsigned char smem[49152];  // Al 64x256B | Bl 128x256B
  __shared__ float Bls[64];
  const int co0 = blockIdx.y << 6;
  const int n0 = blockIdx.x << 7;
  const int tid = threadIdx.x;
  const int w = tid >> 6, l = tid & 63;
  const int wm = w >> 1, wn = w & 1;
  const int c = l & 15, g = l >> 4;
  char* const Al = (char*)smem;
  char* const Bl = (char*)smem + 16384;

  if (tid < 64) { const int co = co0 + tid; Bls[tid] = (co < 284) ? bm[co] : 0.f; }

  const int ar = tid >> 2, ac = (tid & 3) * 24;
  const int bn = tid >> 1, bc = (tid & 1) * 48;
  const int aswz = (ar & 7) << 4;
  const int bswz = (bn & 7) << 4;

  float4 wa[6];
  uint4 wb[6];
  f32x4 acc[2][4];
#pragma unroll
  for (int mf = 0; mf < 2; ++mf)
#pragma unroll
    for (int nf = 0; nf < 4; ++nf) acc[mf][nf] = (f32x4){0.f, 0.f, 0.f, 0.f};

  OP_LOAD(0);
  OP_WRITE_LDS();
  __syncthreads();

  for (int s = 0; s < 3; ++s) {
    const bool hav = (s + 1 < 3);
    if (hav) OP_LOAD((s + 1) * 96);
    __builtin_amdgcn_s_setprio(1);
#pragma unroll
    for (int ks = 0; ks < 3; ++ks) {
      short8 af[2], bf[4];
#pragma unroll
      for (int mf = 0; mf < 2; ++mf) {
        const int row = wm * 32 + mf * 16 + c;
        af[mf] = *(const short8*)(Al + row * 256 + (((ks << 6) + (g << 4)) ^ ((row & 7) << 4)));
      }
#pragma unroll
      for (int nf = 0; nf < 4; ++nf) {
        const int row = wn * 64 + nf * 16 + c;
        bf[nf] = *(const short8*)(Bl + row * 256 + (((ks << 6) + (g << 4)) ^ ((row & 7) << 4)));
      }
#pragma unroll
      for (int mf = 0; mf < 2; ++mf)
#pragma unroll
        for (int nf = 0; nf < 4; ++nf)
          acc[mf][nf] = __builtin_amdgcn_mfma_f32_16x16x32_bf16(af[mf], bf[nf], acc[mf][nf], 0, 0, 0);
    }
    __builtin_amdgcn_s_setprio(0);
    __syncthreads();
    if (hav) {
      OP_WRITE_LDS();
      __syncthreads();
    }
  }

#pragma unroll
  for (int mf = 0; mf < 2; ++mf)
#pragma unroll
    for (int nf = 0; nf < 4; ++nf)
#pragma unroll
      for (int rr = 0; rr < 4; ++rr) {
        const int row = wm * 32 + mf * 16 + (g << 2) + rr;
        const int co = co0 + row;
        if (co < 284)
          out[(size_t)co * NN + n0 + wn * 64 + nf * 16 + c] = acc[mf][nf][rr] + Bls[row];
      }
}

extern "C" void kernel_launch(void* const* d_in, const int* in_sizes, int n_in,
                              void* d_out, int out_size, void* d_ws, size_t ws_size,
                              hipStream_t stream) {
  const float* query   = (const float*)d_in[0];
  const float* key_    = (const float*)d_in[1];
  const float* value   = (const float*)d_in[2];
  const float* coords0 = (const float*)d_in[3];
  const float* coords1 = (const float*)d_in[4];
  const float* Wq = (const float*)d_in[5];
  const float* bq = (const float*)d_in[6];
  const float* Wk = (const float*)d_in[7];
  const float* bk = (const float*)d_in[8];
  const float* Wv = (const float*)d_in[9];
  const float* bv = (const float*)d_in[10];
  const float* Wm = (const float*)d_in[11];
  const float* bm = (const float*)d_in[12];
  float* out = (float*)d_out;

  // ws: Qb 2MB | Kb 2MB | Vb 2.62MB | Xt 6MB | Yt 2.25MB | Opart nsplit*4.52MB
  unsigned short* Qb = (unsigned short*)d_ws;
  unsigned short* Kb = Qb + (size_t)4 * NN * 64;
  unsigned short* Vb = Kb + (size_t)4 * NN * 64;
  unsigned short* Xt = Vb + (size_t)4 * 80 * NN;
  unsigned short* Yt = Xt + (size_t)3 * NN * 256;
  float* Opart = (float*)(Yt + (size_t)NN * 288);

  const size_t fixedB = (size_t)((char*)Opart - (char*)d_ws);
  const size_t per = (size_t)4 * 69 * NN * 4;
  int nsplit = 8;
  while (nsplit > 1 && ws_size < fixedB + (size_t)nsplit * per) nsplit >>= 1;

  hipLaunchKernelGGL(transpose3_kernel, dim3(64, 4, 3), dim3(256), 0, stream,
                     query, key_, value, Xt, coords1, Vb);
  hipLaunchKernelGGL(proj_gemm_kernel, dim3(64, 4, 3), dim3(256), 0, stream,
                     Wq, bq, Wk, bk, Wv, bv, Xt, Qb, Kb, Vb);
  hipLaunchKernelGGL(attn_kernel, dim3(32, 4, nsplit), dim3(256), 0, stream,
                     Qb, Kb, Vb, Opart, NN / nsplit);
  switch (nsplit) {
    case 8:
      hipLaunchKernelGGL((combine_t_kernel<8>), dim3(256), dim3(256), 0, stream, Opart, coords0, Yt);
      break;
    case 4:
      hipLaunchKernelGGL((combine_t_kernel<4>), dim3(256), dim3(256), 0, stream, Opart, coords0, Yt);
      break;
    case 2:
      hipLaunchKernelGGL((combine_t_kernel<2>), dim3(256), dim3(256), 0, stream, Opart, coords0, Yt);
      break;
    default:
      hipLaunchKernelGGL((combine_t_kernel<1>), dim3(256), dim3(256), 0, stream, Opart, coords0, Yt);
      break;
  }
  hipLaunchKernelGGL(outproj_gemm_kernel, dim3(32, 5), dim3(256), 0, stream, Yt, Wm, bm, out);
}

// Round 10
// 90.589 us; speedup vs baseline: 2.6050x; 1.0318x over previous
//
#include <hip/hip_runtime.h>
#include <hip/hip_bf16.h>

#define NN 4096

typedef __attribute__((ext_vector_type(8))) short short8;
typedef __attribute__((ext_vector_type(4))) float f32x4;

__device__ __forceinline__ unsigned short f2bf(float f) {
  union { float f; unsigned u; } v; v.f = f;
  unsigned u = v.u;
  u += 0x7fffu + ((u >> 16) & 1u);
  return (unsigned short)(u >> 16);
}

__device__ __forceinline__ unsigned packpair(float a, float b) {
  __hip_bfloat162 h = __float22bfloat162_rn(make_float2(a, b));  // v_cvt_pk_bf16_f32
  union { __hip_bfloat162 h; unsigned u; } cv; cv.h = h;
  return cv.u;
}

// ---------------- transpose q/k/v: f32 [256][NN] -> bf16 [NN][256]; + coords fill ----------------
// grid (64, 4, 3), block 256
__global__ __launch_bounds__(256) void transpose3_kernel(
    const float* __restrict__ q, const float* __restrict__ k, const float* __restrict__ v,
    unsigned short* __restrict__ Xt, const float* __restrict__ coords1,
    unsigned short* __restrict__ Vb) {
  __shared__ float Tl[64][65];
  const float* X = (blockIdx.z == 0) ? q : (blockIdx.z == 1) ? k : v;
  unsigned short* dst = Xt + (size_t)blockIdx.z * NN * 256;
  const int n0 = blockIdx.x << 6, k0 = blockIdx.y << 6;
  const int t = threadIdx.x;
  const int r = t >> 4, c4 = (t & 15) << 2;
#pragma unroll
  for (int i = 0; i < 4; ++i) {
    const float4 vv = *(const float4*)(X + (size_t)(k0 + r + 16 * i) * NN + n0 + c4);
    Tl[r + 16 * i][c4] = vv.x; Tl[r + 16 * i][c4 + 1] = vv.y;
    Tl[r + 16 * i][c4 + 2] = vv.z; Tl[r + 16 * i][c4 + 3] = vv.w;
  }
  __syncthreads();
  const int kc = (t & 7) << 3;
#pragma unroll
  for (int j = 0; j < 2; ++j) {
    const int n = (t >> 3) + (j << 5);
    unsigned pk[4];
#pragma unroll
    for (int u = 0; u < 4; ++u)
      pk[u] = packpair(Tl[kc + 2 * u][n], Tl[kc + 2 * u + 1][n]);
    *(uint4*)(dst + (size_t)(n0 + n) * 256 + k0 + kc) = *(uint4*)pk;
  }
  // folded coords fill: V rows 64..66 = coords1, 67..79 = 0 (once per n-chunk)
  if (blockIdx.z == 2 && blockIdx.y == 0) {
    const int rr = t >> 2, seg = t & 3;
    const int h = rr >> 4, d = 64 + (rr & 15);
    unsigned short* vd = Vb + (size_t)(h * 80 + d) * NN + n0 + seg * 16;
    if (d < 67) {
      const float* src = coords1 + (size_t)(d - 64) * NN + n0 + seg * 16;
      unsigned u[8];
#pragma unroll
      for (int i = 0; i < 4; ++i) {
        const float4 cv = *(const float4*)(src + 4 * i);
        u[2 * i] = packpair(cv.x, cv.y);
        u[2 * i + 1] = packpair(cv.z, cv.w);
      }
      *(uint4*)vd = *(uint4*)&u[0];
      *(uint4*)(vd + 8) = *(uint4*)&u[4];
    } else {
      const uint4 zz = make_uint4(0u, 0u, 0u, 0u);
      *(uint4*)vd = zz;
      *(uint4*)(vd + 8) = zz;
    }
  }
}

// ---------------- MFMA projection GEMM: C = W(256x256) . X(256xNN) ----------------
// grid (NN/64, 4, 3), block 256 = 4 waves (2x2). BM=64, BN=64, BK=64.
// Q is pre-scaled by 1/sqrt(64) * log2(e) so attention softmax runs in exp2 domain.
__global__ __launch_bounds__(256) void proj_gemm_kernel(
    const float* __restrict__ Wq, const float* __restrict__ bq,
    const float* __restrict__ Wk, const float* __restrict__ bk,
    const float* __restrict__ Wv, const float* __restrict__ bv,
    const unsigned short* __restrict__ Xt,
    unsigned short* __restrict__ Qb, unsigned short* __restrict__ Kb,
    unsigned short* __restrict__ Vb) {
  __shared__ __align__(16) unsigned char smem[16384];  // Al 64x128B | Bl 64x128B
  __shared__ float Bls[64];
  const int z = blockIdx.z;
  const float* W  = (z == 0) ? Wq : (z == 1) ? Wk : Wv;
  const float* bb = (z == 0) ? bq : (z == 1) ? bk : bv;
  const unsigned short* Xz = Xt + (size_t)z * NN * 256;
  const int co0 = blockIdx.y << 6;
  const int n0 = blockIdx.x << 6;
  const int tid = threadIdx.x;
  const int w = tid >> 6, l = tid & 63;
  const int wm = w >> 1, wn = w & 1;
  const int c = l & 15, g = l >> 4;
  char* const Al = (char*)smem;
  char* const Bl = (char*)smem + 8192;

  if (tid < 64) Bls[tid] = bb[co0 + tid];

  const int ar = tid >> 2, ac = (tid & 3) << 4;  // A: 4 thr/row, 16 f32 each
  const int br = tid >> 3, bch = tid & 7;        // B: rows br, br+32
  const int aswz = (ar & 7) << 4;
  const int bswz = (br & 7) << 4;                // (br+32)&7 == br&7

  float4 wa[4];
  uint4 wb[2];
  f32x4 acc[2][2];
#pragma unroll
  for (int mf = 0; mf < 2; ++mf)
#pragma unroll
    for (int nf = 0; nf < 2; ++nf) acc[mf][nf] = (f32x4){0.f, 0.f, 0.f, 0.f};

#define PJ_LOAD(k0_) do { \
  _Pragma("unroll") for (int i = 0; i < 4; ++i) \
    wa[i] = *(const float4*)(W + (size_t)(co0 + ar) * 256 + (k0_) + ac + 4 * i); \
  wb[0] = *(const uint4*)(Xz + (size_t)(n0 + br) * 256 + (k0_) + bch * 8); \
  wb[1] = *(const uint4*)(Xz + (size_t)(n0 + br + 32) * 256 + (k0_) + bch * 8); \
} while (0)

#define PJ_STORE() do { \
  unsigned pk[8]; \
  _Pragma("unroll") for (int i = 0; i < 4; ++i) { \
    pk[2 * i] = packpair(wa[i].x, wa[i].y); \
    pk[2 * i + 1] = packpair(wa[i].z, wa[i].w); \
  } \
  *(uint4*)(Al + ar * 128 + (((ac << 1)) ^ aswz)) = *(uint4*)&pk[0]; \
  *(uint4*)(Al + ar * 128 + (((ac << 1) + 16) ^ aswz)) = *(uint4*)&pk[4]; \
  *(uint4*)(Bl + br * 128 + ((bch << 4) ^ bswz)) = wb[0]; \
  *(uint4*)(Bl + (br + 32) * 128 + ((bch << 4) ^ bswz)) = wb[1]; \
} while (0)

  PJ_LOAD(0);
  PJ_STORE();
  __syncthreads();

  for (int s = 0; s < 4; ++s) {
    const bool hav = (s + 1 < 4);
    if (hav) PJ_LOAD((s + 1) << 6);
    __builtin_amdgcn_s_setprio(1);
#pragma unroll
    for (int ks = 0; ks < 2; ++ks) {
      short8 af[2], bf[2];
#pragma unroll
      for (int mf = 0; mf < 2; ++mf) {
        const int row = wm * 32 + mf * 16 + c;
        af[mf] = *(const short8*)(Al + row * 128 + (((ks << 6) + (g << 4)) ^ ((row & 7) << 4)));
      }
#pragma unroll
      for (int nf = 0; nf < 2; ++nf) {
        const int row = wn * 32 + nf * 16 + c;
        bf[nf] = *(const short8*)(Bl + row * 128 + (((ks << 6) + (g << 4)) ^ ((row & 7) << 4)));
      }
#pragma unroll
      for (int mf = 0; mf < 2; ++mf)
#pragma unroll
        for (int nf = 0; nf < 2; ++nf)
          acc[mf][nf] = __builtin_amdgcn_mfma_f32_16x16x32_bf16(af[mf], bf[nf], acc[mf][nf], 0, 0, 0);
    }
    __builtin_amdgcn_s_setprio(0);
    __syncthreads();
    if (hav) {
      PJ_STORE();
      __syncthreads();
    }
  }

  // epilogue: acc -> LDS bounce (bf16, stride 72) -> layout-specific global writes
  unsigned short* Clu = (unsigned short*)smem;  // [64][72]
  const float scale = (z == 0) ? 0.18033688f : 1.0f;  // 0.125 * log2(e)
#pragma unroll
  for (int mf = 0; mf < 2; ++mf)
#pragma unroll
    for (int nf = 0; nf < 2; ++nf)
#pragma unroll
      for (int rr = 0; rr < 4; ++rr) {
        const int row = wm * 32 + mf * 16 + (g << 2) + rr;
        const int col = wn * 32 + nf * 16 + c;
        Clu[row * 72 + col] = f2bf((acc[mf][nf][rr] + Bls[row]) * scale);
      }
  __syncthreads();
  if (z <= 1) {
    unsigned short* Ob = (z == 0) ? Qb : Kb;
    const int d0 = co0 >> 2;
    const int h = tid >> 6, n = tid & 63;
    unsigned u[8];
#pragma unroll
    for (int p = 0; p < 8; ++p)
      u[p] = (unsigned)Clu[((p << 3) + h) * 72 + n] |
             ((unsigned)Clu[((p << 3) + 4 + h) * 72 + n] << 16);
    uint4* dd = (uint4*)(Ob + ((size_t)h * NN + n0 + n) * 64 + d0);
    dd[0] = *(uint4*)&u[0];
    dd[1] = *(uint4*)&u[4];
  } else {
    const int rl = tid >> 2, seg = (tid & 3) << 4;
    const int h = rl & 3, d = (co0 >> 2) + (rl >> 2);
    unsigned short* vd = Vb + (size_t)(h * 80 + d) * NN + n0 + seg;
    *(uint4*)vd = *(const uint4*)((char*)Clu + rl * 144 + (seg << 1));
    *(uint4*)(vd + 8) = *(const uint4*)((char*)Clu + rl * 144 + (seg << 1) + 16);
  }
}

// ---------------- fused flash attention (split-K, exp2 domain, dbuf single-barrier) ----------------
// grid (32, 4, nsplit): x = q-tile of 128, y = head, z = key-split.
// LDS: [K0 8192 | V0 10240 | K1 8192 | V1 10240 | P 4x4096] = 53248 (3 blocks/CU)
__global__ __launch_bounds__(256) void attn_kernel(
    const unsigned short* __restrict__ Qb, const unsigned short* __restrict__ Kb,
    const unsigned short* __restrict__ Vb, float* __restrict__ Opart, int chunkKeys) {
  __shared__ __align__(16) unsigned char smem[53248];
  const int h = blockIdx.y;
  const int sp = blockIdx.z;
  const int qbase = blockIdx.x * 128;
  const int tid = threadIdx.x;
  const int w = tid >> 6;
  const int l = tid & 63;
  const int c = l & 15;
  const int g = l >> 4;
  const int swc = (c & 7) << 4;

  char* const Pls = (char*)smem + 36864 + w * 4096;

  short8 qf[2][2];
#pragma unroll
  for (int qs = 0; qs < 2; ++qs) {
    const unsigned short* qsrc = Qb + (((h * NN) + qbase + w * 32 + qs * 16 + c) << 6) + (g << 3);
    qf[qs][0] = *(const short8*)qsrc;
    qf[qs][1] = *(const short8*)(qsrc + 32);
  }

  f32x4 Of[2][5];
#pragma unroll
  for (int qs = 0; qs < 2; ++qs)
#pragma unroll
    for (int dt = 0; dt < 5; ++dt) Of[qs][dt] = (f32x4){0.f, 0.f, 0.f, 0.f};
  float mrun[2] = {-1e30f, -1e30f};
  float lrun[2] = {0.f, 0.f};

  const int r0 = tid >> 3, ch = tid & 7;
  const int so = (ch << 4) ^ ((r0 & 7) << 4);
  const int mStart = sp * chunkKeys;
  const int niter = chunkKeys >> 6;

  {
    char* const Kls = (char*)smem;
    char* const Vls = (char*)smem + 8192;
    const unsigned short* kbase = Kb + ((h * NN + mStart) << 6);
    const unsigned short* vbase = Vb + (size_t)(h * 80) * NN + mStart;
    const uint4 ka  = *(const uint4*)(kbase + (r0 << 6) + (ch << 3));
    const uint4 kb2 = *(const uint4*)(kbase + ((r0 + 32) << 6) + (ch << 3));
    const uint4 va  = *(const uint4*)(vbase + (size_t)r0 * NN + (ch << 3));
    const uint4 vb2 = *(const uint4*)(vbase + (size_t)(r0 + 32) * NN + (ch << 3));
    *(uint4*)(Kls + r0 * 128 + so) = ka;
    *(uint4*)(Kls + (r0 + 32) * 128 + so) = kb2;
    *(uint4*)(Vls + r0 * 128 + so) = va;
    *(uint4*)(Vls + (r0 + 32) * 128 + so) = vb2;
    if (tid < 128) {
      const uint4 vc = *(const uint4*)(vbase + (size_t)(r0 + 64) * NN + (ch << 3));
      *(uint4*)(Vls + (r0 + 64) * 128 + so) = vc;
    }
  }
  __syncthreads();

  for (int it = 0; it < niter; ++it) {
    char* const KlsC = (char*)smem + ((it & 1) ? 18432 : 0);
    char* const VlsC = KlsC + 8192;
    char* const KlsN = (char*)smem + ((it & 1) ? 0 : 18432);
    char* const VlsN = KlsN + 8192;

    uint4 ka, kb2, va, vb2, vc;
    const bool hav = (it + 1 < niter);
    if (hav) {
      const int m0 = mStart + ((it + 1) << 6);
      const unsigned short* kbase = Kb + ((h * NN + m0) << 6);
      const unsigned short* vbase = Vb + (size_t)(h * 80) * NN + m0;
      ka  = *(const uint4*)(kbase + (r0 << 6) + (ch << 3));
      kb2 = *(const uint4*)(kbase + ((r0 + 32) << 6) + (ch << 3));
      va  = *(const uint4*)(vbase + (size_t)r0 * NN + (ch << 3));
      vb2 = *(const uint4*)(vbase + (size_t)(r0 + 32) * NN + (ch << 3));
      if (tid < 128) vc = *(const uint4*)(vbase + (size_t)(r0 + 64) * NN + (ch << 3));
    }

    // S^T = K.Q^T (exp2 domain: Q pre-scaled by log2e/8)
    f32x4 sD[2][4];
    __builtin_amdgcn_s_setprio(1);
#pragma unroll
    for (int t = 0; t < 4; ++t) {
      const char* rp = KlsC + (t * 16 + c) * 128;
      const short8 ka0 = *(const short8*)(rp + ((g << 4) ^ swc));
      const short8 ka1 = *(const short8*)(rp + ((64 + (g << 4)) ^ swc));
#pragma unroll
      for (int qs = 0; qs < 2; ++qs) {
        f32x4 a = (f32x4){0.f, 0.f, 0.f, 0.f};
        a = __builtin_amdgcn_mfma_f32_16x16x32_bf16(ka0, qf[qs][0], a, 0, 0, 0);
        a = __builtin_amdgcn_mfma_f32_16x16x32_bf16(ka1, qf[qs][1], a, 0, 0, 0);
        sD[qs][t] = a;
      }
    }
    __builtin_amdgcn_s_setprio(0);

#pragma unroll
    for (int qs = 0; qs < 2; ++qs) {
      float m01 = fmaxf(fmaxf(sD[qs][0][0], sD[qs][0][1]), fmaxf(sD[qs][0][2], sD[qs][0][3]));
      float m11 = fmaxf(fmaxf(sD[qs][1][0], sD[qs][1][1]), fmaxf(sD[qs][1][2], sD[qs][1][3]));
      float m21 = fmaxf(fmaxf(sD[qs][2][0], sD[qs][2][1]), fmaxf(sD[qs][2][2], sD[qs][2][3]));
      float m31 = fmaxf(fmaxf(sD[qs][3][0], sD[qs][3][1]), fmaxf(sD[qs][3][2], sD[qs][3][3]));
      float mx = fmaxf(fmaxf(m01, m11), fmaxf(m21, m31));
      mx = fmaxf(mx, __shfl_xor(mx, 16));
      mx = fmaxf(mx, __shfl_xor(mx, 32));
      // T13 defer-max (log2 domain): 11.5 ~= 8*log2e -> P bounded by 2^11.5, bf16-safe
      if (!__all(mx - mrun[qs] <= 11.5f)) {
        const float mnew = fmaxf(mrun[qs], mx);
        const float a = __builtin_amdgcn_exp2f(mrun[qs] - mnew);
        mrun[qs] = mnew;
        lrun[qs] *= a;
#pragma unroll
        for (int dt = 0; dt < 5; ++dt)
#pragma unroll
          for (int r = 0; r < 4; ++r) Of[qs][dt][r] *= a;
      }
      const float mm = mrun[qs];
      float rs = 0.f;
      unsigned pk[8];
#pragma unroll
      for (int t = 0; t < 4; ++t) {
        const float e0 = __builtin_amdgcn_exp2f(sD[qs][t][0] - mm);
        const float e1 = __builtin_amdgcn_exp2f(sD[qs][t][1] - mm);
        const float e2 = __builtin_amdgcn_exp2f(sD[qs][t][2] - mm);
        const float e3 = __builtin_amdgcn_exp2f(sD[qs][t][3] - mm);
        rs += (e0 + e1) + (e2 + e3);
        pk[t * 2]     = packpair(e0, e1);
        pk[t * 2 + 1] = packpair(e2, e3);
      }
      rs += __shfl_xor(rs, 16);
      rs += __shfl_xor(rs, 32);
      lrun[qs] += rs;
      char* prow = Pls + (qs * 16 + c) * 128;
#pragma unroll
      for (int t = 0; t < 4; ++t)
        *(uint2*)(prow + ((t * 32 + (g << 3)) ^ swc)) = make_uint2(pk[t * 2], pk[t * 2 + 1]);
    }

    short8 pb[2][2];
#pragma unroll
    for (int qs = 0; qs < 2; ++qs) {
      const char* prow = Pls + (qs * 16 + c) * 128;
      pb[qs][0] = *(const short8*)(prow + ((g << 4) ^ swc));
      pb[qs][1] = *(const short8*)(prow + ((64 + (g << 4)) ^ swc));
    }
    __builtin_amdgcn_s_setprio(1);
#pragma unroll
    for (int dt = 0; dt < 5; ++dt) {
      const char* vp = VlsC + (dt * 16 + c) * 128;
      const short8 va0 = *(const short8*)(vp + ((g << 4) ^ swc));
      const short8 va1 = *(const short8*)(vp + ((64 + (g << 4)) ^ swc));
#pragma unroll
      for (int qs = 0; qs < 2; ++qs) {
        Of[qs][dt] = __builtin_amdgcn_mfma_f32_16x16x32_bf16(va0, pb[qs][0], Of[qs][dt], 0, 0, 0);
        Of[qs][dt] = __builtin_amdgcn_mfma_f32_16x16x32_bf16(va1, pb[qs][1], Of[qs][dt], 0, 0, 0);
      }
    }
    __builtin_amdgcn_s_setprio(0);

    // store next tile into the other buffer (no race: everyone finished reading it
    // before the previous barrier), then ONE barrier flips buffers.
    if (hav) {
      *(uint4*)(KlsN + r0 * 128 + so) = ka;
      *(uint4*)(KlsN + (r0 + 32) * 128 + so) = kb2;
      *(uint4*)(VlsN + r0 * 128 + so) = va;
      *(uint4*)(VlsN + (r0 + 32) * 128 + so) = vb2;
      if (tid < 128) *(uint4*)(VlsN + (r0 + 64) * 128 + so) = vc;
    }
    __syncthreads();
  }

  const int rowbase = (sp * 4 + h) * 69;
#pragma unroll
  for (int qs = 0; qs < 2; ++qs) {
    const int qg = qbase + w * 32 + qs * 16 + c;
#pragma unroll
    for (int dt = 0; dt < 5; ++dt)
#pragma unroll
      for (int r = 0; r < 4; ++r) {
        const int dv = dt * 16 + (g << 2) + r;
        if (dv < 67) Opart[(size_t)(rowbase + dv) * NN + qg] = Of[qs][dt][r];
      }
    if (g == 0) {
      Opart[(size_t)(rowbase + 67) * NN + qg] = mrun[qs];  // log2-domain max
      Opart[(size_t)(rowbase + 68) * NN + qg] = lrun[qs];
    }
  }
}

// ---------------- combine splits + augment, write Yt bf16 [NN][288] directly ----------------
// grid (256), block 256: q-chunk of 16; workers = 4 h x 4 dv-groups. NS = compile-time nsplit.
template <int NS>
__global__ __launch_bounds__(256) void combine_t_kernel(
    const float* __restrict__ Opart, const float* __restrict__ coords0,
    unsigned short* __restrict__ Yt) {
  __shared__ __align__(16) unsigned char Yl[16 * 640];  // [16 q][320 ushort], XOR-swizzled
  const int t = threadIdx.x;
  const int q = t & 15;
  const int worker = t >> 4;       // 0..15
  const int h = worker & 3;
  const int dgrp = worker >> 2;    // 0..3
  const int q0 = blockIdx.x << 4;
  const int qg = q0 + q;
  const int rowb = q * 640;
  const int sw = (q & 7) << 4;

  float m[NS], wgt[NS], lv[NS];
  float M = -1e30f;
#pragma unroll
  for (int s = 0; s < NS; ++s)
    m[s] = Opart[((size_t)(s * 4 + h) * 69 + 67) * NN + qg];
#pragma unroll
  for (int s = 0; s < NS; ++s)
    lv[s] = Opart[((size_t)(s * 4 + h) * 69 + 68) * NN + qg];
#pragma unroll
  for (int s = 0; s < NS; ++s) M = fmaxf(M, m[s]);
  float L = 0.f;
#pragma unroll
  for (int s = 0; s < NS; ++s) {
    wgt[s] = __builtin_amdgcn_exp2f(m[s] - M);  // m is log2-domain
    L += lv[s] * wgt[s];
  }
  const float invL = 1.f / L;
#pragma unroll
  for (int s = 0; s < NS; ++s) wgt[s] *= invL;

  if (worker == 0) *(uint2*)(Yl + rowb + (568 ^ sw)) = make_uint2(0u, 0u);  // pad cols 284..287

  const int dv0 = dgrp * 17;
  const int dv1 = (dgrp == 3) ? 67 : dv0 + 17;
  float ss = 0.f;
#pragma unroll 2
  for (int dv = dv0; dv < dv1; ++dv) {
    float vals[NS];
#pragma unroll
    for (int s = 0; s < NS; ++s)
      vals[s] = Opart[((size_t)(s * 4 + h) * 69 + dv) * NN + qg];
    float a = 0.f;
#pragma unroll
    for (int s = 0; s < NS; ++s) a += vals[s] * wgt[s];
    *(unsigned short*)(Yl + rowb + ((((dv << 2) + h) << 1) ^ sw)) = f2bf(a);
    if (dv >= 64) {
      const float au = a - coords0[(size_t)(dv - 64) * NN + qg];
      *(unsigned short*)(Yl + rowb + (((((dv + 3) << 2) + h) << 1) ^ sw)) = f2bf(au);
      ss += au * au;
    }
  }
  if (dgrp == 3) *(unsigned short*)(Yl + rowb + (((280 + h) << 1) ^ sw)) = f2bf(sqrtf(ss));
  __syncthreads();

  for (int i = t; i < 16 * 36; i += 256) {
    const int row = i / 36, seg = i - row * 36;
    *(uint4*)(Yt + (size_t)(q0 + row) * 288 + (seg << 3)) =
        *(const uint4*)(Yl + row * 640 + ((seg << 4) ^ ((row & 7) << 4)));
  }
}

// ---------------- MFMA out projection: out = Wm(284x284) . y + bm ----------------
// grid (NN/64, 5), block 256 = 4 waves (2x2). BM=64, BN=64, BK=96, K=288.
#define OP_LOAD(k0_) do { \
  const int arow = co0 + ar; \
  _Pragma("unroll") for (int i = 0; i < 6; ++i) { \
    const int col = (k0_) + ac + 4 * i; \
    wa[i] = (arow < 284 && col < 284) ? *(const float4*)(Wm + (size_t)arow * 284 + col) \
                                      : make_float4(0.f, 0.f, 0.f, 0.f); \
  } \
  _Pragma("unroll") for (int i = 0; i < 3; ++i) \
    wb[i] = *(const uint4*)(Yt + (size_t)(n0 + bn) * 288 + (k0_) + bc + 8 * i); \
} while (0)

#define OP_WRITE_LDS() do { \
  unsigned pk[12]; \
  _Pragma("unroll") for (int i = 0; i < 6; ++i) { \
    pk[2 * i] = packpair(wa[i].x, wa[i].y); \
    pk[2 * i + 1] = packpair(wa[i].z, wa[i].w); \
  } \
  _Pragma("unroll") for (int i = 0; i < 3; ++i) \
    *(uint4*)(Al + ar * 256 + (((ac << 1) + (i << 4)) ^ aswz)) = *(uint4*)&pk[4 * i]; \
  _Pragma("unroll") for (int i = 0; i < 3; ++i) \
    *(uint4*)(Bl + bn * 256 + (((bc << 1) + (i << 4)) ^ bswz)) = wb[i]; \
} while (0)

__global__ __launch_bounds__(256) void outproj_gemm_kernel(
    const unsigned short* __restrict__ Yt, const float* __restrict__ Wm,
    const float* __restrict__ bm, float* __restrict__ out) {
  __shared__ __align__(16) unsigned char smem[32768];  // Al 64x256B | Bl 64x256B
  __shared__ float Bls[64];
  const int co0 = blockIdx.y << 6;
  const int n0 = blockIdx.x << 6;
  const int tid = threadIdx.x;
  const int w = tid >> 6, l = tid & 63;
  const int wm = w >> 1, wn = w & 1;
  const int c = l & 15, g = l >> 4;
  char* const Al = (char*)smem;
  char* const Bl = (char*)smem + 16384;

  if (tid < 64) { const int co = co0 + tid; Bls[tid] = (co < 284) ? bm[co] : 0.f; }

  const int ar = tid >> 2, ac = (tid & 3) * 24;  // A: 64 rows x 96 f32, 4 thr/row
  const int bn = tid >> 2, bc = (tid & 3) * 24;  // B: 64 rows x 96 bf16, 4 thr/row
  const int aswz = (ar & 7) << 4;
  const int bswz = (bn & 7) << 4;

  float4 wa[6];
  uint4 wb[3];
  f32x4 acc[2][2];
#pragma unroll
  for (int mf = 0; mf < 2; ++mf)
#pragma unroll
    for (int nf = 0; nf < 2; ++nf) acc[mf][nf] = (f32x4){0.f, 0.f, 0.f, 0.f};

  OP_LOAD(0);
  OP_WRITE_LDS();
  __syncthreads();

  for (int s = 0; s < 3; ++s) {
    const bool hav = (s + 1 < 3);
    if (hav) OP_LOAD((s + 1) * 96);
    __builtin_amdgcn_s_setprio(1);
#pragma unroll
    for (int ks = 0; ks < 3; ++ks) {
      short8 af[2], bf[2];
#pragma unroll
      for (int mf = 0; mf < 2; ++mf) {
        const int row = wm * 32 + mf * 16 + c;
        af[mf] = *(const short8*)(Al + row * 256 + (((ks << 6) + (g << 4)) ^ ((row & 7) << 4)));
      }
#pragma unroll
      for (int nf = 0; nf < 2; ++nf) {
        const int row = wn * 32 + nf * 16 + c;
        bf[nf] = *(const short8*)(Bl + row * 256 + (((ks << 6) + (g << 4)) ^ ((row & 7) << 4)));
      }
#pragma unroll
      for (int mf = 0; mf < 2; ++mf)
#pragma unroll
        for (int nf = 0; nf < 2; ++nf)
          acc[mf][nf] = __builtin_amdgcn_mfma_f32_16x16x32_bf16(af[mf], bf[nf], acc[mf][nf], 0, 0, 0);
    }
    __builtin_amdgcn_s_setprio(0);
    __syncthreads();
    if (hav) {
      OP_WRITE_LDS();
      __syncthreads();
    }
  }

#pragma unroll
  for (int mf = 0; mf < 2; ++mf)
#pragma unroll
    for (int nf = 0; nf < 2; ++nf)
#pragma unroll
      for (int rr = 0; rr < 4; ++rr) {
        const int row = wm * 32 + mf * 16 + (g << 2) + rr;
        const int co = co0 + row;
        if (co < 284)
          out[(size_t)co * NN + n0 + wn * 32 + nf * 16 + c] = acc[mf][nf][rr] + Bls[row];
      }
}

extern "C" void kernel_launch(void* const* d_in, const int* in_sizes, int n_in,
                              void* d_out, int out_size, void* d_ws, size_t ws_size,
                              hipStream_t stream) {
  const float* query   = (const float*)d_in[0];
  const float* key_    = (const float*)d_in[1];
  const float* value   = (const float*)d_in[2];
  const float* coords0 = (const float*)d_in[3];
  const float* coords1 = (const float*)d_in[4];
  const float* Wq = (const float*)d_in[5];
  const float* bq = (const float*)d_in[6];
  const float* Wk = (const float*)d_in[7];
  const float* bk = (const float*)d_in[8];
  const float* Wv = (const float*)d_in[9];
  const float* bv = (const float*)d_in[10];
  const float* Wm = (const float*)d_in[11];
  const float* bm = (const float*)d_in[12];
  float* out = (float*)d_out;

  // ws: Qb 2MB | Kb 2MB | Vb 2.62MB | Xt 6MB | Yt 2.25MB | Opart nsplit*4.52MB
  unsigned short* Qb = (unsigned short*)d_ws;
  unsigned short* Kb = Qb + (size_t)4 * NN * 64;
  unsigned short* Vb = Kb + (size_t)4 * NN * 64;
  unsigned short* Xt = Vb + (size_t)4 * 80 * NN;
  unsigned short* Yt = Xt + (size_t)3 * NN * 256;
  float* Opart = (float*)(Yt + (size_t)NN * 288);

  const size_t fixedB = (size_t)((char*)Opart - (char*)d_ws);
  const size_t per = (size_t)4 * 69 * NN * 4;
  int nsplit = 8;
  while (nsplit > 1 && ws_size < fixedB + (size_t)nsplit * per) nsplit >>= 1;

  hipLaunchKernelGGL(transpose3_kernel, dim3(64, 4, 3), dim3(256), 0, stream,
                     query, key_, value, Xt, coords1, Vb);
  hipLaunchKernelGGL(proj_gemm_kernel, dim3(64, 4, 3), dim3(256), 0, stream,
                     Wq, bq, Wk, bk, Wv, bv, Xt, Qb, Kb, Vb);
  hipLaunchKernelGGL(attn_kernel, dim3(32, 4, nsplit), dim3(256), 0, stream,
                     Qb, Kb, Vb, Opart, NN / nsplit);
  switch (nsplit) {
    case 8:
      hipLaunchKernelGGL((combine_t_kernel<8>), dim3(256), dim3(256), 0, stream, Opart, coords0, Yt);
      break;
    case 4:
      hipLaunchKernelGGL((combine_t_kernel<4>), dim3(256), dim3(256), 0, stream, Opart, coords0, Yt);
      break;
    case 2:
      hipLaunchKernelGGL((combine_t_kernel<2>), dim3(256), dim3(256), 0, stream, Opart, coords0, Yt);
      break;
    default:
      hipLaunchKernelGGL((combine_t_kernel<1>), dim3(256), dim3(256), 0, stream, Opart, coords0, Yt);
      break;
  }
  hipLaunchKernelGGL(outproj_gemm_kernel, dim3(64, 5), dim3(256), 0, stream, Yt, Wm, bm, out);
}

// Round 11
// 85.679 us; speedup vs baseline: 2.7543x; 1.0573x over previous
//
#include <hip/hip_runtime.h>
#include <hip/hip_bf16.h>

#define NN 4096

typedef __attribute__((ext_vector_type(8))) short short8;
typedef __attribute__((ext_vector_type(4))) float f32x4;

__device__ __forceinline__ unsigned short f2bf(float f) {
  union { float f; unsigned u; } v; v.f = f;
  unsigned u = v.u;
  u += 0x7fffu + ((u >> 16) & 1u);
  return (unsigned short)(u >> 16);
}

__device__ __forceinline__ unsigned packpair(float a, float b) {
  __hip_bfloat162 h = __float22bfloat162_rn(make_float2(a, b));  // v_cvt_pk_bf16_f32
  union { __hip_bfloat162 h; unsigned u; } cv; cv.h = h;
  return cv.u;
}

// ---------------- transpose q/k/v: f32 [256][NN] -> bf16 [NN][256]; + coords fill ----------------
// grid (64, 4, 3), block 256
__global__ __launch_bounds__(256) void transpose3_kernel(
    const float* __restrict__ q, const float* __restrict__ k, const float* __restrict__ v,
    unsigned short* __restrict__ Xt, const float* __restrict__ coords1,
    unsigned short* __restrict__ Vb) {
  __shared__ float Tl[64][65];
  const float* X = (blockIdx.z == 0) ? q : (blockIdx.z == 1) ? k : v;
  unsigned short* dst = Xt + (size_t)blockIdx.z * NN * 256;
  const int n0 = blockIdx.x << 6, k0 = blockIdx.y << 6;
  const int t = threadIdx.x;
  const int r = t >> 4, c4 = (t & 15) << 2;
#pragma unroll
  for (int i = 0; i < 4; ++i) {
    const float4 vv = *(const float4*)(X + (size_t)(k0 + r + 16 * i) * NN + n0 + c4);
    Tl[r + 16 * i][c4] = vv.x; Tl[r + 16 * i][c4 + 1] = vv.y;
    Tl[r + 16 * i][c4 + 2] = vv.z; Tl[r + 16 * i][c4 + 3] = vv.w;
  }
  __syncthreads();
  const int kc = (t & 7) << 3;
#pragma unroll
  for (int j = 0; j < 2; ++j) {
    const int n = (t >> 3) + (j << 5);
    unsigned pk[4];
#pragma unroll
    for (int u = 0; u < 4; ++u)
      pk[u] = packpair(Tl[kc + 2 * u][n], Tl[kc + 2 * u + 1][n]);
    *(uint4*)(dst + (size_t)(n0 + n) * 256 + k0 + kc) = *(uint4*)pk;
  }
  // folded coords fill: V rows 64..66 = coords1, 67..79 = 0 (once per n-chunk)
  if (blockIdx.z == 2 && blockIdx.y == 0) {
    const int rr = t >> 2, seg = t & 3;
    const int h = rr >> 4, d = 64 + (rr & 15);
    unsigned short* vd = Vb + (size_t)(h * 80 + d) * NN + n0 + seg * 16;
    if (d < 67) {
      const float* src = coords1 + (size_t)(d - 64) * NN + n0 + seg * 16;
      unsigned u[8];
#pragma unroll
      for (int i = 0; i < 4; ++i) {
        const float4 cv = *(const float4*)(src + 4 * i);
        u[2 * i] = packpair(cv.x, cv.y);
        u[2 * i + 1] = packpair(cv.z, cv.w);
      }
      *(uint4*)vd = *(uint4*)&u[0];
      *(uint4*)(vd + 8) = *(uint4*)&u[4];
    } else {
      const uint4 zz = make_uint4(0u, 0u, 0u, 0u);
      *(uint4*)vd = zz;
      *(uint4*)(vd + 8) = zz;
    }
  }
}

// ---------------- MFMA projection GEMM: C = W(256x256) . X(256xNN) ----------------
// grid (NN/64, 4, 3), block 256 = 4 waves (2x2). BM=64, BN=64, BK=64.
// Q is pre-scaled by 1/sqrt(64) * log2(e) so attention softmax runs in exp2 domain.
__global__ __launch_bounds__(256) void proj_gemm_kernel(
    const float* __restrict__ Wq, const float* __restrict__ bq,
    const float* __restrict__ Wk, const float* __restrict__ bk,
    const float* __restrict__ Wv, const float* __restrict__ bv,
    const unsigned short* __restrict__ Xt,
    unsigned short* __restrict__ Qb, unsigned short* __restrict__ Kb,
    unsigned short* __restrict__ Vb) {
  __shared__ __align__(16) unsigned char smem[16384];  // Al 64x128B | Bl 64x128B
  __shared__ float Bls[64];
  const int z = blockIdx.z;
  const float* W  = (z == 0) ? Wq : (z == 1) ? Wk : Wv;
  const float* bb = (z == 0) ? bq : (z == 1) ? bk : bv;
  const unsigned short* Xz = Xt + (size_t)z * NN * 256;
  const int co0 = blockIdx.y << 6;
  const int n0 = blockIdx.x << 6;
  const int tid = threadIdx.x;
  const int w = tid >> 6, l = tid & 63;
  const int wm = w >> 1, wn = w & 1;
  const int c = l & 15, g = l >> 4;
  char* const Al = (char*)smem;
  char* const Bl = (char*)smem + 8192;

  if (tid < 64) Bls[tid] = bb[co0 + tid];

  const int ar = tid >> 2, ac = (tid & 3) << 4;  // A: 4 thr/row, 16 f32 each
  const int br = tid >> 3, bch = tid & 7;        // B: rows br, br+32
  const int aswz = (ar & 7) << 4;
  const int bswz = (br & 7) << 4;                // (br+32)&7 == br&7

  float4 wa[4];
  uint4 wb[2];
  f32x4 acc[2][2];
#pragma unroll
  for (int mf = 0; mf < 2; ++mf)
#pragma unroll
    for (int nf = 0; nf < 2; ++nf) acc[mf][nf] = (f32x4){0.f, 0.f, 0.f, 0.f};

#define PJ_LOAD(k0_) do { \
  _Pragma("unroll") for (int i = 0; i < 4; ++i) \
    wa[i] = *(const float4*)(W + (size_t)(co0 + ar) * 256 + (k0_) + ac + 4 * i); \
  wb[0] = *(const uint4*)(Xz + (size_t)(n0 + br) * 256 + (k0_) + bch * 8); \
  wb[1] = *(const uint4*)(Xz + (size_t)(n0 + br + 32) * 256 + (k0_) + bch * 8); \
} while (0)

#define PJ_STORE() do { \
  unsigned pk[8]; \
  _Pragma("unroll") for (int i = 0; i < 4; ++i) { \
    pk[2 * i] = packpair(wa[i].x, wa[i].y); \
    pk[2 * i + 1] = packpair(wa[i].z, wa[i].w); \
  } \
  *(uint4*)(Al + ar * 128 + (((ac << 1)) ^ aswz)) = *(uint4*)&pk[0]; \
  *(uint4*)(Al + ar * 128 + (((ac << 1) + 16) ^ aswz)) = *(uint4*)&pk[4]; \
  *(uint4*)(Bl + br * 128 + ((bch << 4) ^ bswz)) = wb[0]; \
  *(uint4*)(Bl + (br + 32) * 128 + ((bch << 4) ^ bswz)) = wb[1]; \
} while (0)

  PJ_LOAD(0);
  PJ_STORE();
  __syncthreads();

  for (int s = 0; s < 4; ++s) {
    const bool hav = (s + 1 < 4);
    if (hav) PJ_LOAD((s + 1) << 6);
    __builtin_amdgcn_s_setprio(1);
#pragma unroll
    for (int ks = 0; ks < 2; ++ks) {
      short8 af[2], bf[2];
#pragma unroll
      for (int mf = 0; mf < 2; ++mf) {
        const int row = wm * 32 + mf * 16 + c;
        af[mf] = *(const short8*)(Al + row * 128 + (((ks << 6) + (g << 4)) ^ ((row & 7) << 4)));
      }
#pragma unroll
      for (int nf = 0; nf < 2; ++nf) {
        const int row = wn * 32 + nf * 16 + c;
        bf[nf] = *(const short8*)(Bl + row * 128 + (((ks << 6) + (g << 4)) ^ ((row & 7) << 4)));
      }
#pragma unroll
      for (int mf = 0; mf < 2; ++mf)
#pragma unroll
        for (int nf = 0; nf < 2; ++nf)
          acc[mf][nf] = __builtin_amdgcn_mfma_f32_16x16x32_bf16(af[mf], bf[nf], acc[mf][nf], 0, 0, 0);
    }
    __builtin_amdgcn_s_setprio(0);
    __syncthreads();
    if (hav) {
      PJ_STORE();
      __syncthreads();
    }
  }

  // epilogue: acc -> LDS bounce (bf16, stride 72) -> layout-specific global writes
  unsigned short* Clu = (unsigned short*)smem;  // [64][72]
  const float scale = (z == 0) ? 0.18033688f : 1.0f;  // 0.125 * log2(e)
#pragma unroll
  for (int mf = 0; mf < 2; ++mf)
#pragma unroll
    for (int nf = 0; nf < 2; ++nf)
#pragma unroll
      for (int rr = 0; rr < 4; ++rr) {
        const int row = wm * 32 + mf * 16 + (g << 2) + rr;
        const int col = wn * 32 + nf * 16 + c;
        Clu[row * 72 + col] = f2bf((acc[mf][nf][rr] + Bls[row]) * scale);
      }
  __syncthreads();
  if (z <= 1) {
    unsigned short* Ob = (z == 0) ? Qb : Kb;
    const int d0 = co0 >> 2;
    const int h = tid >> 6, n = tid & 63;
    unsigned u[8];
#pragma unroll
    for (int p = 0; p < 8; ++p)
      u[p] = (unsigned)Clu[((p << 3) + h) * 72 + n] |
             ((unsigned)Clu[((p << 3) + 4 + h) * 72 + n] << 16);
    uint4* dd = (uint4*)(Ob + ((size_t)h * NN + n0 + n) * 64 + d0);
    dd[0] = *(uint4*)&u[0];
    dd[1] = *(uint4*)&u[4];
  } else {
    const int rl = tid >> 2, seg = (tid & 3) << 4;
    const int h = rl & 3, d = (co0 >> 2) + (rl >> 2);
    unsigned short* vd = Vb + (size_t)(h * 80 + d) * NN + n0 + seg;
    *(uint4*)vd = *(const uint4*)((char*)Clu + rl * 144 + (seg << 1));
    *(uint4*)(vd + 8) = *(const uint4*)((char*)Clu + rl * 144 + (seg << 1) + 16);
  }
}

// ---------------- fused flash attention (split-K, exp2 domain, dbuf, XCD-grouped) ----------------
// 1-D grid (128*nsplit), block 256 = 4 waves. Decode maps all 32 q-blocks of one
// (h, split) K/V chunk onto ONE XCD (b&7) so the chunk is fetched once per L2.
// LDS: [K0 8192 | V0 10240 | K1 8192 | V1 10240 | P 4x4096] = 53248
__global__ __launch_bounds__(256) void attn_kernel(
    const unsigned short* __restrict__ Qb, const unsigned short* __restrict__ Kb,
    const unsigned short* __restrict__ Vb, float* __restrict__ Opart,
    int chunkKeys, int nsplit) {
  __shared__ __align__(16) unsigned char smem[53248];
  const int b = blockIdx.x;
  int x, h, sp;
  if (nsplit >= 2) {
    const int xcd = b & 7, slot = b >> 3;
    const int group = xcd * (nsplit >> 1) + (slot >> 5);  // bijective for even nsplit
    x = slot & 31; h = group & 3; sp = group >> 2;
  } else {
    x = b & 31; h = (b >> 5) & 3; sp = 0;
  }
  const int qbase = x * 128;
  const int tid = threadIdx.x;
  const int w = tid >> 6;
  const int l = tid & 63;
  const int c = l & 15;
  const int g = l >> 4;
  const int swc = (c & 7) << 4;

  char* const Pls = (char*)smem + 36864 + w * 4096;

  short8 qf[2][2];
#pragma unroll
  for (int qs = 0; qs < 2; ++qs) {
    const unsigned short* qsrc = Qb + (((h * NN) + qbase + w * 32 + qs * 16 + c) << 6) + (g << 3);
    qf[qs][0] = *(const short8*)qsrc;
    qf[qs][1] = *(const short8*)(qsrc + 32);
  }

  f32x4 Of[2][5];
#pragma unroll
  for (int qs = 0; qs < 2; ++qs)
#pragma unroll
    for (int dt = 0; dt < 5; ++dt) Of[qs][dt] = (f32x4){0.f, 0.f, 0.f, 0.f};
  float mrun[2] = {-1e30f, -1e30f};
  float lrun[2] = {0.f, 0.f};

  const int r0 = tid >> 3, ch = tid & 7;
  const int so = (ch << 4) ^ ((r0 & 7) << 4);
  const int mStart = sp * chunkKeys;
  const int niter = chunkKeys >> 6;

  {
    char* const Kls = (char*)smem;
    char* const Vls = (char*)smem + 8192;
    const unsigned short* kbase = Kb + ((h * NN + mStart) << 6);
    const unsigned short* vbase = Vb + (size_t)(h * 80) * NN + mStart;
    const uint4 ka  = *(const uint4*)(kbase + (r0 << 6) + (ch << 3));
    const uint4 kb2 = *(const uint4*)(kbase + ((r0 + 32) << 6) + (ch << 3));
    const uint4 va  = *(const uint4*)(vbase + (size_t)r0 * NN + (ch << 3));
    const uint4 vb2 = *(const uint4*)(vbase + (size_t)(r0 + 32) * NN + (ch << 3));
    *(uint4*)(Kls + r0 * 128 + so) = ka;
    *(uint4*)(Kls + (r0 + 32) * 128 + so) = kb2;
    *(uint4*)(Vls + r0 * 128 + so) = va;
    *(uint4*)(Vls + (r0 + 32) * 128 + so) = vb2;
    if (tid < 128) {
      const uint4 vc = *(const uint4*)(vbase + (size_t)(r0 + 64) * NN + (ch << 3));
      *(uint4*)(Vls + (r0 + 64) * 128 + so) = vc;
    }
  }
  __syncthreads();

  for (int it = 0; it < niter; ++it) {
    char* const KlsC = (char*)smem + ((it & 1) ? 18432 : 0);
    char* const VlsC = KlsC + 8192;
    char* const KlsN = (char*)smem + ((it & 1) ? 0 : 18432);
    char* const VlsN = KlsN + 8192;

    uint4 ka, kb2, va, vb2, vc;
    const bool hav = (it + 1 < niter);
    if (hav) {
      const int m0 = mStart + ((it + 1) << 6);
      const unsigned short* kbase = Kb + ((h * NN + m0) << 6);
      const unsigned short* vbase = Vb + (size_t)(h * 80) * NN + m0;
      ka  = *(const uint4*)(kbase + (r0 << 6) + (ch << 3));
      kb2 = *(const uint4*)(kbase + ((r0 + 32) << 6) + (ch << 3));
      va  = *(const uint4*)(vbase + (size_t)r0 * NN + (ch << 3));
      vb2 = *(const uint4*)(vbase + (size_t)(r0 + 32) * NN + (ch << 3));
      if (tid < 128) vc = *(const uint4*)(vbase + (size_t)(r0 + 64) * NN + (ch << 3));
    }

    // S^T = K.Q^T (exp2 domain: Q pre-scaled by log2e/8)
    f32x4 sD[2][4];
    __builtin_amdgcn_s_setprio(1);
#pragma unroll
    for (int t = 0; t < 4; ++t) {
      const char* rp = KlsC + (t * 16 + c) * 128;
      const short8 ka0 = *(const short8*)(rp + ((g << 4) ^ swc));
      const short8 ka1 = *(const short8*)(rp + ((64 + (g << 4)) ^ swc));
#pragma unroll
      for (int qs = 0; qs < 2; ++qs) {
        f32x4 a = (f32x4){0.f, 0.f, 0.f, 0.f};
        a = __builtin_amdgcn_mfma_f32_16x16x32_bf16(ka0, qf[qs][0], a, 0, 0, 0);
        a = __builtin_amdgcn_mfma_f32_16x16x32_bf16(ka1, qf[qs][1], a, 0, 0, 0);
        sD[qs][t] = a;
      }
    }
    __builtin_amdgcn_s_setprio(0);

#pragma unroll
    for (int qs = 0; qs < 2; ++qs) {
      float m01 = fmaxf(fmaxf(sD[qs][0][0], sD[qs][0][1]), fmaxf(sD[qs][0][2], sD[qs][0][3]));
      float m11 = fmaxf(fmaxf(sD[qs][1][0], sD[qs][1][1]), fmaxf(sD[qs][1][2], sD[qs][1][3]));
      float m21 = fmaxf(fmaxf(sD[qs][2][0], sD[qs][2][1]), fmaxf(sD[qs][2][2], sD[qs][2][3]));
      float m31 = fmaxf(fmaxf(sD[qs][3][0], sD[qs][3][1]), fmaxf(sD[qs][3][2], sD[qs][3][3]));
      float mx = fmaxf(fmaxf(m01, m11), fmaxf(m21, m31));
      mx = fmaxf(mx, __shfl_xor(mx, 16));
      mx = fmaxf(mx, __shfl_xor(mx, 32));
      // T13 defer-max (log2 domain): 11.5 ~= 8*log2e -> P bounded by 2^11.5, bf16-safe
      if (!__all(mx - mrun[qs] <= 11.5f)) {
        const float mnew = fmaxf(mrun[qs], mx);
        const float a = __builtin_amdgcn_exp2f(mrun[qs] - mnew);
        mrun[qs] = mnew;
        lrun[qs] *= a;
#pragma unroll
        for (int dt = 0; dt < 5; ++dt)
#pragma unroll
          for (int r = 0; r < 4; ++r) Of[qs][dt][r] *= a;
      }
      const float mm = mrun[qs];
      float rs = 0.f;
      unsigned pk[8];
#pragma unroll
      for (int t = 0; t < 4; ++t) {
        const float e0 = __builtin_amdgcn_exp2f(sD[qs][t][0] - mm);
        const float e1 = __builtin_amdgcn_exp2f(sD[qs][t][1] - mm);
        const float e2 = __builtin_amdgcn_exp2f(sD[qs][t][2] - mm);
        const float e3 = __builtin_amdgcn_exp2f(sD[qs][t][3] - mm);
        rs += (e0 + e1) + (e2 + e3);
        pk[t * 2]     = packpair(e0, e1);
        pk[t * 2 + 1] = packpair(e2, e3);
      }
      rs += __shfl_xor(rs, 16);
      rs += __shfl_xor(rs, 32);
      lrun[qs] += rs;
      char* prow = Pls + (qs * 16 + c) * 128;
#pragma unroll
      for (int t = 0; t < 4; ++t)
        *(uint2*)(prow + ((t * 32 + (g << 3)) ^ swc)) = make_uint2(pk[t * 2], pk[t * 2 + 1]);
    }

    short8 pb[2][2];
#pragma unroll
    for (int qs = 0; qs < 2; ++qs) {
      const char* prow = Pls + (qs * 16 + c) * 128;
      pb[qs][0] = *(const short8*)(prow + ((g << 4) ^ swc));
      pb[qs][1] = *(const short8*)(prow + ((64 + (g << 4)) ^ swc));
    }
    __builtin_amdgcn_s_setprio(1);
#pragma unroll
    for (int dt = 0; dt < 5; ++dt) {
      const char* vp = VlsC + (dt * 16 + c) * 128;
      const short8 va0 = *(const short8*)(vp + ((g << 4) ^ swc));
      const short8 va1 = *(const short8*)(vp + ((64 + (g << 4)) ^ swc));
#pragma unroll
      for (int qs = 0; qs < 2; ++qs) {
        Of[qs][dt] = __builtin_amdgcn_mfma_f32_16x16x32_bf16(va0, pb[qs][0], Of[qs][dt], 0, 0, 0);
        Of[qs][dt] = __builtin_amdgcn_mfma_f32_16x16x32_bf16(va1, pb[qs][1], Of[qs][dt], 0, 0, 0);
      }
    }
    __builtin_amdgcn_s_setprio(0);

    // store next tile into the other buffer, then ONE barrier flips buffers.
    if (hav) {
      *(uint4*)(KlsN + r0 * 128 + so) = ka;
      *(uint4*)(KlsN + (r0 + 32) * 128 + so) = kb2;
      *(uint4*)(VlsN + r0 * 128 + so) = va;
      *(uint4*)(VlsN + (r0 + 32) * 128 + so) = vb2;
      if (tid < 128) *(uint4*)(VlsN + (r0 + 64) * 128 + so) = vc;
    }
    __syncthreads();
  }

  const int rowbase = (sp * 4 + h) * 69;
#pragma unroll
  for (int qs = 0; qs < 2; ++qs) {
    const int qg = qbase + w * 32 + qs * 16 + c;
#pragma unroll
    for (int dt = 0; dt < 5; ++dt)
#pragma unroll
      for (int r = 0; r < 4; ++r) {
        const int dv = dt * 16 + (g << 2) + r;
        if (dv < 67) Opart[(size_t)(rowbase + dv) * NN + qg] = Of[qs][dt][r];
      }
    if (g == 0) {
      Opart[(size_t)(rowbase + 67) * NN + qg] = mrun[qs];  // log2-domain max
      Opart[(size_t)(rowbase + 68) * NN + qg] = lrun[qs];
    }
  }
}

// ---------------- combine splits + augment, write Yt bf16 [NN][288] directly ----------------
// grid (256), block 256: q-chunk of 16; workers = 4 h x 4 dv-groups. NS = compile-time nsplit.
template <int NS>
__global__ __launch_bounds__(256) void combine_t_kernel(
    const float* __restrict__ Opart, const float* __restrict__ coords0,
    unsigned short* __restrict__ Yt) {
  __shared__ __align__(16) unsigned char Yl[16 * 640];  // [16 q][320 ushort], XOR-swizzled
  const int t = threadIdx.x;
  const int q = t & 15;
  const int worker = t >> 4;       // 0..15
  const int h = worker & 3;
  const int dgrp = worker >> 2;    // 0..3
  const int q0 = blockIdx.x << 4;
  const int qg = q0 + q;
  const int rowb = q * 640;
  const int sw = (q & 7) << 4;

  float m[NS], wgt[NS], lv[NS];
  float M = -1e30f;
#pragma unroll
  for (int s = 0; s < NS; ++s)
    m[s] = Opart[((size_t)(s * 4 + h) * 69 + 67) * NN + qg];
#pragma unroll
  for (int s = 0; s < NS; ++s)
    lv[s] = Opart[((size_t)(s * 4 + h) * 69 + 68) * NN + qg];
#pragma unroll
  for (int s = 0; s < NS; ++s) M = fmaxf(M, m[s]);
  float L = 0.f;
#pragma unroll
  for (int s = 0; s < NS; ++s) {
    wgt[s] = __builtin_amdgcn_exp2f(m[s] - M);  // m is log2-domain
    L += lv[s] * wgt[s];
  }
  const float invL = 1.f / L;
#pragma unroll
  for (int s = 0; s < NS; ++s) wgt[s] *= invL;

  if (worker == 0) *(uint2*)(Yl + rowb + (568 ^ sw)) = make_uint2(0u, 0u);  // pad cols 284..287

  const int dv0 = dgrp * 17;
  const int dv1 = (dgrp == 3) ? 67 : dv0 + 17;
  float ss = 0.f;
#pragma unroll 2
  for (int dv = dv0; dv < dv1; ++dv) {
    float vals[NS];
#pragma unroll
    for (int s = 0; s < NS; ++s)
      vals[s] = Opart[((size_t)(s * 4 + h) * 69 + dv) * NN + qg];
    float a = 0.f;
#pragma unroll
    for (int s = 0; s < NS; ++s) a += vals[s] * wgt[s];
    *(unsigned short*)(Yl + rowb + ((((dv << 2) + h) << 1) ^ sw)) = f2bf(a);
    if (dv >= 64) {
      const float au = a - coords0[(size_t)(dv - 64) * NN + qg];
      *(unsigned short*)(Yl + rowb + (((((dv + 3) << 2) + h) << 1) ^ sw)) = f2bf(au);
      ss += au * au;
    }
  }
  if (dgrp == 3) *(unsigned short*)(Yl + rowb + (((280 + h) << 1) ^ sw)) = f2bf(sqrtf(ss));
  __syncthreads();

  for (int i = t; i < 16 * 36; i += 256) {
    const int row = i / 36, seg = i - row * 36;
    *(uint4*)(Yt + (size_t)(q0 + row) * 288 + (seg << 3)) =
        *(const uint4*)(Yl + row * 640 + ((seg << 4) ^ ((row & 7) << 4)));
  }
}

// ---------------- MFMA out projection: out = Wm(284x284) . y + bm ----------------
// grid (NN/64, 5), block 256 = 4 waves (2x2). BM=64, BN=64, BK=96, K=288.
#define OP_LOAD(k0_) do { \
  const int arow = co0 + ar; \
  _Pragma("unroll") for (int i = 0; i < 6; ++i) { \
    const int col = (k0_) + ac + 4 * i; \
    wa[i] = (arow < 284 && col < 284) ? *(const float4*)(Wm + (size_t)arow * 284 + col) \
                                      : make_float4(0.f, 0.f, 0.f, 0.f); \
  } \
  _Pragma("unroll") for (int i = 0; i < 3; ++i) \
    wb[i] = *(const uint4*)(Yt + (size_t)(n0 + bn) * 288 + (k0_) + bc + 8 * i); \
} while (0)

#define OP_WRITE_LDS() do { \
  unsigned pk[12]; \
  _Pragma("unroll") for (int i = 0; i < 6; ++i) { \
    pk[2 * i] = packpair(wa[i].x, wa[i].y); \
    pk[2 * i + 1] = packpair(wa[i].z, wa[i].w); \
  } \
  _Pragma("unroll") for (int i = 0; i < 3; ++i) \
    *(uint4*)(Al + ar * 256 + (((ac << 1) + (i << 4)) ^ aswz)) = *(uint4*)&pk[4 * i]; \
  _Pragma("unroll") for (int i = 0; i < 3; ++i) \
    *(uint4*)(Bl + bn * 256 + (((bc << 1) + (i << 4)) ^ bswz)) = wb[i]; \
} while (0)

__global__ __launch_bounds__(256) void outproj_gemm_kernel(
    const unsigned short* __restrict__ Yt, const float* __restrict__ Wm,
    const float* __restrict__ bm, float* __restrict__ out) {
  __shared__ __align__(16) unsigned char smem[32768];  // Al 64x256B | Bl 64x256B
  __shared__ float Bls[64];
  const int co0 = blockIdx.y << 6;
  const int n0 = blockIdx.x << 6;
  const int tid = threadIdx.x;
  const int w = tid >> 6, l = tid & 63;
  const int wm = w >> 1, wn = w & 1;
  const int c = l & 15, g = l >> 4;
  char* const Al = (char*)smem;
  char* const Bl = (char*)smem + 16384;

  if (tid < 64) { const int co = co0 + tid; Bls[tid] = (co < 284) ? bm[co] : 0.f; }

  const int ar = tid >> 2, ac = (tid & 3) * 24;  // A: 64 rows x 96 f32, 4 thr/row
  const int bn = tid >> 2, bc = (tid & 3) * 24;  // B: 64 rows x 96 bf16, 4 thr/row
  const int aswz = (ar & 7) << 4;
  const int bswz = (bn & 7) << 4;

  float4 wa[6];
  uint4 wb[3];
  f32x4 acc[2][2];
#pragma unroll
  for (int mf = 0; mf < 2; ++mf)
#pragma unroll
    for (int nf = 0; nf < 2; ++nf) acc[mf][nf] = (f32x4){0.f, 0.f, 0.f, 0.f};

  OP_LOAD(0);
  OP_WRITE_LDS();
  __syncthreads();

  for (int s = 0; s < 3; ++s) {
    const bool hav = (s + 1 < 3);
    if (hav) OP_LOAD((s + 1) * 96);
    __builtin_amdgcn_s_setprio(1);
#pragma unroll
    for (int ks = 0; ks < 3; ++ks) {
      short8 af[2], bf[2];
#pragma unroll
      for (int mf = 0; mf < 2; ++mf) {
        const int row = wm * 32 + mf * 16 + c;
        af[mf] = *(const short8*)(Al + row * 256 + (((ks << 6) + (g << 4)) ^ ((row & 7) << 4)));
      }
#pragma unroll
      for (int nf = 0; nf < 2; ++nf) {
        const int row = wn * 32 + nf * 16 + c;
        bf[nf] = *(const short8*)(Bl + row * 256 + (((ks << 6) + (g << 4)) ^ ((row & 7) << 4)));
      }
#pragma unroll
      for (int mf = 0; mf < 2; ++mf)
#pragma unroll
        for (int nf = 0; nf < 2; ++nf)
          acc[mf][nf] = __builtin_amdgcn_mfma_f32_16x16x32_bf16(af[mf], bf[nf], acc[mf][nf], 0, 0, 0);
    }
    __builtin_amdgcn_s_setprio(0);
    __syncthreads();
    if (hav) {
      OP_WRITE_LDS();
      __syncthreads();
    }
  }

#pragma unroll
  for (int mf = 0; mf < 2; ++mf)
#pragma unroll
    for (int nf = 0; nf < 2; ++nf)
#pragma unroll
      for (int rr = 0; rr < 4; ++rr) {
        const int row = wm * 32 + mf * 16 + (g << 2) + rr;
        const int co = co0 + row;
        if (co < 284)
          out[(size_t)co * NN + n0 + wn * 32 + nf * 16 + c] = acc[mf][nf][rr] + Bls[row];
      }
}

extern "C" void kernel_launch(void* const* d_in, const int* in_sizes, int n_in,
                              void* d_out, int out_size, void* d_ws, size_t ws_size,
                              hipStream_t stream) {
  const float* query   = (const float*)d_in[0];
  const float* key_    = (const float*)d_in[1];
  const float* value   = (const float*)d_in[2];
  const float* coords0 = (const float*)d_in[3];
  const float* coords1 = (const float*)d_in[4];
  const float* Wq = (const float*)d_in[5];
  const float* bq = (const float*)d_in[6];
  const float* Wk = (const float*)d_in[7];
  const float* bk = (const float*)d_in[8];
  const float* Wv = (const float*)d_in[9];
  const float* bv = (const float*)d_in[10];
  const float* Wm = (const float*)d_in[11];
  const float* bm = (const float*)d_in[12];
  float* out = (float*)d_out;

  // ws: Qb 2MB | Kb 2MB | Vb 2.62MB | Xt 6MB | Yt 2.25MB | Opart nsplit*4.52MB
  unsigned short* Qb = (unsigned short*)d_ws;
  unsigned short* Kb = Qb + (size_t)4 * NN * 64;
  unsigned short* Vb = Kb + (size_t)4 * NN * 64;
  unsigned short* Xt = Vb + (size_t)4 * 80 * NN;
  unsigned short* Yt = Xt + (size_t)3 * NN * 256;
  float* Opart = (float*)(Yt + (size_t)NN * 288);

  const size_t fixedB = (size_t)((char*)Opart - (char*)d_ws);
  const size_t per = (size_t)4 * 69 * NN * 4;
  int nsplit = 4;
  while (nsplit > 1 && ws_size < fixedB + (size_t)nsplit * per) nsplit >>= 1;

  hipLaunchKernelGGL(transpose3_kernel, dim3(64, 4, 3), dim3(256), 0, stream,
                     query, key_, value, Xt, coords1, Vb);
  hipLaunchKernelGGL(proj_gemm_kernel, dim3(64, 4, 3), dim3(256), 0, stream,
                     Wq, bq, Wk, bk, Wv, bv, Xt, Qb, Kb, Vb);
  hipLaunchKernelGGL(attn_kernel, dim3(128 * nsplit), dim3(256), 0, stream,
                     Qb, Kb, Vb, Opart, NN / nsplit, nsplit);
  switch (nsplit) {
    case 4:
      hipLaunchKernelGGL((combine_t_kernel<4>), dim3(256), dim3(256), 0, stream, Opart, coords0, Yt);
      break;
    case 2:
      hipLaunchKernelGGL((combine_t_kernel<2>), dim3(256), dim3(256), 0, stream, Opart, coords0, Yt);
      break;
    default:
      hipLaunchKernelGGL((combine_t_kernel<1>), dim3(256), dim3(256), 0, stream, Opart, coords0, Yt);
      break;
  }
  hipLaunchKernelGGL(outproj_gemm_kernel, dim3(64, 5), dim3(256), 0, stream, Yt, Wm, bm, out);
}

// Round 12
// 81.262 us; speedup vs baseline: 2.9040x; 1.0544x over previous
//
#include <hip/hip_runtime.h>
#include <hip/hip_bf16.h>

#define NN 4096

typedef __attribute__((ext_vector_type(8))) short short8;
typedef __attribute__((ext_vector_type(4))) float f32x4;

__device__ __forceinline__ unsigned short f2bf(float f) {
  union { float f; unsigned u; } v; v.f = f;
  unsigned u = v.u;
  u += 0x7fffu + ((u >> 16) & 1u);
  return (unsigned short)(u >> 16);
}

__device__ __forceinline__ unsigned packpair(float a, float b) {
  __hip_bfloat162 h = __float22bfloat162_rn(make_float2(a, b));  // v_cvt_pk_bf16_f32
  union { __hip_bfloat162 h; unsigned u; } cv; cv.h = h;
  return cv.u;
}

// ---------------- transpose q/k/v: f32 [256][NN] -> bf16 [NN][256]; + coords fill ----------------
// grid (64, 4, 3), block 256
__global__ __launch_bounds__(256) void transpose3_kernel(
    const float* __restrict__ q, const float* __restrict__ k, const float* __restrict__ v,
    unsigned short* __restrict__ Xt, const float* __restrict__ coords1,
    unsigned short* __restrict__ Vb) {
  __shared__ float Tl[64][65];
  const float* X = (blockIdx.z == 0) ? q : (blockIdx.z == 1) ? k : v;
  unsigned short* dst = Xt + (size_t)blockIdx.z * NN * 256;
  const int n0 = blockIdx.x << 6, k0 = blockIdx.y << 6;
  const int t = threadIdx.x;
  const int r = t >> 4, c4 = (t & 15) << 2;
#pragma unroll
  for (int i = 0; i < 4; ++i) {
    const float4 vv = *(const float4*)(X + (size_t)(k0 + r + 16 * i) * NN + n0 + c4);
    Tl[r + 16 * i][c4] = vv.x; Tl[r + 16 * i][c4 + 1] = vv.y;
    Tl[r + 16 * i][c4 + 2] = vv.z; Tl[r + 16 * i][c4 + 3] = vv.w;
  }
  __syncthreads();
  const int kc = (t & 7) << 3;
#pragma unroll
  for (int j = 0; j < 2; ++j) {
    const int n = (t >> 3) + (j << 5);
    unsigned pk[4];
#pragma unroll
    for (int u = 0; u < 4; ++u)
      pk[u] = packpair(Tl[kc + 2 * u][n], Tl[kc + 2 * u + 1][n]);
    *(uint4*)(dst + (size_t)(n0 + n) * 256 + k0 + kc) = *(uint4*)pk;
  }
  // folded coords fill: V rows 64..66 = coords1, 67..79 = 0 (once per n-chunk)
  if (blockIdx.z == 2 && blockIdx.y == 0) {
    const int rr = t >> 2, seg = t & 3;
    const int h = rr >> 4, d = 64 + (rr & 15);
    unsigned short* vd = Vb + (size_t)(h * 80 + d) * NN + n0 + seg * 16;
    if (d < 67) {
      const float* src = coords1 + (size_t)(d - 64) * NN + n0 + seg * 16;
      unsigned u[8];
#pragma unroll
      for (int i = 0; i < 4; ++i) {
        const float4 cv = *(const float4*)(src + 4 * i);
        u[2 * i] = packpair(cv.x, cv.y);
        u[2 * i + 1] = packpair(cv.z, cv.w);
      }
      *(uint4*)vd = *(uint4*)&u[0];
      *(uint4*)(vd + 8) = *(uint4*)&u[4];
    } else {
      const uint4 zz = make_uint4(0u, 0u, 0u, 0u);
      *(uint4*)vd = zz;
      *(uint4*)(vd + 8) = zz;
    }
  }
}

// ---------------- MFMA projection GEMM: C = W(256x256) . X(256xNN) ----------------
// grid (NN/64, 4, 3), block 256 = 4 waves (2x2). BM=64, BN=64, BK=64.
// Q is pre-scaled by 1/sqrt(64) * log2(e) so attention softmax runs in exp2 domain.
__global__ __launch_bounds__(256) void proj_gemm_kernel(
    const float* __restrict__ Wq, const float* __restrict__ bq,
    const float* __restrict__ Wk, const float* __restrict__ bk,
    const float* __restrict__ Wv, const float* __restrict__ bv,
    const unsigned short* __restrict__ Xt,
    unsigned short* __restrict__ Qb, unsigned short* __restrict__ Kb,
    unsigned short* __restrict__ Vb) {
  __shared__ __align__(16) unsigned char smem[16384];  // Al 64x128B | Bl 64x128B
  __shared__ float Bls[64];
  const int z = blockIdx.z;
  const float* W  = (z == 0) ? Wq : (z == 1) ? Wk : Wv;
  const float* bb = (z == 0) ? bq : (z == 1) ? bk : bv;
  const unsigned short* Xz = Xt + (size_t)z * NN * 256;
  const int co0 = blockIdx.y << 6;
  const int n0 = blockIdx.x << 6;
  const int tid = threadIdx.x;
  const int w = tid >> 6, l = tid & 63;
  const int wm = w >> 1, wn = w & 1;
  const int c = l & 15, g = l >> 4;
  char* const Al = (char*)smem;
  char* const Bl = (char*)smem + 8192;

  if (tid < 64) Bls[tid] = bb[co0 + tid];

  const int ar = tid >> 2, ac = (tid & 3) << 4;  // A: 4 thr/row, 16 f32 each
  const int br = tid >> 3, bch = tid & 7;        // B: rows br, br+32
  const int aswz = (ar & 7) << 4;
  const int bswz = (br & 7) << 4;                // (br+32)&7 == br&7

  float4 wa[4];
  uint4 wb[2];
  f32x4 acc[2][2];
#pragma unroll
  for (int mf = 0; mf < 2; ++mf)
#pragma unroll
    for (int nf = 0; nf < 2; ++nf) acc[mf][nf] = (f32x4){0.f, 0.f, 0.f, 0.f};

#define PJ_LOAD(k0_) do { \
  _Pragma("unroll") for (int i = 0; i < 4; ++i) \
    wa[i] = *(const float4*)(W + (size_t)(co0 + ar) * 256 + (k0_) + ac + 4 * i); \
  wb[0] = *(const uint4*)(Xz + (size_t)(n0 + br) * 256 + (k0_) + bch * 8); \
  wb[1] = *(const uint4*)(Xz + (size_t)(n0 + br + 32) * 256 + (k0_) + bch * 8); \
} while (0)

#define PJ_STORE() do { \
  unsigned pk[8]; \
  _Pragma("unroll") for (int i = 0; i < 4; ++i) { \
    pk[2 * i] = packpair(wa[i].x, wa[i].y); \
    pk[2 * i + 1] = packpair(wa[i].z, wa[i].w); \
  } \
  *(uint4*)(Al + ar * 128 + (((ac << 1)) ^ aswz)) = *(uint4*)&pk[0]; \
  *(uint4*)(Al + ar * 128 + (((ac << 1) + 16) ^ aswz)) = *(uint4*)&pk[4]; \
  *(uint4*)(Bl + br * 128 + ((bch << 4) ^ bswz)) = wb[0]; \
  *(uint4*)(Bl + (br + 32) * 128 + ((bch << 4) ^ bswz)) = wb[1]; \
} while (0)

  PJ_LOAD(0);
  PJ_STORE();
  __syncthreads();

  for (int s = 0; s < 4; ++s) {
    const bool hav = (s + 1 < 4);
    if (hav) PJ_LOAD((s + 1) << 6);
    __builtin_amdgcn_s_setprio(1);
#pragma unroll
    for (int ks = 0; ks < 2; ++ks) {
      short8 af[2], bf[2];
#pragma unroll
      for (int mf = 0; mf < 2; ++mf) {
        const int row = wm * 32 + mf * 16 + c;
        af[mf] = *(const short8*)(Al + row * 128 + (((ks << 6) + (g << 4)) ^ ((row & 7) << 4)));
      }
#pragma unroll
      for (int nf = 0; nf < 2; ++nf) {
        const int row = wn * 32 + nf * 16 + c;
        bf[nf] = *(const short8*)(Bl + row * 128 + (((ks << 6) + (g << 4)) ^ ((row & 7) << 4)));
      }
#pragma unroll
      for (int mf = 0; mf < 2; ++mf)
#pragma unroll
        for (int nf = 0; nf < 2; ++nf)
          acc[mf][nf] = __builtin_amdgcn_mfma_f32_16x16x32_bf16(af[mf], bf[nf], acc[mf][nf], 0, 0, 0);
    }
    __builtin_amdgcn_s_setprio(0);
    __syncthreads();
    if (hav) {
      PJ_STORE();
      __syncthreads();
    }
  }

  // epilogue: acc -> LDS bounce (bf16, stride 72) -> layout-specific global writes
  unsigned short* Clu = (unsigned short*)smem;  // [64][72]
  const float scale = (z == 0) ? 0.18033688f : 1.0f;  // 0.125 * log2(e)
#pragma unroll
  for (int mf = 0; mf < 2; ++mf)
#pragma unroll
    for (int nf = 0; nf < 2; ++nf)
#pragma unroll
      for (int rr = 0; rr < 4; ++rr) {
        const int row = wm * 32 + mf * 16 + (g << 2) + rr;
        const int col = wn * 32 + nf * 16 + c;
        Clu[row * 72 + col] = f2bf((acc[mf][nf][rr] + Bls[row]) * scale);
      }
  __syncthreads();
  if (z <= 1) {
    unsigned short* Ob = (z == 0) ? Qb : Kb;
    const int d0 = co0 >> 2;
    const int h = tid >> 6, n = tid & 63;
    unsigned u[8];
#pragma unroll
    for (int p = 0; p < 8; ++p)
      u[p] = (unsigned)Clu[((p << 3) + h) * 72 + n] |
             ((unsigned)Clu[((p << 3) + 4 + h) * 72 + n] << 16);
    uint4* dd = (uint4*)(Ob + ((size_t)h * NN + n0 + n) * 64 + d0);
    dd[0] = *(uint4*)&u[0];
    dd[1] = *(uint4*)&u[4];
  } else {
    const int rl = tid >> 2, seg = (tid & 3) << 4;
    const int h = rl & 3, d = (co0 >> 2) + (rl >> 2);
    unsigned short* vd = Vb + (size_t)(h * 80 + d) * NN + n0 + seg;
    *(uint4*)vd = *(const uint4*)((char*)Clu + rl * 144 + (seg << 1));
    *(uint4*)(vd + 8) = *(const uint4*)((char*)Clu + rl * 144 + (seg << 1) + 16);
  }
}

// ---------------- fused flash attention (split-K, exp2, triple-buffer pipelined) ----------------
// 1-D grid (128*nsplit), block 256 = 4 waves. XCD-grouped decode (all 32 q-blocks of
// one (h,split) K/V chunk on one XCD). Software pipeline: softmax(i) [VALU] overlaps
// QK(i+1) [MFMA]; K/V triple-buffered so one barrier per tile suffices.
// LDS: 3 x (K 8192 | V 10240) + P 4x4096 = 71680 (2 blocks/CU)
__global__ __launch_bounds__(256, 2) void attn_kernel(
    const unsigned short* __restrict__ Qb, const unsigned short* __restrict__ Kb,
    const unsigned short* __restrict__ Vb, float* __restrict__ Opart,
    int chunkKeys, int nsplit) {
  __shared__ __align__(16) unsigned char smem[71680];
  const int b = blockIdx.x;
  int x, h, sp;
  if (nsplit >= 2) {
    const int xcd = b & 7, slot = b >> 3;
    const int group = xcd * (nsplit >> 1) + (slot >> 5);  // bijective for even nsplit
    x = slot & 31; h = group & 3; sp = group >> 2;
  } else {
    x = b & 31; h = (b >> 5) & 3; sp = 0;
  }
  const int qbase = x * 128;
  const int tid = threadIdx.x;
  const int w = tid >> 6;
  const int l = tid & 63;
  const int c = l & 15;
  const int g = l >> 4;
  const int swc = (c & 7) << 4;

  char* const Pls = (char*)smem + 55296 + w * 4096;

  short8 qf[2][2];
#pragma unroll
  for (int qs = 0; qs < 2; ++qs) {
    const unsigned short* qsrc = Qb + (((h * NN) + qbase + w * 32 + qs * 16 + c) << 6) + (g << 3);
    qf[qs][0] = *(const short8*)qsrc;
    qf[qs][1] = *(const short8*)(qsrc + 32);
  }

  f32x4 Of[2][5];
#pragma unroll
  for (int qs = 0; qs < 2; ++qs)
#pragma unroll
    for (int dt = 0; dt < 5; ++dt) Of[qs][dt] = (f32x4){0.f, 0.f, 0.f, 0.f};
  float mrun[2] = {-1e30f, -1e30f};
  float lrun[2] = {0.f, 0.f};

  const int r0 = tid >> 3, ch = tid & 7;
  const int so = (ch << 4) ^ ((r0 & 7) << 4);
  const int mStart = sp * chunkKeys;
  const int niter = chunkKeys >> 6;  // even (>= 16)

  uint4 ska, skb, sva, svb, svc;

#define LOADT(m0_) do { \
    const unsigned short* kbase_ = Kb + ((h * NN + (m0_)) << 6); \
    const unsigned short* vbase_ = Vb + (size_t)(h * 80) * NN + (m0_); \
    ska = *(const uint4*)(kbase_ + (r0 << 6) + (ch << 3)); \
    skb = *(const uint4*)(kbase_ + ((r0 + 32) << 6) + (ch << 3)); \
    sva = *(const uint4*)(vbase_ + (size_t)r0 * NN + (ch << 3)); \
    svb = *(const uint4*)(vbase_ + (size_t)(r0 + 32) * NN + (ch << 3)); \
    if (tid < 128) svc = *(const uint4*)(vbase_ + (size_t)(r0 + 64) * NN + (ch << 3)); \
  } while (0)

#define STORET(bj_) do { \
    char* Kd_ = (char*)smem + (bj_) * 18432; \
    char* Vd_ = Kd_ + 8192; \
    *(uint4*)(Kd_ + r0 * 128 + so) = ska; \
    *(uint4*)(Kd_ + (r0 + 32) * 128 + so) = skb; \
    *(uint4*)(Vd_ + r0 * 128 + so) = sva; \
    *(uint4*)(Vd_ + (r0 + 32) * 128 + so) = svb; \
    if (tid < 128) *(uint4*)(Vd_ + (r0 + 64) * 128 + so) = svc; \
  } while (0)

#define QKSTEP(bj_, DST) do { \
    const char* Kc_ = (char*)smem + (bj_) * 18432; \
    __builtin_amdgcn_s_setprio(1); \
    _Pragma("unroll") for (int t = 0; t < 4; ++t) { \
      const char* rp_ = Kc_ + (t * 16 + c) * 128; \
      const short8 k0_ = *(const short8*)(rp_ + ((g << 4) ^ swc)); \
      const short8 k1_ = *(const short8*)(rp_ + ((64 + (g << 4)) ^ swc)); \
      _Pragma("unroll") for (int qs = 0; qs < 2; ++qs) { \
        f32x4 a_ = (f32x4){0.f, 0.f, 0.f, 0.f}; \
        a_ = __builtin_amdgcn_mfma_f32_16x16x32_bf16(k0_, qf[qs][0], a_, 0, 0, 0); \
        a_ = __builtin_amdgcn_mfma_f32_16x16x32_bf16(k1_, qf[qs][1], a_, 0, 0, 0); \
        DST[qs][t] = a_; \
      } \
    } \
    __builtin_amdgcn_s_setprio(0); \
  } while (0)

#define SMSTEP(SRC) do { \
    _Pragma("unroll") for (int qs = 0; qs < 2; ++qs) { \
      float m01_ = fmaxf(fmaxf(SRC[qs][0][0], SRC[qs][0][1]), fmaxf(SRC[qs][0][2], SRC[qs][0][3])); \
      float m11_ = fmaxf(fmaxf(SRC[qs][1][0], SRC[qs][1][1]), fmaxf(SRC[qs][1][2], SRC[qs][1][3])); \
      float m21_ = fmaxf(fmaxf(SRC[qs][2][0], SRC[qs][2][1]), fmaxf(SRC[qs][2][2], SRC[qs][2][3])); \
      float m31_ = fmaxf(fmaxf(SRC[qs][3][0], SRC[qs][3][1]), fmaxf(SRC[qs][3][2], SRC[qs][3][3])); \
      float mx_ = fmaxf(fmaxf(m01_, m11_), fmaxf(m21_, m31_)); \
      mx_ = fmaxf(mx_, __shfl_xor(mx_, 16)); \
      mx_ = fmaxf(mx_, __shfl_xor(mx_, 32)); \
      if (!__all(mx_ - mrun[qs] <= 11.5f)) { \
        const float mn_ = fmaxf(mrun[qs], mx_); \
        const float a_ = __builtin_amdgcn_exp2f(mrun[qs] - mn_); \
        mrun[qs] = mn_; \
        lrun[qs] *= a_; \
        _Pragma("unroll") for (int dt = 0; dt < 5; ++dt) \
          _Pragma("unroll") for (int r = 0; r < 4; ++r) Of[qs][dt][r] *= a_; \
      } \
      const float mm_ = mrun[qs]; \
      float rs_ = 0.f; \
      unsigned pk_[8]; \
      _Pragma("unroll") for (int t = 0; t < 4; ++t) { \
        const float e0_ = __builtin_amdgcn_exp2f(SRC[qs][t][0] - mm_); \
        const float e1_ = __builtin_amdgcn_exp2f(SRC[qs][t][1] - mm_); \
        const float e2_ = __builtin_amdgcn_exp2f(SRC[qs][t][2] - mm_); \
        const float e3_ = __builtin_amdgcn_exp2f(SRC[qs][t][3] - mm_); \
        rs_ += (e0_ + e1_) + (e2_ + e3_); \
        pk_[t * 2]     = packpair(e0_, e1_); \
        pk_[t * 2 + 1] = packpair(e2_, e3_); \
      } \
      rs_ += __shfl_xor(rs_, 16); \
      rs_ += __shfl_xor(rs_, 32); \
      lrun[qs] += rs_; \
      char* prow_ = Pls + (qs * 16 + c) * 128; \
      _Pragma("unroll") for (int t = 0; t < 4; ++t) \
        *(uint2*)(prow_ + ((t * 32 + (g << 3)) ^ swc)) = make_uint2(pk_[t * 2], pk_[t * 2 + 1]); \
    } \
  } while (0)

#define PVSTEP(bj_) do { \
    short8 pb_[2][2]; \
    _Pragma("unroll") for (int qs = 0; qs < 2; ++qs) { \
      const char* prow_ = Pls + (qs * 16 + c) * 128; \
      pb_[qs][0] = *(const short8*)(prow_ + ((g << 4) ^ swc)); \
      pb_[qs][1] = *(const short8*)(prow_ + ((64 + (g << 4)) ^ swc)); \
    } \
    const char* Vc_ = (char*)smem + (bj_) * 18432 + 8192; \
    __builtin_amdgcn_s_setprio(1); \
    _Pragma("unroll") for (int dt = 0; dt < 5; ++dt) { \
      const char* vp_ = Vc_ + (dt * 16 + c) * 128; \
      const short8 v0_ = *(const short8*)(vp_ + ((g << 4) ^ swc)); \
      const short8 v1_ = *(const short8*)(vp_ + ((64 + (g << 4)) ^ swc)); \
      _Pragma("unroll") for (int qs = 0; qs < 2; ++qs) { \
        Of[qs][dt] = __builtin_amdgcn_mfma_f32_16x16x32_bf16(v0_, pb_[qs][0], Of[qs][dt], 0, 0, 0); \
        Of[qs][dt] = __builtin_amdgcn_mfma_f32_16x16x32_bf16(v1_, pb_[qs][1], Of[qs][dt], 0, 0, 0); \
      } \
    } \
    __builtin_amdgcn_s_setprio(0); \
  } while (0)

  f32x4 sD0[2][4], sD1[2][4];

  // ---- prologue: tile0 -> buf0; QK(0); tile1 -> buf1; tile2 loads in regs ----
  LOADT(mStart);
  STORET(0);
  LOADT(mStart + 64);
  __syncthreads();                 // buf0 ready
  QKSTEP(0, sD0);                  // QK(0)
  STORET(1);                       // tile1 -> buf1
  LOADT(mStart + 128);             // tile2 loads in flight (niter >= 16)
  __syncthreads();                 // buf1 ready

  for (int it = 0; it < niter; it += 2) {
    // ---- even half: current sD0 (tile it) ----
    SMSTEP(sD0);                                   // softmax(it) [VALU]
    QKSTEP((it + 1) % 3, sD1);                     // QK(it+1)    [MFMA] - independent
    PVSTEP(it % 3);                                // PV(it)
    if (it + 2 < niter) {
      STORET((it + 2) % 3);                        // tile(it+2) -> its buffer
      if (it + 3 < niter) LOADT(mStart + ((it + 3) << 6));
    }
    __syncthreads();
    // ---- odd half: current sD1 (tile it+1) ----
    SMSTEP(sD1);
    if (it + 2 < niter) QKSTEP((it + 2) % 3, sD0);
    PVSTEP((it + 1) % 3);
    if (it + 3 < niter) {
      STORET((it + 3) % 3);
      if (it + 4 < niter) LOADT(mStart + ((it + 4) << 6));
    }
    __syncthreads();
  }

#undef LOADT
#undef STORET
#undef QKSTEP
#undef SMSTEP
#undef PVSTEP

  const int rowbase = (sp * 4 + h) * 69;
#pragma unroll
  for (int qs = 0; qs < 2; ++qs) {
    const int qg = qbase + w * 32 + qs * 16 + c;
#pragma unroll
    for (int dt = 0; dt < 5; ++dt)
#pragma unroll
      for (int r = 0; r < 4; ++r) {
        const int dv = dt * 16 + (g << 2) + r;
        if (dv < 67) Opart[(size_t)(rowbase + dv) * NN + qg] = Of[qs][dt][r];
      }
    if (g == 0) {
      Opart[(size_t)(rowbase + 67) * NN + qg] = mrun[qs];  // log2-domain max
      Opart[(size_t)(rowbase + 68) * NN + qg] = lrun[qs];
    }
  }
}

// ---------------- combine splits + augment, write Yt bf16 [NN][288] directly ----------------
// grid (256), block 256: q-chunk of 16; workers = 4 h x 4 dv-groups. NS = compile-time nsplit.
template <int NS>
__global__ __launch_bounds__(256) void combine_t_kernel(
    const float* __restrict__ Opart, const float* __restrict__ coords0,
    unsigned short* __restrict__ Yt) {
  __shared__ __align__(16) unsigned char Yl[16 * 640];  // [16 q][320 ushort], XOR-swizzled
  const int t = threadIdx.x;
  const int q = t & 15;
  const int worker = t >> 4;       // 0..15
  const int h = worker & 3;
  const int dgrp = worker >> 2;    // 0..3
  const int q0 = blockIdx.x << 4;
  const int qg = q0 + q;
  const int rowb = q * 640;
  const int sw = (q & 7) << 4;

  float m[NS], wgt[NS], lv[NS];
  float M = -1e30f;
#pragma unroll
  for (int s = 0; s < NS; ++s)
    m[s] = Opart[((size_t)(s * 4 + h) * 69 + 67) * NN + qg];
#pragma unroll
  for (int s = 0; s < NS; ++s)
    lv[s] = Opart[((size_t)(s * 4 + h) * 69 + 68) * NN + qg];
#pragma unroll
  for (int s = 0; s < NS; ++s) M = fmaxf(M, m[s]);
  float L = 0.f;
#pragma unroll
  for (int s = 0; s < NS; ++s) {
    wgt[s] = __builtin_amdgcn_exp2f(m[s] - M);  // m is log2-domain
    L += lv[s] * wgt[s];
  }
  const float invL = 1.f / L;
#pragma unroll
  for (int s = 0; s < NS; ++s) wgt[s] *= invL;

  if (worker == 0) *(uint2*)(Yl + rowb + (568 ^ sw)) = make_uint2(0u, 0u);  // pad cols 284..287

  const int dv0 = dgrp * 17;
  const int dv1 = (dgrp == 3) ? 67 : dv0 + 17;
  float ss = 0.f;
#pragma unroll 2
  for (int dv = dv0; dv < dv1; ++dv) {
    float vals[NS];
#pragma unroll
    for (int s = 0; s < NS; ++s)
      vals[s] = Opart[((size_t)(s * 4 + h) * 69 + dv) * NN + qg];
    float a = 0.f;
#pragma unroll
    for (int s = 0; s < NS; ++s) a += vals[s] * wgt[s];
    *(unsigned short*)(Yl + rowb + ((((dv << 2) + h) << 1) ^ sw)) = f2bf(a);
    if (dv >= 64) {
      const float au = a - coords0[(size_t)(dv - 64) * NN + qg];
      *(unsigned short*)(Yl + rowb + (((((dv + 3) << 2) + h) << 1) ^ sw)) = f2bf(au);
      ss += au * au;
    }
  }
  if (dgrp == 3) *(unsigned short*)(Yl + rowb + (((280 + h) << 1) ^ sw)) = f2bf(sqrtf(ss));
  __syncthreads();

  for (int i = t; i < 16 * 36; i += 256) {
    const int row = i / 36, seg = i - row * 36;
    *(uint4*)(Yt + (size_t)(q0 + row) * 288 + (seg << 3)) =
        *(const uint4*)(Yl + row * 640 + ((seg << 4) ^ ((row & 7) << 4)));
  }
}

// ---------------- MFMA out projection: out = Wm(284x284) . y + bm ----------------
// grid (NN/64, 5), block 256 = 4 waves (2x2). BM=64, BN=64, BK=96, K=288.
#define OP_LOAD(k0_) do { \
  const int arow = co0 + ar; \
  _Pragma("unroll") for (int i = 0; i < 6; ++i) { \
    const int col = (k0_) + ac + 4 * i; \
    wa[i] = (arow < 284 && col < 284) ? *(const float4*)(Wm + (size_t)arow * 284 + col) \
                                      : make_float4(0.f, 0.f, 0.f, 0.f); \
  } \
  _Pragma("unroll") for (int i = 0; i < 3; ++i) \
    wb[i] = *(const uint4*)(Yt + (size_t)(n0 + bn) * 288 + (k0_) + bc + 8 * i); \
} while (0)

#define OP_WRITE_LDS() do { \
  unsigned pk[12]; \
  _Pragma("unroll") for (int i = 0; i < 6; ++i) { \
    pk[2 * i] = packpair(wa[i].x, wa[i].y); \
    pk[2 * i + 1] = packpair(wa[i].z, wa[i].w); \
  } \
  _Pragma("unroll") for (int i = 0; i < 3; ++i) \
    *(uint4*)(Al + ar * 256 + (((ac << 1) + (i << 4)) ^ aswz)) = *(uint4*)&pk[4 * i]; \
  _Pragma("unroll") for (int i = 0; i < 3; ++i) \
    *(uint4*)(Bl + bn * 256 + (((bc << 1) + (i << 4)) ^ bswz)) = wb[i]; \
} while (0)

__global__ __launch_bounds__(256) void outproj_gemm_kernel(
    const unsigned short* __restrict__ Yt, const float* __restrict__ Wm,
    const float* __restrict__ bm, float* __restrict__ out) {
  __shared__ __align__(16) unsigned char smem[32768];  // Al 64x256B | Bl 64x256B
  __shared__ float Bls[64];
  const int co0 = blockIdx.y << 6;
  const int n0 = blockIdx.x << 6;
  const int tid = threadIdx.x;
  const int w = tid >> 6, l = tid & 63;
  const int wm = w >> 1, wn = w & 1;
  const int c = l & 15, g = l >> 4;
  char* const Al = (char*)smem;
  char* const Bl = (char*)smem + 16384;

  if (tid < 64) { const int co = co0 + tid; Bls[tid] = (co < 284) ? bm[co] : 0.f; }

  const int ar = tid >> 2, ac = (tid & 3) * 24;  // A: 64 rows x 96 f32, 4 thr/row
  const int bn = tid >> 2, bc = (tid & 3) * 24;  // B: 64 rows x 96 bf16, 4 thr/row
  const int aswz = (ar & 7) << 4;
  const int bswz = (bn & 7) << 4;

  float4 wa[6];
  uint4 wb[3];
  f32x4 acc[2][2];
#pragma unroll
  for (int mf = 0; mf < 2; ++mf)
#pragma unroll
    for (int nf = 0; nf < 2; ++nf) acc[mf][nf] = (f32x4){0.f, 0.f, 0.f, 0.f};

  OP_LOAD(0);
  OP_WRITE_LDS();
  __syncthreads();

  for (int s = 0; s < 3; ++s) {
    const bool hav = (s + 1 < 3);
    if (hav) OP_LOAD((s + 1) * 96);
    __builtin_amdgcn_s_setprio(1);
#pragma unroll
    for (int ks = 0; ks < 3; ++ks) {
      short8 af[2], bf[2];
#pragma unroll
      for (int mf = 0; mf < 2; ++mf) {
        const int row = wm * 32 + mf * 16 + c;
        af[mf] = *(const short8*)(Al + row * 256 + (((ks << 6) + (g << 4)) ^ ((row & 7) << 4)));
      }
#pragma unroll
      for (int nf = 0; nf < 2; ++nf) {
        const int row = wn * 32 + nf * 16 + c;
        bf[nf] = *(const short8*)(Bl + row * 256 + (((ks << 6) + (g << 4)) ^ ((row & 7) << 4)));
      }
#pragma unroll
      for (int mf = 0; mf < 2; ++mf)
#pragma unroll
        for (int nf = 0; nf < 2; ++nf)
          acc[mf][nf] = __builtin_amdgcn_mfma_f32_16x16x32_bf16(af[mf], bf[nf], acc[mf][nf], 0, 0, 0);
    }
    __builtin_amdgcn_s_setprio(0);
    __syncthreads();
    if (hav) {
      OP_WRITE_LDS();
      __syncthreads();
    }
  }

#pragma unroll
  for (int mf = 0; mf < 2; ++mf)
#pragma unroll
    for (int nf = 0; nf < 2; ++nf)
#pragma unroll
      for (int rr = 0; rr < 4; ++rr) {
        const int row = wm * 32 + mf * 16 + (g << 2) + rr;
        const int co = co0 + row;
        if (co < 284)
          out[(size_t)co * NN + n0 + wn * 32 + nf * 16 + c] = acc[mf][nf][rr] + Bls[row];
      }
}

extern "C" void kernel_launch(void* const* d_in, const int* in_sizes, int n_in,
                              void* d_out, int out_size, void* d_ws, size_t ws_size,
                              hipStream_t stream) {
  const float* query   = (const float*)d_in[0];
  const float* key_    = (const float*)d_in[1];
  const float* value   = (const float*)d_in[2];
  const float* coords0 = (const float*)d_in[3];
  const float* coords1 = (const float*)d_in[4];
  const float* Wq = (const float*)d_in[5];
  const float* bq = (const float*)d_in[6];
  const float* Wk = (const float*)d_in[7];
  const float* bk = (const float*)d_in[8];
  const float* Wv = (const float*)d_in[9];
  const float* bv = (const float*)d_in[10];
  const float* Wm = (const float*)d_in[11];
  const float* bm = (const float*)d_in[12];
  float* out = (float*)d_out;

  // ws: Qb 2MB | Kb 2MB | Vb 2.62MB | Xt 6MB | Yt 2.25MB | Opart nsplit*4.52MB
  unsigned short* Qb = (unsigned short*)d_ws;
  unsigned short* Kb = Qb + (size_t)4 * NN * 64;
  unsigned short* Vb = Kb + (size_t)4 * NN * 64;
  unsigned short* Xt = Vb + (size_t)4 * 80 * NN;
  unsigned short* Yt = Xt + (size_t)3 * NN * 256;
  float* Opart = (float*)(Yt + (size_t)NN * 288);

  const size_t fixedB = (size_t)((char*)Opart - (char*)d_ws);
  const size_t per = (size_t)4 * 69 * NN * 4;
  int nsplit = 4;
  while (nsplit > 1 && ws_size < fixedB + (size_t)nsplit * per) nsplit >>= 1;

  hipLaunchKernelGGL(transpose3_kernel, dim3(64, 4, 3), dim3(256), 0, stream,
                     query, key_, value, Xt, coords1, Vb);
  hipLaunchKernelGGL(proj_gemm_kernel, dim3(64, 4, 3), dim3(256), 0, stream,
                     Wq, bq, Wk, bk, Wv, bv, Xt, Qb, Kb, Vb);
  hipLaunchKernelGGL(attn_kernel, dim3(128 * nsplit), dim3(256), 0, stream,
                     Qb, Kb, Vb, Opart, NN / nsplit, nsplit);
  switch (nsplit) {
    case 4:
      hipLaunchKernelGGL((combine_t_kernel<4>), dim3(256), dim3(256), 0, stream, Opart, coords0, Yt);
      break;
    case 2:
      hipLaunchKernelGGL((combine_t_kernel<2>), dim3(256), dim3(256), 0, stream, Opart, coords0, Yt);
      break;
    default:
      hipLaunchKernelGGL((combine_t_kernel<1>), dim3(256), dim3(256), 0, stream, Opart, coords0, Yt);
      break;
  }
  hipLaunchKernelGGL(outproj_gemm_kernel, dim3(64, 5), dim3(256), 0, stream, Yt, Wm, bm, out);
}

// Round 13
// 75.839 us; speedup vs baseline: 3.1117x; 1.0715x over previous
//
#include <hip/hip_runtime.h>
#include <hip/hip_bf16.h>

#define NN 4096

typedef __attribute__((ext_vector_type(8))) short short8;
typedef __attribute__((ext_vector_type(4))) float f32x4;

__device__ __forceinline__ unsigned short f2bf(float f) {
  union { float f; unsigned u; } v; v.f = f;
  unsigned u = v.u;
  u += 0x7fffu + ((u >> 16) & 1u);
  return (unsigned short)(u >> 16);
}

__device__ __forceinline__ unsigned packpair(float a, float b) {
  __hip_bfloat162 h = __float22bfloat162_rn(make_float2(a, b));  // v_cvt_pk_bf16_f32
  union { __hip_bfloat162 h; unsigned u; } cv; cv.h = h;
  return cv.u;
}

__device__ __forceinline__ float bf2f(unsigned short us) {
  union { unsigned u; float f; } cv; cv.u = (unsigned)us << 16;
  return cv.f;
}

// ---------------- transpose q/k/v: f32 [256][NN] -> bf16 [NN][256]; + coords fill ----------------
// grid (64, 4, 3), block 256
__global__ __launch_bounds__(256) void transpose3_kernel(
    const float* __restrict__ q, const float* __restrict__ k, const float* __restrict__ v,
    unsigned short* __restrict__ Xt, const float* __restrict__ coords1,
    unsigned short* __restrict__ Vb) {
  __shared__ float Tl[64][65];
  const float* X = (blockIdx.z == 0) ? q : (blockIdx.z == 1) ? k : v;
  unsigned short* dst = Xt + (size_t)blockIdx.z * NN * 256;
  const int n0 = blockIdx.x << 6, k0 = blockIdx.y << 6;
  const int t = threadIdx.x;
  const int r = t >> 4, c4 = (t & 15) << 2;
#pragma unroll
  for (int i = 0; i < 4; ++i) {
    const float4 vv = *(const float4*)(X + (size_t)(k0 + r + 16 * i) * NN + n0 + c4);
    Tl[r + 16 * i][c4] = vv.x; Tl[r + 16 * i][c4 + 1] = vv.y;
    Tl[r + 16 * i][c4 + 2] = vv.z; Tl[r + 16 * i][c4 + 3] = vv.w;
  }
  __syncthreads();
  const int kc = (t & 7) << 3;
#pragma unroll
  for (int j = 0; j < 2; ++j) {
    const int n = (t >> 3) + (j << 5);
    unsigned pk[4];
#pragma unroll
    for (int u = 0; u < 4; ++u)
      pk[u] = packpair(Tl[kc + 2 * u][n], Tl[kc + 2 * u + 1][n]);
    *(uint4*)(dst + (size_t)(n0 + n) * 256 + k0 + kc) = *(uint4*)pk;
  }
  // folded coords fill: V rows 64..66 = coords1, 67..79 = 0 (once per n-chunk)
  if (blockIdx.z == 2 && blockIdx.y == 0) {
    const int rr = t >> 2, seg = t & 3;
    const int h = rr >> 4, d = 64 + (rr & 15);
    unsigned short* vd = Vb + (size_t)(h * 80 + d) * NN + n0 + seg * 16;
    if (d < 67) {
      const float* src = coords1 + (size_t)(d - 64) * NN + n0 + seg * 16;
      unsigned u[8];
#pragma unroll
      for (int i = 0; i < 4; ++i) {
        const float4 cv = *(const float4*)(src + 4 * i);
        u[2 * i] = packpair(cv.x, cv.y);
        u[2 * i + 1] = packpair(cv.z, cv.w);
      }
      *(uint4*)vd = *(uint4*)&u[0];
      *(uint4*)(vd + 8) = *(uint4*)&u[4];
    } else {
      const uint4 zz = make_uint4(0u, 0u, 0u, 0u);
      *(uint4*)vd = zz;
      *(uint4*)(vd + 8) = zz;
    }
  }
}

// ---------------- MFMA projection GEMM: C = W(256x256) . X(256xNN) ----------------
// grid (NN/64, 4, 3), block 256 = 4 waves (2x2). BM=64, BN=64, BK=64.
// Q is pre-scaled by 1/sqrt(64) * log2(e) so attention softmax runs in exp2 domain.
__global__ __launch_bounds__(256) void proj_gemm_kernel(
    const float* __restrict__ Wq, const float* __restrict__ bq,
    const float* __restrict__ Wk, const float* __restrict__ bk,
    const float* __restrict__ Wv, const float* __restrict__ bv,
    const unsigned short* __restrict__ Xt,
    unsigned short* __restrict__ Qb, unsigned short* __restrict__ Kb,
    unsigned short* __restrict__ Vb) {
  __shared__ __align__(16) unsigned char smem[16384];  // Al 64x128B | Bl 64x128B
  __shared__ float Bls[64];
  const int z = blockIdx.z;
  const float* W  = (z == 0) ? Wq : (z == 1) ? Wk : Wv;
  const float* bb = (z == 0) ? bq : (z == 1) ? bk : bv;
  const unsigned short* Xz = Xt + (size_t)z * NN * 256;
  const int co0 = blockIdx.y << 6;
  const int n0 = blockIdx.x << 6;
  const int tid = threadIdx.x;
  const int w = tid >> 6, l = tid & 63;
  const int wm = w >> 1, wn = w & 1;
  const int c = l & 15, g = l >> 4;
  char* const Al = (char*)smem;
  char* const Bl = (char*)smem + 8192;

  if (tid < 64) Bls[tid] = bb[co0 + tid];

  const int ar = tid >> 2, ac = (tid & 3) << 4;  // A: 4 thr/row, 16 f32 each
  const int br = tid >> 3, bch = tid & 7;        // B: rows br, br+32
  const int aswz = (ar & 7) << 4;
  const int bswz = (br & 7) << 4;                // (br+32)&7 == br&7

  float4 wa[4];
  uint4 wb[2];
  f32x4 acc[2][2];
#pragma unroll
  for (int mf = 0; mf < 2; ++mf)
#pragma unroll
    for (int nf = 0; nf < 2; ++nf) acc[mf][nf] = (f32x4){0.f, 0.f, 0.f, 0.f};

#define PJ_LOAD(k0_) do { \
  _Pragma("unroll") for (int i = 0; i < 4; ++i) \
    wa[i] = *(const float4*)(W + (size_t)(co0 + ar) * 256 + (k0_) + ac + 4 * i); \
  wb[0] = *(const uint4*)(Xz + (size_t)(n0 + br) * 256 + (k0_) + bch * 8); \
  wb[1] = *(const uint4*)(Xz + (size_t)(n0 + br + 32) * 256 + (k0_) + bch * 8); \
} while (0)

#define PJ_STORE() do { \
  unsigned pk[8]; \
  _Pragma("unroll") for (int i = 0; i < 4; ++i) { \
    pk[2 * i] = packpair(wa[i].x, wa[i].y); \
    pk[2 * i + 1] = packpair(wa[i].z, wa[i].w); \
  } \
  *(uint4*)(Al + ar * 128 + (((ac << 1)) ^ aswz)) = *(uint4*)&pk[0]; \
  *(uint4*)(Al + ar * 128 + (((ac << 1) + 16) ^ aswz)) = *(uint4*)&pk[4]; \
  *(uint4*)(Bl + br * 128 + ((bch << 4) ^ bswz)) = wb[0]; \
  *(uint4*)(Bl + (br + 32) * 128 + ((bch << 4) ^ bswz)) = wb[1]; \
} while (0)

  PJ_LOAD(0);
  PJ_STORE();
  __syncthreads();

  for (int s = 0; s < 4; ++s) {
    const bool hav = (s + 1 < 4);
    if (hav) PJ_LOAD((s + 1) << 6);
    __builtin_amdgcn_s_setprio(1);
#pragma unroll
    for (int ks = 0; ks < 2; ++ks) {
      short8 af[2], bf[2];
#pragma unroll
      for (int mf = 0; mf < 2; ++mf) {
        const int row = wm * 32 + mf * 16 + c;
        af[mf] = *(const short8*)(Al + row * 128 + (((ks << 6) + (g << 4)) ^ ((row & 7) << 4)));
      }
#pragma unroll
      for (int nf = 0; nf < 2; ++nf) {
        const int row = wn * 32 + nf * 16 + c;
        bf[nf] = *(const short8*)(Bl + row * 128 + (((ks << 6) + (g << 4)) ^ ((row & 7) << 4)));
      }
#pragma unroll
      for (int mf = 0; mf < 2; ++mf)
#pragma unroll
        for (int nf = 0; nf < 2; ++nf)
          acc[mf][nf] = __builtin_amdgcn_mfma_f32_16x16x32_bf16(af[mf], bf[nf], acc[mf][nf], 0, 0, 0);
    }
    __builtin_amdgcn_s_setprio(0);
    __syncthreads();
    if (hav) {
      PJ_STORE();
      __syncthreads();
    }
  }

  // epilogue: acc -> LDS bounce (bf16, stride 72) -> layout-specific global writes
  unsigned short* Clu = (unsigned short*)smem;  // [64][72]
  const float scale = (z == 0) ? 0.18033688f : 1.0f;  // 0.125 * log2(e)
#pragma unroll
  for (int mf = 0; mf < 2; ++mf)
#pragma unroll
    for (int nf = 0; nf < 2; ++nf)
#pragma unroll
      for (int rr = 0; rr < 4; ++rr) {
        const int row = wm * 32 + mf * 16 + (g << 2) + rr;
        const int col = wn * 32 + nf * 16 + c;
        Clu[row * 72 + col] = f2bf((acc[mf][nf][rr] + Bls[row]) * scale);
      }
  __syncthreads();
  if (z <= 1) {
    unsigned short* Ob = (z == 0) ? Qb : Kb;
    const int d0 = co0 >> 2;
    const int h = tid >> 6, n = tid & 63;
    unsigned u[8];
#pragma unroll
    for (int p = 0; p < 8; ++p)
      u[p] = (unsigned)Clu[((p << 3) + h) * 72 + n] |
             ((unsigned)Clu[((p << 3) + 4 + h) * 72 + n] << 16);
    uint4* dd = (uint4*)(Ob + ((size_t)h * NN + n0 + n) * 64 + d0);
    dd[0] = *(uint4*)&u[0];
    dd[1] = *(uint4*)&u[4];
  } else {
    const int rl = tid >> 2, seg = (tid & 3) << 4;
    const int h = rl & 3, d = (co0 >> 2) + (rl >> 2);
    unsigned short* vd = Vb + (size_t)(h * 80 + d) * NN + n0 + seg;
    *(uint4*)vd = *(const uint4*)((char*)Clu + rl * 144 + (seg << 1));
    *(uint4*)(vd + 8) = *(const uint4*)((char*)Clu + rl * 144 + (seg << 1) + 16);
  }
}

// ---------------- fused flash attention (split-K, exp2, triple-buffer pipelined) ----------------
// 1-D grid (128*nsplit), block 256 = 4 waves. XCD-grouped decode. Software pipeline:
// softmax(i) [VALU] overlaps QK(i+1) [MFMA]; K/V triple-buffered, one barrier per tile.
// Partials stored bf16 (ObT [sp*4+h][q][72]); m/l stored f32 (Ml [sp*4+h][2][NN]).
// LDS: 3 x (K 8192 | V 10240) + P 4x4096 = 71680 (2 blocks/CU)
__global__ __launch_bounds__(256, 2) void attn_kernel(
    const unsigned short* __restrict__ Qb, const unsigned short* __restrict__ Kb,
    const unsigned short* __restrict__ Vb, unsigned short* __restrict__ ObT,
    float* __restrict__ Ml, int chunkKeys, int nsplit) {
  __shared__ __align__(16) unsigned char smem[71680];
  const int b = blockIdx.x;
  int x, h, sp;
  if (nsplit >= 2) {
    const int xcd = b & 7, slot = b >> 3;
    const int group = xcd * (nsplit >> 1) + (slot >> 5);  // bijective for even nsplit
    x = slot & 31; h = group & 3; sp = group >> 2;
  } else {
    x = b & 31; h = (b >> 5) & 3; sp = 0;
  }
  const int qbase = x * 128;
  const int tid = threadIdx.x;
  const int w = tid >> 6;
  const int l = tid & 63;
  const int c = l & 15;
  const int g = l >> 4;
  const int swc = (c & 7) << 4;

  char* const Pls = (char*)smem + 55296 + w * 4096;

  short8 qf[2][2];
#pragma unroll
  for (int qs = 0; qs < 2; ++qs) {
    const unsigned short* qsrc = Qb + (((h * NN) + qbase + w * 32 + qs * 16 + c) << 6) + (g << 3);
    qf[qs][0] = *(const short8*)qsrc;
    qf[qs][1] = *(const short8*)(qsrc + 32);
  }

  f32x4 Of[2][5];
#pragma unroll
  for (int qs = 0; qs < 2; ++qs)
#pragma unroll
    for (int dt = 0; dt < 5; ++dt) Of[qs][dt] = (f32x4){0.f, 0.f, 0.f, 0.f};
  float mrun[2] = {-1e30f, -1e30f};
  float lrun[2] = {0.f, 0.f};

  const int r0 = tid >> 3, ch = tid & 7;
  const int so = (ch << 4) ^ ((r0 & 7) << 4);
  const int mStart = sp * chunkKeys;
  const int niter = chunkKeys >> 6;  // even (>= 16)

  uint4 ska, skb, sva, svb, svc;

#define LOADT(m0_) do { \
    const unsigned short* kbase_ = Kb + ((h * NN + (m0_)) << 6); \
    const unsigned short* vbase_ = Vb + (size_t)(h * 80) * NN + (m0_); \
    ska = *(const uint4*)(kbase_ + (r0 << 6) + (ch << 3)); \
    skb = *(const uint4*)(kbase_ + ((r0 + 32) << 6) + (ch << 3)); \
    sva = *(const uint4*)(vbase_ + (size_t)r0 * NN + (ch << 3)); \
    svb = *(const uint4*)(vbase_ + (size_t)(r0 + 32) * NN + (ch << 3)); \
    if (tid < 128) svc = *(const uint4*)(vbase_ + (size_t)(r0 + 64) * NN + (ch << 3)); \
  } while (0)

#define STORET(bj_) do { \
    char* Kd_ = (char*)smem + (bj_) * 18432; \
    char* Vd_ = Kd_ + 8192; \
    *(uint4*)(Kd_ + r0 * 128 + so) = ska; \
    *(uint4*)(Kd_ + (r0 + 32) * 128 + so) = skb; \
    *(uint4*)(Vd_ + r0 * 128 + so) = sva; \
    *(uint4*)(Vd_ + (r0 + 32) * 128 + so) = svb; \
    if (tid < 128) *(uint4*)(Vd_ + (r0 + 64) * 128 + so) = svc; \
  } while (0)

#define QKSTEP(bj_, DST) do { \
    const char* Kc_ = (char*)smem + (bj_) * 18432; \
    __builtin_amdgcn_s_setprio(1); \
    _Pragma("unroll") for (int t = 0; t < 4; ++t) { \
      const char* rp_ = Kc_ + (t * 16 + c) * 128; \
      const short8 k0_ = *(const short8*)(rp_ + ((g << 4) ^ swc)); \
      const short8 k1_ = *(const short8*)(rp_ + ((64 + (g << 4)) ^ swc)); \
      _Pragma("unroll") for (int qs = 0; qs < 2; ++qs) { \
        f32x4 a_ = (f32x4){0.f, 0.f, 0.f, 0.f}; \
        a_ = __builtin_amdgcn_mfma_f32_16x16x32_bf16(k0_, qf[qs][0], a_, 0, 0, 0); \
        a_ = __builtin_amdgcn_mfma_f32_16x16x32_bf16(k1_, qf[qs][1], a_, 0, 0, 0); \
        DST[qs][t] = a_; \
      } \
    } \
    __builtin_amdgcn_s_setprio(0); \
  } while (0)

#define SMSTEP(SRC) do { \
    _Pragma("unroll") for (int qs = 0; qs < 2; ++qs) { \
      float m01_ = fmaxf(fmaxf(SRC[qs][0][0], SRC[qs][0][1]), fmaxf(SRC[qs][0][2], SRC[qs][0][3])); \
      float m11_ = fmaxf(fmaxf(SRC[qs][1][0], SRC[qs][1][1]), fmaxf(SRC[qs][1][2], SRC[qs][1][3])); \
      float m21_ = fmaxf(fmaxf(SRC[qs][2][0], SRC[qs][2][1]), fmaxf(SRC[qs][2][2], SRC[qs][2][3])); \
      float m31_ = fmaxf(fmaxf(SRC[qs][3][0], SRC[qs][3][1]), fmaxf(SRC[qs][3][2], SRC[qs][3][3])); \
      float mx_ = fmaxf(fmaxf(m01_, m11_), fmaxf(m21_, m31_)); \
      mx_ = fmaxf(mx_, __shfl_xor(mx_, 16)); \
      mx_ = fmaxf(mx_, __shfl_xor(mx_, 32)); \
      if (!__all(mx_ - mrun[qs] <= 11.5f)) { \
        const float mn_ = fmaxf(mrun[qs], mx_); \
        const float a_ = __builtin_amdgcn_exp2f(mrun[qs] - mn_); \
        mrun[qs] = mn_; \
        lrun[qs] *= a_; \
        _Pragma("unroll") for (int dt = 0; dt < 5; ++dt) \
          _Pragma("unroll") for (int r = 0; r < 4; ++r) Of[qs][dt][r] *= a_; \
      } \
      const float mm_ = mrun[qs]; \
      float rs_ = 0.f; \
      unsigned pk_[8]; \
      _Pragma("unroll") for (int t = 0; t < 4; ++t) { \
        const float e0_ = __builtin_amdgcn_exp2f(SRC[qs][t][0] - mm_); \
        const float e1_ = __builtin_amdgcn_exp2f(SRC[qs][t][1] - mm_); \
        const float e2_ = __builtin_amdgcn_exp2f(SRC[qs][t][2] - mm_); \
        const float e3_ = __builtin_amdgcn_exp2f(SRC[qs][t][3] - mm_); \
        rs_ += (e0_ + e1_) + (e2_ + e3_); \
        pk_[t * 2]     = packpair(e0_, e1_); \
        pk_[t * 2 + 1] = packpair(e2_, e3_); \
      } \
      rs_ += __shfl_xor(rs_, 16); \
      rs_ += __shfl_xor(rs_, 32); \
      lrun[qs] += rs_; \
      char* prow_ = Pls + (qs * 16 + c) * 128; \
      _Pragma("unroll") for (int t = 0; t < 4; ++t) \
        *(uint2*)(prow_ + ((t * 32 + (g << 3)) ^ swc)) = make_uint2(pk_[t * 2], pk_[t * 2 + 1]); \
    } \
  } while (0)

#define PVSTEP(bj_) do { \
    short8 pb_[2][2]; \
    _Pragma("unroll") for (int qs = 0; qs < 2; ++qs) { \
      const char* prow_ = Pls + (qs * 16 + c) * 128; \
      pb_[qs][0] = *(const short8*)(prow_ + ((g << 4) ^ swc)); \
      pb_[qs][1] = *(const short8*)(prow_ + ((64 + (g << 4)) ^ swc)); \
    } \
    const char* Vc_ = (char*)smem + (bj_) * 18432 + 8192; \
    __builtin_amdgcn_s_setprio(1); \
    _Pragma("unroll") for (int dt = 0; dt < 5; ++dt) { \
      const char* vp_ = Vc_ + (dt * 16 + c) * 128; \
      const short8 v0_ = *(const short8*)(vp_ + ((g << 4) ^ swc)); \
      const short8 v1_ = *(const short8*)(vp_ + ((64 + (g << 4)) ^ swc)); \
      _Pragma("unroll") for (int qs = 0; qs < 2; ++qs) { \
        Of[qs][dt] = __builtin_amdgcn_mfma_f32_16x16x32_bf16(v0_, pb_[qs][0], Of[qs][dt], 0, 0, 0); \
        Of[qs][dt] = __builtin_amdgcn_mfma_f32_16x16x32_bf16(v1_, pb_[qs][1], Of[qs][dt], 0, 0, 0); \
      } \
    } \
    __builtin_amdgcn_s_setprio(0); \
  } while (0)

  f32x4 sD0[2][4], sD1[2][4];

  // ---- prologue: tile0 -> buf0; QK(0); tile1 -> buf1; tile2 loads in regs ----
  LOADT(mStart);
  STORET(0);
  LOADT(mStart + 64);
  __syncthreads();                 // buf0 ready
  QKSTEP(0, sD0);                  // QK(0)
  STORET(1);                       // tile1 -> buf1
  LOADT(mStart + 128);             // tile2 loads in flight (niter >= 16)
  __syncthreads();                 // buf1 ready

  for (int it = 0; it < niter; it += 2) {
    // ---- even half: current sD0 (tile it) ----
    SMSTEP(sD0);                                   // softmax(it) [VALU]
    QKSTEP((it + 1) % 3, sD1);                     // QK(it+1)    [MFMA] - independent
    PVSTEP(it % 3);                                // PV(it)
    if (it + 2 < niter) {
      STORET((it + 2) % 3);                        // tile(it+2) -> its buffer
      if (it + 3 < niter) LOADT(mStart + ((it + 3) << 6));
    }
    __syncthreads();
    // ---- odd half: current sD1 (tile it+1) ----
    SMSTEP(sD1);
    if (it + 2 < niter) QKSTEP((it + 2) % 3, sD0);
    PVSTEP((it + 1) % 3);
    if (it + 3 < niter) {
      STORET((it + 3) % 3);
      if (it + 4 < niter) LOADT(mStart + ((it + 4) << 6));
    }
    __syncthreads();
  }

#undef LOADT
#undef STORET
#undef QKSTEP
#undef SMSTEP
#undef PVSTEP

  // epilogue: bf16 partials (5 uint2 stores per qs) + f32 m/l
  const int hb = sp * 4 + h;
#pragma unroll
  for (int qs = 0; qs < 2; ++qs) {
    const int qg = qbase + w * 32 + qs * 16 + c;
    unsigned short* orow = ObT + ((size_t)hb * NN + qg) * 72;
#pragma unroll
    for (int dt = 0; dt < 5; ++dt) {
      if (dt == 4 && g >= 2) continue;  // dv >= 72: nonexistent (V rows zero-padded)
      const unsigned lo = packpair(Of[qs][dt][0], Of[qs][dt][1]);
      const unsigned hi = packpair(Of[qs][dt][2], Of[qs][dt][3]);
      *(uint2*)(orow + dt * 16 + (g << 2)) = make_uint2(lo, hi);
    }
    if (g == 0) {
      Ml[((size_t)hb * 2 + 0) * NN + qg] = mrun[qs];  // log2-domain max
      Ml[((size_t)hb * 2 + 1) * NN + qg] = lrun[qs];
    }
  }
}

// ---------------- combine splits + augment, write Yt bf16 [NN][288] directly ----------------
// grid (256), block 256: q-chunk of 16; workers = 4 h x 4 dv-groups (16-dv chunks).
// Reads bf16 partial rows ObT [hb][q][72] via uint4; m/l from f32 Ml.
template <int NS>
__global__ __launch_bounds__(256) void combine_t_kernel(
    const unsigned short* __restrict__ ObT, const float* __restrict__ Ml,
    const float* __restrict__ coords0, unsigned short* __restrict__ Yt) {
  __shared__ __align__(16) unsigned char Yl[16 * 640];  // [16 q][320 ushort], XOR-swizzled
  const int t = threadIdx.x;
  const int q = t & 15;
  const int worker = t >> 4;       // 0..15
  const int h = worker & 3;
  const int dgrp = worker >> 2;    // 0..3 -> dv [0,16) [16,32) [32,48) [48,72)
  const int q0 = blockIdx.x << 4;
  const int qg = q0 + q;
  const int rowb = q * 640;
  const int sw = (q & 7) << 4;

  float m[NS], wgt[NS], lv[NS];
#pragma unroll
  for (int s = 0; s < NS; ++s)
    m[s] = Ml[((size_t)(s * 4 + h) * 2 + 0) * NN + qg];
#pragma unroll
  for (int s = 0; s < NS; ++s)
    lv[s] = Ml[((size_t)(s * 4 + h) * 2 + 1) * NN + qg];
  float M = -1e30f;
#pragma unroll
  for (int s = 0; s < NS; ++s) M = fmaxf(M, m[s]);
  float L = 0.f;
#pragma unroll
  for (int s = 0; s < NS; ++s) {
    wgt[s] = __builtin_amdgcn_exp2f(m[s] - M);  // m is log2-domain
    L += lv[s] * wgt[s];
  }
  const float invL = 1.f / L;
#pragma unroll
  for (int s = 0; s < NS; ++s) wgt[s] *= invL;

  if (worker == 0) *(uint2*)(Yl + rowb + (568 ^ sw)) = make_uint2(0u, 0u);  // pad cols 284..287

  const int c0 = dgrp << 4;
  const int nch = (dgrp == 3) ? 3 : 2;
  uint4 ld[NS][3];
#pragma unroll
  for (int s = 0; s < NS; ++s) {
    const unsigned short* orow = ObT + ((size_t)(s * 4 + h) * NN + qg) * 72 + c0;
#pragma unroll
    for (int i = 0; i < 3; ++i)
      if (i < nch) ld[s][i] = *(const uint4*)(orow + (i << 3));
  }

  float ss = 0.f;
#pragma unroll
  for (int i = 0; i < 3; ++i) {
    if (i < nch) {
#pragma unroll
      for (int e = 0; e < 8; ++e) {
        const int dv = c0 + (i << 3) + e;
        if (dv < 67) {
          float a = 0.f;
#pragma unroll
          for (int s = 0; s < NS; ++s) {
            const unsigned short us = ((const unsigned short*)&ld[s][i])[e];
            a = fmaf(bf2f(us), wgt[s], a);
          }
          *(unsigned short*)(Yl + rowb + ((((dv << 2) + h) << 1) ^ sw)) = f2bf(a);
          if (dv >= 64) {
            const float au = a - coords0[(size_t)(dv - 64) * NN + qg];
            *(unsigned short*)(Yl + rowb + (((((dv + 3) << 2) + h) << 1) ^ sw)) = f2bf(au);
            ss += au * au;
          }
        }
      }
    }
  }
  if (dgrp == 3) *(unsigned short*)(Yl + rowb + (((280 + h) << 1) ^ sw)) = f2bf(sqrtf(ss));
  __syncthreads();

  for (int i = t; i < 16 * 36; i += 256) {
    const int row = i / 36, seg = i - row * 36;
    *(uint4*)(Yt + (size_t)(q0 + row) * 288 + (seg << 3)) =
        *(const uint4*)(Yl + row * 640 + ((seg << 4) ^ ((row & 7) << 4)));
  }
}

// ---------------- MFMA out projection: out = Wm(284x284) . y + bm ----------------
// grid (NN/64, 5), block 256 = 4 waves (2x2). BM=64, BN=64, BK=96, K=288.
#define OP_LOAD(k0_) do { \
  const int arow = co0 + ar; \
  _Pragma("unroll") for (int i = 0; i < 6; ++i) { \
    const int col = (k0_) + ac + 4 * i; \
    wa[i] = (arow < 284 && col < 284) ? *(const float4*)(Wm + (size_t)arow * 284 + col) \
                                      : make_float4(0.f, 0.f, 0.f, 0.f); \
  } \
  _Pragma("unroll") for (int i = 0; i < 3; ++i) \
    wb[i] = *(const uint4*)(Yt + (size_t)(n0 + bn) * 288 + (k0_) + bc + 8 * i); \
} while (0)

#define OP_WRITE_LDS() do { \
  unsigned pk[12]; \
  _Pragma("unroll") for (int i = 0; i < 6; ++i) { \
    pk[2 * i] = packpair(wa[i].x, wa[i].y); \
    pk[2 * i + 1] = packpair(wa[i].z, wa[i].w); \
  } \
  _Pragma("unroll") for (int i = 0; i < 3; ++i) \
    *(uint4*)(Al + ar * 256 + (((ac << 1) + (i << 4)) ^ aswz)) = *(uint4*)&pk[4 * i]; \
  _Pragma("unroll") for (int i = 0; i < 3; ++i) \
    *(uint4*)(Bl + bn * 256 + (((bc << 1) + (i << 4)) ^ bswz)) = wb[i]; \
} while (0)

__global__ __launch_bounds__(256) void outproj_gemm_kernel(
    const unsigned short* __restrict__ Yt, const float* __restrict__ Wm,
    const float* __restrict__ bm, float* __restrict__ out) {
  __shared__ __align__(16) unsigned char smem[32768];  // Al 64x256B | Bl 64x256B
  __shared__ float Bls[64];
  const int co0 = blockIdx.y << 6;
  const int n0 = blockIdx.x << 6;
  const int tid = threadIdx.x;
  const int w = tid >> 6, l = tid & 63;
  const int wm = w >> 1, wn = w & 1;
  const int c = l & 15, g = l >> 4;
  char* const Al = (char*)smem;
  char* const Bl = (char*)smem + 16384;

  if (tid < 64) { const int co = co0 + tid; Bls[tid] = (co < 284) ? bm[co] : 0.f; }

  const int ar = tid >> 2, ac = (tid & 3) * 24;  // A: 64 rows x 96 f32, 4 thr/row
  const int bn = tid >> 2, bc = (tid & 3) * 24;  // B: 64 rows x 96 bf16, 4 thr/row
  const int aswz = (ar & 7) << 4;
  const int bswz = (bn & 7) << 4;

  float4 wa[6];
  uint4 wb[3];
  f32x4 acc[2][2];
#pragma unroll
  for (int mf = 0; mf < 2; ++mf)
#pragma unroll
    for (int nf = 0; nf < 2; ++nf) acc[mf][nf] = (f32x4){0.f, 0.f, 0.f, 0.f};

  OP_LOAD(0);
  OP_WRITE_LDS();
  __syncthreads();

  for (int s = 0; s < 3; ++s) {
    const bool hav = (s + 1 < 3);
    if (hav) OP_LOAD((s + 1) * 96);
    __builtin_amdgcn_s_setprio(1);
#pragma unroll
    for (int ks = 0; ks < 3; ++ks) {
      short8 af[2], bf[2];
#pragma unroll
      for (int mf = 0; mf < 2; ++mf) {
        const int row = wm * 32 + mf * 16 + c;
        af[mf] = *(const short8*)(Al + row * 256 + (((ks << 6) + (g << 4)) ^ ((row & 7) << 4)));
      }
#pragma unroll
      for (int nf = 0; nf < 2; ++nf) {
        const int row = wn * 32 + nf * 16 + c;
        bf[nf] = *(const short8*)(Bl + row * 256 + (((ks << 6) + (g << 4)) ^ ((row & 7) << 4)));
      }
#pragma unroll
      for (int mf = 0; mf < 2; ++mf)
#pragma unroll
        for (int nf = 0; nf < 2; ++nf)
          acc[mf][nf] = __builtin_amdgcn_mfma_f32_16x16x32_bf16(af[mf], bf[nf], acc[mf][nf], 0, 0, 0);
    }
    __builtin_amdgcn_s_setprio(0);
    __syncthreads();
    if (hav) {
      OP_WRITE_LDS();
      __syncthreads();
    }
  }

#pragma unroll
  for (int mf = 0; mf < 2; ++mf)
#pragma unroll
    for (int nf = 0; nf < 2; ++nf)
#pragma unroll
      for (int rr = 0; rr < 4; ++rr) {
        const int row = wm * 32 + mf * 16 + (g << 2) + rr;
        const int co = co0 + row;
        if (co < 284)
          out[(size_t)co * NN + n0 + wn * 32 + nf * 16 + c] = acc[mf][nf][rr] + Bls[row];
      }
}

extern "C" void kernel_launch(void* const* d_in, const int* in_sizes, int n_in,
                              void* d_out, int out_size, void* d_ws, size_t ws_size,
                              hipStream_t stream) {
  const float* query   = (const float*)d_in[0];
  const float* key_    = (const float*)d_in[1];
  const float* value   = (const float*)d_in[2];
  const float* coords0 = (const float*)d_in[3];
  const float* coords1 = (const float*)d_in[4];
  const float* Wq = (const float*)d_in[5];
  const float* bq = (const float*)d_in[6];
  const float* Wk = (const float*)d_in[7];
  const float* bk = (const float*)d_in[8];
  const float* Wv = (const float*)d_in[9];
  const float* bv = (const float*)d_in[10];
  const float* Wm = (const float*)d_in[11];
  const float* bm = (const float*)d_in[12];
  float* out = (float*)d_out;

  // ws: Qb 2MB | Kb 2MB | Vb 2.62MB | Xt 6MB | Yt 2.25MB | ObT nsplit*2.36MB | Ml nsplit*128KB
  unsigned short* Qb = (unsigned short*)d_ws;
  unsigned short* Kb = Qb + (size_t)4 * NN * 64;
  unsigned short* Vb = Kb + (size_t)4 * NN * 64;
  unsigned short* Xt = Vb + (size_t)4 * 80 * NN;
  unsigned short* Yt = Xt + (size_t)3 * NN * 256;
  unsigned short* ObT = Yt + (size_t)NN * 288;

  const size_t fixedB = (size_t)((char*)ObT - (char*)d_ws);
  const size_t per = (size_t)4 * NN * 72 * 2 + (size_t)4 * 2 * NN * 4;
  int nsplit = 4;
  while (nsplit > 1 && ws_size < fixedB + (size_t)nsplit * per) nsplit >>= 1;
  float* Ml = (float*)(ObT + (size_t)nsplit * 4 * NN * 72);

  hipLaunchKernelGGL(transpose3_kernel, dim3(64, 4, 3), dim3(256), 0, stream,
                     query, key_, value, Xt, coords1, Vb);
  hipLaunchKernelGGL(proj_gemm_kernel, dim3(64, 4, 3), dim3(256), 0, stream,
                     Wq, bq, Wk, bk, Wv, bv, Xt, Qb, Kb, Vb);
  hipLaunchKernelGGL(attn_kernel, dim3(128 * nsplit), dim3(256), 0, stream,
                     Qb, Kb, Vb, ObT, Ml, NN / nsplit, nsplit);
  switch (nsplit) {
    case 4:
      hipLaunchKernelGGL((combine_t_kernel<4>), dim3(256), dim3(256), 0, stream, ObT, Ml, coords0, Yt);
      break;
    case 2:
      hipLaunchKernelGGL((combine_t_kernel<2>), dim3(256), dim3(256), 0, stream, ObT, Ml, coords0, Yt);
      break;
    default:
      hipLaunchKernelGGL((combine_t_kernel<1>), dim3(256), dim3(256), 0, stream, ObT, Ml, coords0, Yt);
      break;
  }
  hipLaunchKernelGGL(outproj_gemm_kernel, dim3(64, 5), dim3(256), 0, stream, Yt, Wm, bm, out);
}